// Round 1
// baseline (1620.343 us; speedup 1.0000x reference)
//
#include <hip/hip_runtime.h>

// ---------------- types / helpers ----------------
typedef __bf16 bf16x8 __attribute__((ext_vector_type(8)));
typedef float  f32x4  __attribute__((ext_vector_type(4)));

#define QSCALE 0.17677669529663687f   // 32^-0.5 (main attn head_dim=32)

__device__ __forceinline__ f32x4 mfma16(bf16x8 a, bf16x8 b, f32x4 c) {
  return __builtin_amdgcn_mfma_f32_16x16x32_bf16(a, b, c, 0, 0, 0);
}

// row-major [rows][rowChunks*8] bf16 tile with XOR-swizzled 16B chunks
__device__ __forceinline__ int swz_idx(int row, int col, int rowChunks) {
  return row * (rowChunks << 3) + ((((col >> 3) ^ (row & 7)) << 3) | (col & 7));
}

// A/B fragment load from swizzled row-major LDS tile.
// lane -> (16dim = rowBase + (lane&15), k-chunk = chunkBase + (lane>>4))
__device__ __forceinline__ bf16x8 ld_tile(const __bf16* t, int rowChunks,
                                          int rowBase, int chunkBase, int lane) {
  int row = rowBase + (lane & 15);
  int c = (chunkBase + (lane >> 4)) ^ (row & 7);
  return *(const bf16x8*)(t + row * (rowChunks << 3) + (c << 3));
}

// fragment load from pre-packed global weights (coalesced 1KiB per wave)
__device__ __forceinline__ bf16x8 ld_pack(const __bf16* pk, int nt, int ks,
                                          int ksteps, int lane) {
  int idx = ((nt * ksteps + ks) * 64 + lane) * 8;
  return *(const bf16x8*)(pk + idx);
}

__device__ __forceinline__ int region_of(int hh, int ww) {
  int rh = (hh < 248) ? 0 : ((hh < 252) ? 1 : 2);
  int rw = (ww < 248) ? 0 : ((ww < 252) ? 1 : 2);
  return rh * 3 + rw;
}

// ---------------- K0: pack weights to bf16 fragment order ----------------
// segments (elements): [0,32768) qkv rows 0..255 (q rows scaled);
// [32768,49152) W_v (qkv rows 256..383) ; [49152,65536) proj ;
// [65536,98304) fc1 ; [98304,131072) fc2 (K=256)
__global__ void k_pack(const float* __restrict__ qkvw, const float* __restrict__ projw,
                       const float* __restrict__ fc1w, const float* __restrict__ fc2w,
                       __bf16* __restrict__ pk) {
  int i = blockIdx.x * 256 + threadIdx.x;
  const float* src; int K; int e; int scaleQ = 0;
  if (i < 32768)      { src = qkvw;             K = 128; e = i;          scaleQ = 1; }
  else if (i < 49152) { src = qkvw + 256 * 128; K = 128; e = i - 32768; }
  else if (i < 65536) { src = projw;            K = 128; e = i - 49152; }
  else if (i < 98304) { src = fc1w;             K = 128; e = i - 65536; }
  else                { src = fc2w;             K = 256; e = i - 98304; }
  int i8 = e & 7, ln = (e >> 3) & 63, t = e >> 9;
  int ls = (K == 256) ? 3 : 2;
  int ks = t & ((1 << ls) - 1), nt = t >> ls;
  int row = (nt << 4) + (ln & 15);
  int k = (ks << 5) + ((ln >> 4) << 3) + i8;
  float v = src[row * K + k];
  if (scaleQ && row < 128) v *= QSCALE;
  pk[i] = (__bf16)v;
}

// ---------------- K1: grouped 8x8/stride8 conv -> uni [B][32][32][64] ----------------
__global__ void k_uniconv(const float* __restrict__ x, const float* __restrict__ uw,
                          const float* __restrict__ ub, float* __restrict__ uni) {
  int bidx = blockIdx.x;               // b*1024 + oh*32 + ow
  int b = bidx >> 10, oh = (bidx >> 5) & 31, ow = bidx & 31;
  int d = threadIdx.x;                 // input channel 0..127
  const float* xb = x + (((size_t)((b << 16) + ((oh << 3) << 8) + (ow << 3))) << 7) + d;
  const float* w = uw + d * 64;        // uni_w[d/2][d&1][kh][kw] == uw[d*64 + kh*8+kw]
  float acc = 0.f;
#pragma unroll
  for (int kh = 0; kh < 8; ++kh)
#pragma unroll
    for (int kw = 0; kw < 8; ++kw)
      acc += xb[(size_t)(((kh << 8) + kw)) << 7] * w[kh * 8 + kw];
  acc += __shfl_xor(acc, 1);
  if (!(d & 1)) uni[((size_t)bidx << 6) + (d >> 1)] = acc + ub[d >> 1];
}

// ---------------- K2: ngram sliding 2x2 MHSA (fwd+bwd) + merge -> ctx [B][32][32][128]
__global__ void k_ngram(const float* __restrict__ uni, const float* __restrict__ ngqkvw,
                        const float* __restrict__ ngqkvb, const float* __restrict__ ngprojw,
                        const float* __restrict__ ngprojb, const float* __restrict__ ngbias,
                        const float* __restrict__ mergew, const float* __restrict__ mergeb,
                        float* __restrict__ ctx) {
  __shared__ float tok[2][4][64];
  __shared__ float qs[2][4][64], kl[2][4][64], vs[2][4][64];
  __shared__ float sc[2][4][4][4];
  __shared__ float pr[2][4][4][4];
  __shared__ float avg[2][64];
  __shared__ float po[128];

  int bidx = blockIdx.x;
  int b = bidx >> 10, i = (bidx >> 5) & 31, j = bidx & 31;
  int tid = threadIdx.x;
  int dir = tid >> 6, lane = tid & 63;   // dir 0 = fwd pad, 1 = bwd pad

#pragma unroll
  for (int p = 0; p < 4; ++p) {
    int pi = i + (p >> 1), pj = j + (p & 1);
    int r, c;
    if (dir == 0) { r = (pi < 32) ? pi : 30; c = (pj < 32) ? pj : 30; }
    else          { r = (pi == 0) ? 1 : pi - 1; c = (pj == 0) ? 1 : pj - 1; }
    tok[dir][p][lane] = uni[(size_t)((((b << 5) + r) << 5) + c) * 64 + lane];
  }
  __syncthreads();
#pragma unroll
  for (int p = 0; p < 4; ++p) {
    float aq = ngqkvb[lane], ak = ngqkvb[64 + lane], av = ngqkvb[128 + lane];
    const float* wq = ngqkvw + lane * 64;
    const float* wk = ngqkvw + (64 + lane) * 64;
    const float* wv = ngqkvw + (128 + lane) * 64;
    for (int c = 0; c < 64; ++c) {
      float t = tok[dir][p][c];
      aq += wq[c] * t; ak += wk[c] * t; av += wv[c] * t;
    }
    qs[dir][p][lane] = aq * 0.25f;   // 16^-0.5
    kl[dir][p][lane] = ak;
    vs[dir][p][lane] = av;
  }
  __syncthreads();
  {
    int h = lane >> 4, rem = lane & 15, p = rem >> 2, m = rem & 3;
    float s = 0.f;
#pragma unroll
    for (int e = 0; e < 16; ++e) s += qs[dir][p][h * 16 + e] * kl[dir][m][h * 16 + e];
    int idx = ((p >> 1) - (m >> 1) + 1) * 3 + ((p & 1) - (m & 1) + 1);
    s += ngbias[idx * 4 + h];
    sc[dir][h][p][m] = s;
  }
  __syncthreads();
  {
    int h = lane >> 4, rem = lane & 15, p = rem >> 2, m = rem & 3;
    float v0 = sc[dir][h][p][0], v1 = sc[dir][h][p][1];
    float v2 = sc[dir][h][p][2], v3 = sc[dir][h][p][3];
    float mx = fmaxf(fmaxf(v0, v1), fmaxf(v2, v3));
    float e0 = __expf(v0 - mx), e1 = __expf(v1 - mx);
    float e2 = __expf(v2 - mx), e3 = __expf(v3 - mx);
    float inv = 1.f / (e0 + e1 + e2 + e3);
    float em = (m == 0) ? e0 : (m == 1) ? e1 : (m == 2) ? e2 : e3;
    pr[dir][h][p][m] = em * inv;
  }
  __syncthreads();
  {
    int c = lane, h = c >> 4;
    float a = 0.f;
#pragma unroll
    for (int p = 0; p < 4; ++p)
#pragma unroll
      for (int m = 0; m < 4; ++m)
        a += pr[dir][h][p][m] * vs[dir][m][c];
    avg[dir][c] = a * 0.25f;         // avgpool over the window's 4 tokens
  }
  __syncthreads();
  {
    float a = ngprojb[lane];
    const float* wp = ngprojw + lane * 64;
    for (int c = 0; c < 64; ++c) a += wp[c] * avg[dir][c];
    po[(dir << 6) + lane] = a;
  }
  __syncthreads();
  {
    int o = tid;                     // 0..127
    float a = mergeb[o];
    const float* wm = mergew + o * 128;
    for (int c = 0; c < 128; ++c) a += wm[c] * po[c];
    ctx[(((size_t)((((b << 5) + i) << 5) + j)) << 7) + o] = a;
  }
}

// ---------------- K3: fused window attention + LN + FFN + LN ----------------
// LDS map (128 KiB dynamic):
//  [0,16K)   Xbf  [64][128] bf16 swz : tokens (x+ctx) -> later x1 bf16
//  [16K,32K) QO   [64][128] bf16 swz : Q then O     | with Kl forms Hl [64][256] in FFN
//  [32K,48K) Kl   [64][128] bf16 swz
//  [48K,64K) Vt   [128][64] bf16 swz (V transposed)  | with P start: Rf/Ff f32 [64][132]
//  [64K,96K) Pl   [4][64][64] bf16 swz (per-wave P)
//  [96K,128K) Xf  [64][128] f32 : x -> x1
__global__ void __launch_bounds__(256, 1)
k_main(const float* __restrict__ xin, const float* __restrict__ ctx,
       const __bf16* __restrict__ pk_qkv, const __bf16* __restrict__ pk_wv,
       const __bf16* __restrict__ pk_proj, const __bf16* __restrict__ pk_fc1,
       const __bf16* __restrict__ pk_fc2,
       const float* __restrict__ qkvb, const float* __restrict__ projb,
       const float* __restrict__ bt,
       const float* __restrict__ n1g, const float* __restrict__ n1b,
       const float* __restrict__ n2g, const float* __restrict__ n2b,
       const float* __restrict__ fc1b, const float* __restrict__ fc2b,
       float* __restrict__ outp) {
  extern __shared__ char smem[];
  __bf16* Xbf = (__bf16*)smem;
  __bf16* QO  = (__bf16*)(smem + 16 * 1024);
  __bf16* Kl  = (__bf16*)(smem + 32 * 1024);
  __bf16* Vt  = (__bf16*)(smem + 48 * 1024);
  __bf16* Pl  = (__bf16*)(smem + 64 * 1024);
  float*  Xf  = (float*)(smem + 96 * 1024);
  float*  Rf  = (float*)(smem + 48 * 1024);   // [64][132] f32 (aliases Vt+P, used after PV)
  __bf16* Hl  = (__bf16*)(smem + 16 * 1024);  // [64][256] bf16 swz (aliases QO+Kl, FFN)
  float*  Ff  = (float*)(smem + 48 * 1024);   // [64][132] f32

  const int widx = blockIdx.x;
  const int b = widx >> 10, wi = (widx >> 5) & 31, wj = widx & 31;
  const int tid = threadIdx.x;
  const int lane = tid & 63, wv = tid >> 6;
  const int lm = lane & 15, lg = lane >> 4;

  // ---- Phase 0: load tokens (x + ctx), write Xf (f32) and Xbf (bf16 swz) ----
  {
    int n = tid >> 2, q = tid & 3;
    int ts1 = n >> 3, ts2 = n & 7;
    int hh = ((wi << 3) + ts1 + 4) & 255;
    int ww = ((wj << 3) + ts2 + 4) & 255;
    const float* xp = xin + (((size_t)((b << 16) + (hh << 8) + ww)) << 7);
    const float* cp = ctx + (((size_t)((((b << 5) + (hh >> 3)) << 5) + (ww >> 3))) << 7);
#pragma unroll
    for (int jc = 0; jc < 4; ++jc) {
      int c = (q << 2) + jc;                // bf16 chunk 0..15 (8 elems)
      const float* xs = xp + (c << 3);
      const float* cs = cp + (c << 3);
      float4 xa = *(const float4*)xs;
      float4 xb = *(const float4*)(xs + 4);
      float4 ca = *(const float4*)cs;
      float4 cb = *(const float4*)(cs + 4);
      float v[8];
      v[0] = xa.x + ca.x; v[1] = xa.y + ca.y; v[2] = xa.z + ca.z; v[3] = xa.w + ca.w;
      v[4] = xb.x + cb.x; v[5] = xb.y + cb.y; v[6] = xb.z + cb.z; v[7] = xb.w + cb.w;
      float* xd = Xf + (n << 7) + (c << 3);
      *(float4*)xd = make_float4(v[0], v[1], v[2], v[3]);
      *(float4*)(xd + 4) = make_float4(v[4], v[5], v[6], v[7]);
      bf16x8 p8;
#pragma unroll
      for (int e = 0; e < 8; ++e) p8[e] = (__bf16)v[e];
      *(bf16x8*)(Xbf + (n << 7) + ((c ^ (n & 7)) << 3)) = p8;
    }
  }
  __syncthreads();

  // ---- Phase 1a: Q,K = X @ Wqk (wave -> 4 ntiles of 16 cols) ----
  for (int mt = 0; mt < 4; ++mt) {
    bf16x8 af[4];
#pragma unroll
    for (int ks = 0; ks < 4; ++ks) af[ks] = ld_tile(Xbf, 16, mt * 16, ks * 4, lane);
#pragma unroll
    for (int nt2 = 0; nt2 < 4; ++nt2) {
      int ntG = (wv << 2) + nt2;            // 0..15 over 256 q/k cols
      f32x4 acc = {0.f, 0.f, 0.f, 0.f};
#pragma unroll
      for (int ks = 0; ks < 4; ++ks)
        acc = mfma16(af[ks], ld_pack(pk_qkv, ntG, ks, 4, lane), acc);
      int col = (ntG << 4) + lm;            // qkv channel 0..255
      float bias = (col < 128) ? qkvb[col] * QSCALE : qkvb[col];
      __bf16* dst = (col < 128) ? QO : Kl;
      int cc = col & 127;
#pragma unroll
      for (int r = 0; r < 4; ++r) {
        int row = mt * 16 + lg * 4 + r;
        dst[swz_idx(row, cc, 16)] = (__bf16)(acc[r] + bias);
      }
    }
  }
  // ---- Phase 1b: V^T = Wv @ X^T (wave -> 2 mtiles of 16 ch) ----
  for (int mt2 = 0; mt2 < 2; ++mt2) {
    int mtG = (wv << 1) + mt2;              // ch tile 0..7
    bf16x8 af[4];
#pragma unroll
    for (int ks = 0; ks < 4; ++ks) af[ks] = ld_pack(pk_wv, mtG, ks, 4, lane);
#pragma unroll
    for (int nt = 0; nt < 4; ++nt) {
      f32x4 acc = {0.f, 0.f, 0.f, 0.f};
#pragma unroll
      for (int ks = 0; ks < 4; ++ks)
        acc = mfma16(af[ks], ld_tile(Xbf, 16, nt * 16, ks * 4, lane), acc);
      int tok = (nt << 4) + lm;
#pragma unroll
      for (int r = 0; r < 4; ++r) {
        int ch = (mtG << 4) + lg * 4 + r;
        Vt[swz_idx(ch, tok, 8)] = (__bf16)(acc[r] + qkvb[256 + ch]);
      }
    }
  }
  __syncthreads();

  // ---- Phase 2: scores + softmax (wave = head) ----
  float rinv[4][4];
  {
    const int h = wv;
    bf16x8 aq[4], bk[4];
#pragma unroll
    for (int t = 0; t < 4; ++t) {
      aq[t] = ld_tile(QO, 16, t * 16, h * 4, lane);
      bk[t] = ld_tile(Kl, 16, t * 16, h * 4, lane);
    }
    f32x4 sc[4][4];
#pragma unroll
    for (int mt = 0; mt < 4; ++mt)
#pragma unroll
      for (int nt = 0; nt < 4; ++nt) {
        f32x4 z = {0.f, 0.f, 0.f, 0.f};
        sc[mt][nt] = mfma16(aq[mt], bk[nt], z);
      }
    int s1m[4], s2m[4], regm[4];
#pragma unroll
    for (int nt = 0; nt < 4; ++nt) {
      int m = nt * 16 + lm;
      s1m[nt] = m >> 3; s2m[nt] = m & 7;
      regm[nt] = region_of(wi * 8 + s1m[nt], wj * 8 + s2m[nt]);
    }
    const bool edge = (wi == 31) || (wj == 31);
    __bf16* Pme = Pl + (wv << 12);
#pragma unroll
    for (int mt = 0; mt < 4; ++mt) {
#pragma unroll
      for (int r = 0; r < 4; ++r) {
        int n = mt * 16 + lg * 4 + r;
        int s1n = n >> 3, s2n = n & 7;
        int regn = region_of(wi * 8 + s1n, wj * 8 + s2n);
        float v[4];
#pragma unroll
        for (int nt = 0; nt < 4; ++nt) {
          int idx = (s1n - s1m[nt] + 7) * 15 + (s2n - s2m[nt] + 7);
          float s = sc[mt][nt][r] + bt[idx * 4 + h];
          if (edge && (regn != regm[nt])) s -= 100.f;
          v[nt] = s;
        }
        float mx = fmaxf(fmaxf(v[0], v[1]), fmaxf(v[2], v[3]));
#pragma unroll
        for (int d = 1; d < 16; d <<= 1) mx = fmaxf(mx, __shfl_xor(mx, d));
        float ssum = 0.f;
#pragma unroll
        for (int nt = 0; nt < 4; ++nt) { v[nt] = __expf(v[nt] - mx); ssum += v[nt]; }
#pragma unroll
        for (int d = 1; d < 16; d <<= 1) ssum += __shfl_xor(ssum, d);
        rinv[mt][r] = 1.f / ssum;
#pragma unroll
        for (int nt = 0; nt < 4; ++nt)
          Pme[swz_idx(n, nt * 16 + lm, 8)] = (__bf16)v[nt];
      }
    }
  }

  // ---- Phase 3: O_h = P @ V_h (scale by 1/rowsum), write into QO cols h*32.. ----
  {
    const int h = wv;
    const __bf16* Pme = Pl + (wv << 12);
    bf16x8 ap[4][2], bv[2][2];
#pragma unroll
    for (int nt = 0; nt < 2; ++nt)
#pragma unroll
      for (int ks = 0; ks < 2; ++ks)
        bv[nt][ks] = ld_tile(Vt, 8, h * 32 + nt * 16, ks * 4, lane);
#pragma unroll
    for (int mt = 0; mt < 4; ++mt)
#pragma unroll
      for (int ks = 0; ks < 2; ++ks)
        ap[mt][ks] = ld_tile(Pme, 8, mt * 16, ks * 4, lane);
#pragma unroll
    for (int mt = 0; mt < 4; ++mt)
#pragma unroll
      for (int nt = 0; nt < 2; ++nt) {
        f32x4 acc = {0.f, 0.f, 0.f, 0.f};
        acc = mfma16(ap[mt][0], bv[nt][0], acc);
        acc = mfma16(ap[mt][1], bv[nt][1], acc);
        int cc = h * 32 + nt * 16 + lm;
#pragma unroll
        for (int r = 0; r < 4; ++r) {
          int row = mt * 16 + lg * 4 + r;
          QO[swz_idx(row, cc, 16)] = (__bf16)(acc[r] * rinv[mt][r]);
        }
      }
  }
  __syncthreads();

  // ---- Phase 4: R = O @ Wproj + b -> Rf f32 ----
  for (int mt = 0; mt < 4; ++mt) {
    bf16x8 ao[4];
#pragma unroll
    for (int ks = 0; ks < 4; ++ks) ao[ks] = ld_tile(QO, 16, mt * 16, ks * 4, lane);
#pragma unroll
    for (int nt2 = 0; nt2 < 2; ++nt2) {
      int ntG = (wv << 1) + nt2;
      f32x4 acc = {0.f, 0.f, 0.f, 0.f};
#pragma unroll
      for (int ks = 0; ks < 4; ++ks)
        acc = mfma16(ao[ks], ld_pack(pk_proj, ntG, ks, 4, lane), acc);
      int col = (ntG << 4) + lm;
      float pb = projb[col];
#pragma unroll
      for (int r = 0; r < 4; ++r) {
        int row = mt * 16 + lg * 4 + r;
        Rf[row * 132 + col] = acc[r] + pb;
      }
    }
  }
  __syncthreads();

  // ---- Phase 5: x1 = x + LN(R); store f32->Xf, bf16->Xbf ----
  {
    int n = tid >> 2, q = tid & 3;
    const float* rrow = Rf + n * 132 + (q << 5);
    float vals[32];
    float sum1 = 0.f, sum2 = 0.f;
#pragma unroll
    for (int jj = 0; jj < 32; ++jj) { float v = rrow[jj]; vals[jj] = v; sum1 += v; sum2 += v * v; }
    sum1 += __shfl_xor(sum1, 1); sum1 += __shfl_xor(sum1, 2);
    sum2 += __shfl_xor(sum2, 1); sum2 += __shfl_xor(sum2, 2);
    float mean = sum1 * 0.0078125f;
    float var = sum2 * 0.0078125f - mean * mean;
    float rstd = rsqrtf(var + 1e-5f);
    float* xrow = Xf + (n << 7) + (q << 5);
#pragma unroll
    for (int jc = 0; jc < 4; ++jc) {
      bf16x8 p8;
#pragma unroll
      for (int e = 0; e < 8; ++e) {
        int jj = jc * 8 + e; int d = (q << 5) + jj;
        float ln = (vals[jj] - mean) * rstd * n1g[d] + n1b[d];
        float x1 = xrow[jj] + ln;
        xrow[jj] = x1;
        p8[e] = (__bf16)x1;
      }
      int c = (q << 2) + jc;
      *(bf16x8*)(Xbf + (n << 7) + ((c ^ (n & 7)) << 3)) = p8;
    }
  }
  __syncthreads();

  // ---- Phase 6: H = gelu(x1 @ Wfc1 + b) -> Hl bf16 swz ----
  for (int mt = 0; mt < 4; ++mt) {
    bf16x8 a1[4];
#pragma unroll
    for (int ks = 0; ks < 4; ++ks) a1[ks] = ld_tile(Xbf, 16, mt * 16, ks * 4, lane);
#pragma unroll
    for (int nt2 = 0; nt2 < 4; ++nt2) {
      int ntG = (wv << 2) + nt2;            // 0..15 over 256 cols
      f32x4 acc = {0.f, 0.f, 0.f, 0.f};
#pragma unroll
      for (int ks = 0; ks < 4; ++ks)
        acc = mfma16(a1[ks], ld_pack(pk_fc1, ntG, ks, 4, lane), acc);
      int col = (ntG << 4) + lm;
      float b1 = fc1b[col];
#pragma unroll
      for (int r = 0; r < 4; ++r) {
        int row = mt * 16 + lg * 4 + r;
        float hv = acc[r] + b1;
        hv = 0.5f * hv * (1.f + erff(hv * 0.70710678118654752f));
        Hl[swz_idx(row, col, 32)] = (__bf16)hv;
      }
    }
  }
  __syncthreads();

  // ---- Phase 7: F = H @ Wfc2 + b -> Ff f32 ----
  for (int mt = 0; mt < 4; ++mt) {
    bf16x8 a2[8];
#pragma unroll
    for (int ks = 0; ks < 8; ++ks) a2[ks] = ld_tile(Hl, 32, mt * 16, ks * 4, lane);
#pragma unroll
    for (int nt2 = 0; nt2 < 2; ++nt2) {
      int ntG = (wv << 1) + nt2;
      f32x4 acc = {0.f, 0.f, 0.f, 0.f};
#pragma unroll
      for (int ks = 0; ks < 8; ++ks)
        acc = mfma16(a2[ks], ld_pack(pk_fc2, ntG, ks, 8, lane), acc);
      int col = (ntG << 4) + lm;
      float b2 = fc2b[col];
#pragma unroll
      for (int r = 0; r < 4; ++r) {
        int row = mt * 16 + lg * 4 + r;
        Ff[row * 132 + col] = acc[r] + b2;
      }
    }
  }
  __syncthreads();

  // ---- Phase 8: out = x1 + LN(F), scatter back to original positions ----
  {
    int n = tid >> 2, q = tid & 3;
    const float* frow = Ff + n * 132 + (q << 5);
    float vals[32];
    float sum1 = 0.f, sum2 = 0.f;
#pragma unroll
    for (int jj = 0; jj < 32; ++jj) { float v = frow[jj]; vals[jj] = v; sum1 += v; sum2 += v * v; }
    sum1 += __shfl_xor(sum1, 1); sum1 += __shfl_xor(sum1, 2);
    sum2 += __shfl_xor(sum2, 1); sum2 += __shfl_xor(sum2, 2);
    float mean = sum1 * 0.0078125f;
    float var = sum2 * 0.0078125f - mean * mean;
    float rstd = rsqrtf(var + 1e-5f);
    int ts1 = n >> 3, ts2 = n & 7;
    int hh = ((wi << 3) + ts1 + 4) & 255;
    int ww = ((wj << 3) + ts2 + 4) & 255;
    float* op = outp + (((size_t)((b << 16) + (hh << 8) + ww)) << 7) + (q << 5);
    const float* xrow = Xf + (n << 7) + (q << 5);
    int dbase = (q << 5);
#pragma unroll
    for (int jj = 0; jj < 32; jj += 4) {
      float4 o4;
      o4.x = xrow[jj + 0] + (vals[jj + 0] - mean) * rstd * n2g[dbase + jj + 0] + n2b[dbase + jj + 0];
      o4.y = xrow[jj + 1] + (vals[jj + 1] - mean) * rstd * n2g[dbase + jj + 1] + n2b[dbase + jj + 1];
      o4.z = xrow[jj + 2] + (vals[jj + 2] - mean) * rstd * n2g[dbase + jj + 2] + n2b[dbase + jj + 2];
      o4.w = xrow[jj + 3] + (vals[jj + 3] - mean) * rstd * n2g[dbase + jj + 3] + n2b[dbase + jj + 3];
      *(float4*)(op + jj) = o4;
    }
  }
}

// ---------------- launch ----------------
extern "C" void kernel_launch(void* const* d_in, const int* in_sizes, int n_in,
                              void* d_out, int out_size, void* d_ws, size_t ws_size,
                              hipStream_t stream) {
  const float* x      = (const float*)d_in[0];
  const float* uni_w  = (const float*)d_in[1];
  const float* uni_b  = (const float*)d_in[2];
  const float* ngqkvw = (const float*)d_in[3];
  const float* ngqkvb = (const float*)d_in[4];
  const float* ngprojw= (const float*)d_in[5];
  const float* ngprojb= (const float*)d_in[6];
  const float* ngbias = (const float*)d_in[7];
  const float* mergew = (const float*)d_in[8];
  const float* mergeb = (const float*)d_in[9];
  const float* qkvw   = (const float*)d_in[10];
  const float* qkvb   = (const float*)d_in[11];
  const float* projw  = (const float*)d_in[12];
  const float* projb  = (const float*)d_in[13];
  const float* bt     = (const float*)d_in[14];
  const float* n1g    = (const float*)d_in[15];
  const float* n1b    = (const float*)d_in[16];
  const float* n2g    = (const float*)d_in[17];
  const float* n2b    = (const float*)d_in[18];
  const float* fc1w   = (const float*)d_in[19];
  const float* fc1b   = (const float*)d_in[20];
  const float* fc2w   = (const float*)d_in[21];
  const float* fc2b   = (const float*)d_in[22];

  char* ws = (char*)d_ws;
  float*  uni = (float*)ws;                   // 1 MiB : [4][32][32][64]
  float*  ctx = (float*)(ws + (1 << 20));     // 2 MiB : [4][32][32][128]
  __bf16* pk  = (__bf16*)(ws + (3 << 20));    // 256 KiB packed weights
  __bf16* pk_qkv  = pk;
  __bf16* pk_wv   = pk + 32768;
  __bf16* pk_proj = pk + 49152;
  __bf16* pk_fc1  = pk + 65536;
  __bf16* pk_fc2  = pk + 98304;

  k_pack<<<512, 256, 0, stream>>>(qkvw, projw, fc1w, fc2w, pk);
  k_uniconv<<<4096, 128, 0, stream>>>(x, uni_w, uni_b, uni);
  k_ngram<<<4096, 128, 0, stream>>>(uni, ngqkvw, ngqkvb, ngprojw, ngprojb, ngbias,
                                    mergew, mergeb, ctx);
  k_main<<<4096, 256, 131072, stream>>>(x, ctx, pk_qkv, pk_wv, pk_proj, pk_fc1, pk_fc2,
                                        qkvb, projb, bt, n1g, n1b, n2g, n2b, fc1b, fc2b,
                                        (float*)d_out);
}

// Round 2
// 631.580 us; speedup vs baseline: 2.5655x; 2.5655x over previous
//
#include <hip/hip_runtime.h>

// ---------------- types / helpers ----------------
typedef __bf16 bf16x8 __attribute__((ext_vector_type(8)));
typedef float  f32x4  __attribute__((ext_vector_type(4)));

#define QSCALE 0.17677669529663687f   // 32^-0.5 (main attn head_dim=32)

__device__ __forceinline__ f32x4 mfma16(bf16x8 a, bf16x8 b, f32x4 c) {
  return __builtin_amdgcn_mfma_f32_16x16x32_bf16(a, b, c, 0, 0, 0);
}

// row-major [rows][rowChunks*8] bf16 tile with XOR-swizzled 16B chunks
__device__ __forceinline__ int swz_idx(int row, int col, int rowChunks) {
  return row * (rowChunks << 3) + ((((col >> 3) ^ (row & 7)) << 3) | (col & 7));
}

// A/B fragment load from swizzled row-major LDS tile.
__device__ __forceinline__ bf16x8 ld_tile(const __bf16* t, int rowChunks,
                                          int rowBase, int chunkBase, int lane) {
  int row = rowBase + (lane & 15);
  int c = (chunkBase + (lane >> 4)) ^ (row & 7);
  return *(const bf16x8*)(t + row * (rowChunks << 3) + (c << 3));
}

// fragment load from pre-packed global weights (coalesced 1KiB per wave)
__device__ __forceinline__ bf16x8 ld_pack(const __bf16* pk, int nt, int ks,
                                          int ksteps, int lane) {
  int idx = ((nt * ksteps + ks) * 64 + lane) * 8;
  return *(const bf16x8*)(pk + idx);
}

__device__ __forceinline__ int region_of(int hh, int ww) {
  int rh = (hh < 248) ? 0 : ((hh < 252) ? 1 : 2);
  int rw = (ww < 248) ? 0 : ((ww < 252) ? 1 : 2);
  return rh * 3 + rw;
}

// ---------------- K0: pack weights to bf16 fragment order ----------------
__global__ void k_pack(const float* __restrict__ qkvw, const float* __restrict__ projw,
                       const float* __restrict__ fc1w, const float* __restrict__ fc2w,
                       __bf16* __restrict__ pk) {
  int i = blockIdx.x * 256 + threadIdx.x;
  const float* src; int K; int e; int scaleQ = 0;
  if (i < 32768)      { src = qkvw;             K = 128; e = i;          scaleQ = 1; }
  else if (i < 49152) { src = qkvw + 256 * 128; K = 128; e = i - 32768; }
  else if (i < 65536) { src = projw;            K = 128; e = i - 49152; }
  else if (i < 98304) { src = fc1w;             K = 128; e = i - 65536; }
  else                { src = fc2w;             K = 256; e = i - 98304; }
  int i8 = e & 7, ln = (e >> 3) & 63, t = e >> 9;
  int ls = (K == 256) ? 3 : 2;
  int ks = t & ((1 << ls) - 1), nt = t >> ls;
  int row = (nt << 4) + (ln & 15);
  int k = (ks << 5) + ((ln >> 4) << 3) + i8;
  float v = src[row * K + k];
  if (scaleQ && row < 128) v *= QSCALE;
  pk[i] = (__bf16)v;
}

// ---------------- K0b: fused ngram proj+merge weights ----------------
// W1T[e][o] = sum_d mergew[o][d]    * ngprojw[d][e]   (e<64, o<128)
// W2T[e][o] = sum_d mergew[o][64+d] * ngprojw[d][e]
// fb[o] = mergeb[o] + sum_d (mergew[o][d]+mergew[o][64+d]) * ngprojb[d]
__global__ void k_packctx(const float* __restrict__ ngprojw, const float* __restrict__ ngprojb,
                          const float* __restrict__ mergew, const float* __restrict__ mergeb,
                          float* __restrict__ w12T, float* __restrict__ fb) {
  int idx = blockIdx.x * 256 + threadIdx.x;
  if (idx < 16384) {
    int which = idx >> 13;
    int r = idx & 8191;
    int e = r >> 7, o = r & 127;
    float a = 0.f;
#pragma unroll 8
    for (int d = 0; d < 64; ++d)
      a += mergew[o * 128 + which * 64 + d] * ngprojw[d * 64 + e];
    w12T[idx] = a;
  } else if (idx < 16384 + 128) {
    int o = idx - 16384;
    float a = mergeb[o];
#pragma unroll 8
    for (int d = 0; d < 64; ++d)
      a += (mergew[o * 128 + d] + mergew[o * 128 + 64 + d]) * ngprojb[d];
    fb[o] = a;
  }
}

// ---------------- K1: grouped 8x8/stride8 conv -> uni [B][32][32][64] ----------------
__global__ void k_uniconv(const float* __restrict__ x, const float* __restrict__ uw,
                          const float* __restrict__ ub, float* __restrict__ uni) {
  int bidx = blockIdx.x;               // b*1024 + oh*32 + ow
  int b = bidx >> 10, oh = (bidx >> 5) & 31, ow = bidx & 31;
  int d = threadIdx.x;                 // input channel 0..127
  const float* xb = x + (((size_t)((b << 16) + ((oh << 3) << 8) + (ow << 3))) << 7) + d;
  const float* w = uw + d * 64;
  float acc = 0.f;
#pragma unroll
  for (int kh = 0; kh < 8; ++kh)
#pragma unroll
    for (int kw = 0; kw < 8; ++kw)
      acc += xb[(size_t)(((kh << 8) + kw)) << 7] * w[kh * 8 + kw];
  acc += __shfl_xor(acc, 1);
  if (!(d & 1)) uni[((size_t)bidx << 6) + (d >> 1)] = acc + ub[d >> 1];
}

// ---------------- K2: ngram path, 8 windows/block, LDS-staged weights ----------------
// block = 256 thr; grid = 4(b) * 32(i) * 4(jq) = 512
// LDS (floats): qkvT[64][192] | w1T[64][128] | w2T[64][128] | tokl[2][2][9][64]
//               | qs[36][192] | prs[16][4][4] | avgl[16][64] | ngb[192] | fbs[128] | nbias[36]
__global__ void __launch_bounds__(256, 1)
k_ngram(const float* __restrict__ uni, const float* __restrict__ ngqkvw,
        const float* __restrict__ ngqkvb, const float* __restrict__ ngbias,
        const float* __restrict__ w12T, const float* __restrict__ fbg,
        float* __restrict__ ctx) {
  extern __shared__ float sm[];
  float* qkvT = sm;                     // 12288
  float* w1T  = qkvT + 12288;           // 8192
  float* w2T  = w1T + 8192;             // 8192
  float* tokl = w2T + 8192;             // 2304
  float* qs   = tokl + 2304;            // 6912
  float* prs  = qs + 6912;              // 256
  float* avgl = prs + 256;              // 1024
  float* ngb  = avgl + 1024;            // 192
  float* fbs  = ngb + 192;              // 128
  float* nbias= fbs + 128;              // 36

  const int t = threadIdx.x;
  const int bidx = blockIdx.x;
  const int b = bidx >> 7, ii = (bidx >> 2) & 31, jq = bidx & 3;
  const int j0 = jq * 8;

  // ---- P0: stage weights (coalesced global reads) + tokens ----
#pragma unroll
  for (int it = 0; it < 12; ++it) {
    int f = it * 256 + t;               // 0..3071 float4s of ngqkvw
    int o = f >> 4, c4 = (f & 15) << 2;
    float4 v = *(const float4*)(ngqkvw + o * 64 + c4);
    float s = (o < 64) ? 0.25f : 1.f;   // fold 16^-0.5 into q rows
    qkvT[(c4 + 0) * 192 + o] = v.x * s;
    qkvT[(c4 + 1) * 192 + o] = v.y * s;
    qkvT[(c4 + 2) * 192 + o] = v.z * s;
    qkvT[(c4 + 3) * 192 + o] = v.w * s;
  }
#pragma unroll
  for (int it = 0; it < 16; ++it) {     // w1T + w2T contiguous: 16384 floats
    int f = (it * 256 + t) << 2;
    *(float4*)(w1T + f) = *(const float4*)(w12T + f);
  }
  if (t < 192) ngb[t] = ngqkvb[t] * (t < 64 ? 0.25f : 1.f);
  if (t < 128) fbs[t] = fbg[t];
  if (t < 36)  nbias[t] = ngbias[t];
  {
    int w = t >> 6, lane = t & 63;
    int dir = w >> 1, rr = w & 1;
    int pi = ii + rr;
    int srcr = (dir == 0) ? ((pi < 32) ? pi : 30) : ((pi == 0) ? 1 : pi - 1);
#pragma unroll
    for (int cc = 0; cc < 9; ++cc) {
      int pj = j0 + cc;
      int srcc = (dir == 0) ? ((pj < 32) ? pj : 30) : ((pj == 0) ? 1 : pj - 1);
      tokl[((dir * 2 + rr) * 9 + cc) * 64 + lane] =
          uni[(size_t)((b * 32 + srcr) * 32 + srcc) * 64 + lane];
    }
  }
  __syncthreads();

  // ---- P1: qkv for all 36 padded positions (wave -> 9 positions) ----
  {
    int w = t >> 6, lane = t & 63;
    for (int itp = 0; itp < 9; ++itp) {
      int pos = itp * 4 + w;
      const float* tk = tokl + pos * 64;
      float a0 = ngb[lane], a1 = ngb[64 + lane], a2 = ngb[128 + lane];
#pragma unroll 4
      for (int c = 0; c < 64; ++c) {
        float tv = tk[c];
        const float* qr = qkvT + c * 192;
        a0 += qr[lane] * tv;
        a1 += qr[64 + lane] * tv;
        a2 += qr[128 + lane] * tv;
      }
      float* dst = qs + pos * 192;
      dst[lane] = a0; dst[64 + lane] = a1; dst[128 + lane] = a2;
    }
  }
  __syncthreads();

  // ---- P2a: scores + softmax + sum-over-p (thread = (windir, head, qpos)) ----
  {
    int dw = t >> 4;                    // dir = dw>>3, jl = dw&7
    int idx = t & 15, h = idx >> 2, p = idx & 3;
    int dir = dw >> 3, jl = dw & 7;
    const float* qp = qs + ((dir * 2 + (p >> 1)) * 9 + jl + (p & 1)) * 192 + h * 16;
    float s[4];
#pragma unroll
    for (int m = 0; m < 4; ++m) {
      const float* km = qs + ((dir * 2 + (m >> 1)) * 9 + jl + (m & 1)) * 192 + 64 + h * 16;
      float a = 0.f;
#pragma unroll
      for (int e = 0; e < 16; ++e) a += qp[e] * km[e];
      int bi2 = ((p >> 1) - (m >> 1) + 1) * 3 + ((p & 1) - (m & 1) + 1);
      s[m] = a + nbias[bi2 * 4 + h];
    }
    float mx = fmaxf(fmaxf(s[0], s[1]), fmaxf(s[2], s[3]));
    float e0 = __expf(s[0] - mx), e1 = __expf(s[1] - mx);
    float e2 = __expf(s[2] - mx), e3 = __expf(s[3] - mx);
    float inv = 1.f / (e0 + e1 + e2 + e3);
    float p0 = e0 * inv, p1 = e1 * inv, p2 = e2 * inv, p3 = e3 * inv;
    p0 += __shfl_xor(p0, 1); p0 += __shfl_xor(p0, 2);
    p1 += __shfl_xor(p1, 1); p1 += __shfl_xor(p1, 2);
    p2 += __shfl_xor(p2, 1); p2 += __shfl_xor(p2, 2);
    p3 += __shfl_xor(p3, 1); p3 += __shfl_xor(p3, 2);
    if (p == 0) {
      float* d = prs + (dw * 4 + h) * 4;
      d[0] = p0; d[1] = p1; d[2] = p2; d[3] = p3;
    }
  }
  __syncthreads();

  // ---- P2b: avg[windir][c] = 0.25 * sum_m prsum[h(c)][m] * V[m][c] ----
  {
    int w = t >> 6, lane = t & 63;
#pragma unroll
    for (int it = 0; it < 4; ++it) {
      int dw = it * 4 + w;
      int dir = dw >> 3, jl = dw & 7;
      int h = lane >> 4;
      float a = 0.f;
#pragma unroll
      for (int m = 0; m < 4; ++m) {
        float pm = prs[(dw * 4 + h) * 4 + m];
        float vv = qs[((dir * 2 + (m >> 1)) * 9 + jl + (m & 1)) * 192 + 128 + lane];
        a += pm * vv;
      }
      avgl[dw * 64 + lane] = a * 0.25f;
    }
  }
  __syncthreads();

  // ---- P3: ctx[o] = fb[o] + W1T·avg_f + W2T·avg_b, write global (coalesced) ----
  {
#pragma unroll
    for (int it = 0; it < 4; ++it) {
      int id = it * 256 + t;
      int win = id >> 7, o = id & 127;
      const float* af = avgl + win * 64;        // dir 0
      const float* ab = avgl + (8 + win) * 64;  // dir 1
      float a = fbs[o];
#pragma unroll 4
      for (int c = 0; c < 64; ++c)
        a += w1T[c * 128 + o] * af[c] + w2T[c * 128 + o] * ab[c];
      int j = j0 + win;
      ctx[((size_t)((b * 32 + ii) * 32 + j)) * 128 + o] = a;
    }
  }
}

// ---------------- K3: fused window attention + LN + FFN + LN ----------------
__global__ void __launch_bounds__(256, 1)
k_main(const float* __restrict__ xin, const float* __restrict__ ctx,
       const __bf16* __restrict__ pk_qkv, const __bf16* __restrict__ pk_wv,
       const __bf16* __restrict__ pk_proj, const __bf16* __restrict__ pk_fc1,
       const __bf16* __restrict__ pk_fc2,
       const float* __restrict__ qkvb, const float* __restrict__ projb,
       const float* __restrict__ bt,
       const float* __restrict__ n1g, const float* __restrict__ n1b,
       const float* __restrict__ n2g, const float* __restrict__ n2b,
       const float* __restrict__ fc1b, const float* __restrict__ fc2b,
       float* __restrict__ outp) {
  extern __shared__ char smem[];
  __bf16* Xbf = (__bf16*)smem;
  __bf16* QO  = (__bf16*)(smem + 16 * 1024);
  __bf16* Kl  = (__bf16*)(smem + 32 * 1024);
  __bf16* Vt  = (__bf16*)(smem + 48 * 1024);
  __bf16* Pl  = (__bf16*)(smem + 64 * 1024);
  float*  Xf  = (float*)(smem + 96 * 1024);
  float*  Rf  = (float*)(smem + 48 * 1024);
  __bf16* Hl  = (__bf16*)(smem + 16 * 1024);
  float*  Ff  = (float*)(smem + 48 * 1024);

  const int widx = blockIdx.x;
  const int b = widx >> 10, wi = (widx >> 5) & 31, wj = widx & 31;
  const int tid = threadIdx.x;
  const int lane = tid & 63, wv = tid >> 6;
  const int lm = lane & 15, lg = lane >> 4;

  // ---- Phase 0: load tokens (x + ctx) ----
  {
    int n = tid >> 2, q = tid & 3;
    int ts1 = n >> 3, ts2 = n & 7;
    int hh = ((wi << 3) + ts1 + 4) & 255;
    int ww = ((wj << 3) + ts2 + 4) & 255;
    const float* xp = xin + (((size_t)((b << 16) + (hh << 8) + ww)) << 7);
    const float* cp = ctx + (((size_t)((((b << 5) + (hh >> 3)) << 5) + (ww >> 3))) << 7);
#pragma unroll
    for (int jc = 0; jc < 4; ++jc) {
      int c = (q << 2) + jc;
      const float* xs = xp + (c << 3);
      const float* cs = cp + (c << 3);
      float4 xa = *(const float4*)xs;
      float4 xb = *(const float4*)(xs + 4);
      float4 ca = *(const float4*)cs;
      float4 cb = *(const float4*)(cs + 4);
      float v[8];
      v[0] = xa.x + ca.x; v[1] = xa.y + ca.y; v[2] = xa.z + ca.z; v[3] = xa.w + ca.w;
      v[4] = xb.x + cb.x; v[5] = xb.y + cb.y; v[6] = xb.z + cb.z; v[7] = xb.w + cb.w;
      float* xd = Xf + (n << 7) + (c << 3);
      *(float4*)xd = make_float4(v[0], v[1], v[2], v[3]);
      *(float4*)(xd + 4) = make_float4(v[4], v[5], v[6], v[7]);
      bf16x8 p8;
#pragma unroll
      for (int e = 0; e < 8; ++e) p8[e] = (__bf16)v[e];
      *(bf16x8*)(Xbf + (n << 7) + ((c ^ (n & 7)) << 3)) = p8;
    }
  }
  __syncthreads();

  // ---- Phase 1a: Q,K ----
  for (int mt = 0; mt < 4; ++mt) {
    bf16x8 af[4];
#pragma unroll
    for (int ks = 0; ks < 4; ++ks) af[ks] = ld_tile(Xbf, 16, mt * 16, ks * 4, lane);
#pragma unroll
    for (int nt2 = 0; nt2 < 4; ++nt2) {
      int ntG = (wv << 2) + nt2;
      f32x4 acc = {0.f, 0.f, 0.f, 0.f};
#pragma unroll
      for (int ks = 0; ks < 4; ++ks)
        acc = mfma16(af[ks], ld_pack(pk_qkv, ntG, ks, 4, lane), acc);
      int col = (ntG << 4) + lm;
      float bias = (col < 128) ? qkvb[col] * QSCALE : qkvb[col];
      __bf16* dst = (col < 128) ? QO : Kl;
      int cc = col & 127;
#pragma unroll
      for (int r = 0; r < 4; ++r) {
        int row = mt * 16 + lg * 4 + r;
        dst[swz_idx(row, cc, 16)] = (__bf16)(acc[r] + bias);
      }
    }
  }
  // ---- Phase 1b: V^T ----
  for (int mt2 = 0; mt2 < 2; ++mt2) {
    int mtG = (wv << 1) + mt2;
    bf16x8 af[4];
#pragma unroll
    for (int ks = 0; ks < 4; ++ks) af[ks] = ld_pack(pk_wv, mtG, ks, 4, lane);
#pragma unroll
    for (int nt = 0; nt < 4; ++nt) {
      f32x4 acc = {0.f, 0.f, 0.f, 0.f};
#pragma unroll
      for (int ks = 0; ks < 4; ++ks)
        acc = mfma16(af[ks], ld_tile(Xbf, 16, nt * 16, ks * 4, lane), acc);
      int tok = (nt << 4) + lm;
#pragma unroll
      for (int r = 0; r < 4; ++r) {
        int ch = (mtG << 4) + lg * 4 + r;
        Vt[swz_idx(ch, tok, 8)] = (__bf16)(acc[r] + qkvb[256 + ch]);
      }
    }
  }
  __syncthreads();

  // ---- Phase 2: scores + softmax (wave = head) ----
  float rinv[4][4];
  {
    const int h = wv;
    bf16x8 aq[4], bk[4];
#pragma unroll
    for (int t = 0; t < 4; ++t) {
      aq[t] = ld_tile(QO, 16, t * 16, h * 4, lane);
      bk[t] = ld_tile(Kl, 16, t * 16, h * 4, lane);
    }
    f32x4 sc[4][4];
#pragma unroll
    for (int mt = 0; mt < 4; ++mt)
#pragma unroll
      for (int nt = 0; nt < 4; ++nt) {
        f32x4 z = {0.f, 0.f, 0.f, 0.f};
        sc[mt][nt] = mfma16(aq[mt], bk[nt], z);
      }
    int s1m[4], s2m[4], regm[4];
#pragma unroll
    for (int nt = 0; nt < 4; ++nt) {
      int m = nt * 16 + lm;
      s1m[nt] = m >> 3; s2m[nt] = m & 7;
      regm[nt] = region_of(wi * 8 + s1m[nt], wj * 8 + s2m[nt]);
    }
    const bool edge = (wi == 31) || (wj == 31);
    __bf16* Pme = Pl + (wv << 12);
#pragma unroll
    for (int mt = 0; mt < 4; ++mt) {
#pragma unroll
      for (int r = 0; r < 4; ++r) {
        int n = mt * 16 + lg * 4 + r;
        int s1n = n >> 3, s2n = n & 7;
        int regn = region_of(wi * 8 + s1n, wj * 8 + s2n);
        float v[4];
#pragma unroll
        for (int nt = 0; nt < 4; ++nt) {
          int idx = (s1n - s1m[nt] + 7) * 15 + (s2n - s2m[nt] + 7);
          float s = sc[mt][nt][r] + bt[idx * 4 + h];
          if (edge && (regn != regm[nt])) s -= 100.f;
          v[nt] = s;
        }
        float mx = fmaxf(fmaxf(v[0], v[1]), fmaxf(v[2], v[3]));
#pragma unroll
        for (int d = 1; d < 16; d <<= 1) mx = fmaxf(mx, __shfl_xor(mx, d));
        float ssum = 0.f;
#pragma unroll
        for (int nt = 0; nt < 4; ++nt) { v[nt] = __expf(v[nt] - mx); ssum += v[nt]; }
#pragma unroll
        for (int d = 1; d < 16; d <<= 1) ssum += __shfl_xor(ssum, d);
        rinv[mt][r] = 1.f / ssum;
#pragma unroll
        for (int nt = 0; nt < 4; ++nt)
          Pme[swz_idx(n, nt * 16 + lm, 8)] = (__bf16)v[nt];
      }
    }
  }

  // ---- Phase 3: O_h = P @ V_h ----
  {
    const int h = wv;
    const __bf16* Pme = Pl + (wv << 12);
    bf16x8 ap[4][2], bv[2][2];
#pragma unroll
    for (int nt = 0; nt < 2; ++nt)
#pragma unroll
      for (int ks = 0; ks < 2; ++ks)
        bv[nt][ks] = ld_tile(Vt, 8, h * 32 + nt * 16, ks * 4, lane);
#pragma unroll
    for (int mt = 0; mt < 4; ++mt)
#pragma unroll
      for (int ks = 0; ks < 2; ++ks)
        ap[mt][ks] = ld_tile(Pme, 8, mt * 16, ks * 4, lane);
#pragma unroll
    for (int mt = 0; mt < 4; ++mt)
#pragma unroll
      for (int nt = 0; nt < 2; ++nt) {
        f32x4 acc = {0.f, 0.f, 0.f, 0.f};
        acc = mfma16(ap[mt][0], bv[nt][0], acc);
        acc = mfma16(ap[mt][1], bv[nt][1], acc);
        int cc = h * 32 + nt * 16 + lm;
#pragma unroll
        for (int r = 0; r < 4; ++r) {
          int row = mt * 16 + lg * 4 + r;
          QO[swz_idx(row, cc, 16)] = (__bf16)(acc[r] * rinv[mt][r]);
        }
      }
  }
  __syncthreads();

  // ---- Phase 4: R = O @ Wproj + b ----
  for (int mt = 0; mt < 4; ++mt) {
    bf16x8 ao[4];
#pragma unroll
    for (int ks = 0; ks < 4; ++ks) ao[ks] = ld_tile(QO, 16, mt * 16, ks * 4, lane);
#pragma unroll
    for (int nt2 = 0; nt2 < 2; ++nt2) {
      int ntG = (wv << 1) + nt2;
      f32x4 acc = {0.f, 0.f, 0.f, 0.f};
#pragma unroll
      for (int ks = 0; ks < 4; ++ks)
        acc = mfma16(ao[ks], ld_pack(pk_proj, ntG, ks, 4, lane), acc);
      int col = (ntG << 4) + lm;
      float pb = projb[col];
#pragma unroll
      for (int r = 0; r < 4; ++r) {
        int row = mt * 16 + lg * 4 + r;
        Rf[row * 132 + col] = acc[r] + pb;
      }
    }
  }
  __syncthreads();

  // ---- Phase 5: x1 = x + LN(R) ----
  {
    int n = tid >> 2, q = tid & 3;
    const float* rrow = Rf + n * 132 + (q << 5);
    float vals[32];
    float sum1 = 0.f, sum2 = 0.f;
#pragma unroll
    for (int jj = 0; jj < 32; ++jj) { float v = rrow[jj]; vals[jj] = v; sum1 += v; sum2 += v * v; }
    sum1 += __shfl_xor(sum1, 1); sum1 += __shfl_xor(sum1, 2);
    sum2 += __shfl_xor(sum2, 1); sum2 += __shfl_xor(sum2, 2);
    float mean = sum1 * 0.0078125f;
    float var = sum2 * 0.0078125f - mean * mean;
    float rstd = rsqrtf(var + 1e-5f);
    float* xrow = Xf + (n << 7) + (q << 5);
#pragma unroll
    for (int jc = 0; jc < 4; ++jc) {
      bf16x8 p8;
#pragma unroll
      for (int e = 0; e < 8; ++e) {
        int jj = jc * 8 + e; int d = (q << 5) + jj;
        float ln = (vals[jj] - mean) * rstd * n1g[d] + n1b[d];
        float x1 = xrow[jj] + ln;
        xrow[jj] = x1;
        p8[e] = (__bf16)x1;
      }
      int c = (q << 2) + jc;
      *(bf16x8*)(Xbf + (n << 7) + ((c ^ (n & 7)) << 3)) = p8;
    }
  }
  __syncthreads();

  // ---- Phase 6: H = gelu(x1 @ Wfc1 + b) ----
  for (int mt = 0; mt < 4; ++mt) {
    bf16x8 a1[4];
#pragma unroll
    for (int ks = 0; ks < 4; ++ks) a1[ks] = ld_tile(Xbf, 16, mt * 16, ks * 4, lane);
#pragma unroll
    for (int nt2 = 0; nt2 < 4; ++nt2) {
      int ntG = (wv << 2) + nt2;
      f32x4 acc = {0.f, 0.f, 0.f, 0.f};
#pragma unroll
      for (int ks = 0; ks < 4; ++ks)
        acc = mfma16(a1[ks], ld_pack(pk_fc1, ntG, ks, 4, lane), acc);
      int col = (ntG << 4) + lm;
      float b1 = fc1b[col];
#pragma unroll
      for (int r = 0; r < 4; ++r) {
        int row = mt * 16 + lg * 4 + r;
        float hv = acc[r] + b1;
        hv = 0.5f * hv * (1.f + erff(hv * 0.70710678118654752f));
        Hl[swz_idx(row, col, 32)] = (__bf16)hv;
      }
    }
  }
  __syncthreads();

  // ---- Phase 7: F = H @ Wfc2 + b ----
  for (int mt = 0; mt < 4; ++mt) {
    bf16x8 a2[8];
#pragma unroll
    for (int ks = 0; ks < 8; ++ks) a2[ks] = ld_tile(Hl, 32, mt * 16, ks * 4, lane);
#pragma unroll
    for (int nt2 = 0; nt2 < 2; ++nt2) {
      int ntG = (wv << 1) + nt2;
      f32x4 acc = {0.f, 0.f, 0.f, 0.f};
#pragma unroll
      for (int ks = 0; ks < 8; ++ks)
        acc = mfma16(a2[ks], ld_pack(pk_fc2, ntG, ks, 8, lane), acc);
      int col = (ntG << 4) + lm;
      float b2 = fc2b[col];
#pragma unroll
      for (int r = 0; r < 4; ++r) {
        int row = mt * 16 + lg * 4 + r;
        Ff[row * 132 + col] = acc[r] + b2;
      }
    }
  }
  __syncthreads();

  // ---- Phase 8: out = x1 + LN(F) ----
  {
    int n = tid >> 2, q = tid & 3;
    const float* frow = Ff + n * 132 + (q << 5);
    float vals[32];
    float sum1 = 0.f, sum2 = 0.f;
#pragma unroll
    for (int jj = 0; jj < 32; ++jj) { float v = frow[jj]; vals[jj] = v; sum1 += v; sum2 += v * v; }
    sum1 += __shfl_xor(sum1, 1); sum1 += __shfl_xor(sum1, 2);
    sum2 += __shfl_xor(sum2, 1); sum2 += __shfl_xor(sum2, 2);
    float mean = sum1 * 0.0078125f;
    float var = sum2 * 0.0078125f - mean * mean;
    float rstd = rsqrtf(var + 1e-5f);
    int ts1 = n >> 3, ts2 = n & 7;
    int hh = ((wi << 3) + ts1 + 4) & 255;
    int ww = ((wj << 3) + ts2 + 4) & 255;
    float* op = outp + (((size_t)((b << 16) + (hh << 8) + ww)) << 7) + (q << 5);
    const float* xrow = Xf + (n << 7) + (q << 5);
    int dbase = (q << 5);
#pragma unroll
    for (int jj = 0; jj < 32; jj += 4) {
      float4 o4;
      o4.x = xrow[jj + 0] + (vals[jj + 0] - mean) * rstd * n2g[dbase + jj + 0] + n2b[dbase + jj + 0];
      o4.y = xrow[jj + 1] + (vals[jj + 1] - mean) * rstd * n2g[dbase + jj + 1] + n2b[dbase + jj + 1];
      o4.z = xrow[jj + 2] + (vals[jj + 2] - mean) * rstd * n2g[dbase + jj + 2] + n2b[dbase + jj + 2];
      o4.w = xrow[jj + 3] + (vals[jj + 3] - mean) * rstd * n2g[dbase + jj + 3] + n2b[dbase + jj + 3];
      *(float4*)(op + jj) = o4;
    }
  }
}

// ---------------- launch ----------------
extern "C" void kernel_launch(void* const* d_in, const int* in_sizes, int n_in,
                              void* d_out, int out_size, void* d_ws, size_t ws_size,
                              hipStream_t stream) {
  const float* x      = (const float*)d_in[0];
  const float* uni_w  = (const float*)d_in[1];
  const float* uni_b  = (const float*)d_in[2];
  const float* ngqkvw = (const float*)d_in[3];
  const float* ngqkvb = (const float*)d_in[4];
  const float* ngprojw= (const float*)d_in[5];
  const float* ngprojb= (const float*)d_in[6];
  const float* ngbias = (const float*)d_in[7];
  const float* mergew = (const float*)d_in[8];
  const float* mergeb = (const float*)d_in[9];
  const float* qkvw   = (const float*)d_in[10];
  const float* qkvb   = (const float*)d_in[11];
  const float* projw  = (const float*)d_in[12];
  const float* projb  = (const float*)d_in[13];
  const float* bt     = (const float*)d_in[14];
  const float* n1g    = (const float*)d_in[15];
  const float* n1b    = (const float*)d_in[16];
  const float* n2g    = (const float*)d_in[17];
  const float* n2b    = (const float*)d_in[18];
  const float* fc1w   = (const float*)d_in[19];
  const float* fc1b   = (const float*)d_in[20];
  const float* fc2w   = (const float*)d_in[21];
  const float* fc2b   = (const float*)d_in[22];

  char* ws = (char*)d_ws;
  float*  uni = (float*)ws;                   // 1 MiB : [4][32][32][64]
  float*  ctx = (float*)(ws + (1 << 20));     // 2 MiB : [4][32][32][128]
  __bf16* pk  = (__bf16*)(ws + (3 << 20));    // 256 KiB packed weights
  __bf16* pk_qkv  = pk;
  __bf16* pk_wv   = pk + 32768;
  __bf16* pk_proj = pk + 49152;
  __bf16* pk_fc1  = pk + 65536;
  __bf16* pk_fc2  = pk + 98304;
  float*  w12T = (float*)(ws + (7 << 19));    // 3.5 MiB: [2][64][128] fused ctx weights
  float*  fb   = w12T + 16384;                // fused ctx bias [128]

  k_pack<<<512, 256, 0, stream>>>(qkvw, projw, fc1w, fc2w, pk);
  k_packctx<<<65, 256, 0, stream>>>(ngprojw, ngprojb, mergew, mergeb, w12T, fb);
  k_uniconv<<<4096, 128, 0, stream>>>(x, uni_w, uni_b, uni);
  k_ngram<<<512, 256, 158096, stream>>>(uni, ngqkvw, ngqkvb, ngbias, w12T, fb, ctx);
  k_main<<<4096, 256, 131072, stream>>>(x, ctx, pk_qkv, pk_wv, pk_proj, pk_fc1, pk_fc2,
                                        qkvb, projb, bt, n1g, n1b, n2g, n2b, fc1b, fc2b,
                                        (float*)d_out);
}

// Round 5
// 537.921 us; speedup vs baseline: 3.0122x; 1.1741x over previous
//
#include <hip/hip_runtime.h>

// ---------------- types / helpers ----------------
typedef __bf16 bf16x8 __attribute__((ext_vector_type(8)));
typedef float  f32x4  __attribute__((ext_vector_type(4)));

#define QSCALE 0.17677669529663687f   // 32^-0.5 (main attn head_dim=32)
#define XF_LD 130                     // f32 tile stride: 130 ≡ 2 (mod 32) -> 4-way max

__device__ __forceinline__ f32x4 mfma16(bf16x8 a, bf16x8 b, f32x4 c) {
  return __builtin_amdgcn_mfma_f32_16x16x32_bf16(a, b, c, 0, 0, 0);
}

// row-major [rows][rowChunks*8] bf16 tile with XOR-swizzled 16B chunks
__device__ __forceinline__ int swz_idx(int row, int col, int rowChunks) {
  return row * (rowChunks << 3) + ((((col >> 3) ^ (row & 7)) << 3) | (col & 7));
}

// A/B fragment load from swizzled row-major LDS tile.
__device__ __forceinline__ bf16x8 ld_tile(const __bf16* t, int rowChunks,
                                          int rowBase, int chunkBase, int lane) {
  int row = rowBase + (lane & 15);
  int c = (chunkBase + (lane >> 4)) ^ (row & 7);
  return *(const bf16x8*)(t + row * (rowChunks << 3) + (c << 3));
}

// fragment load from pre-packed global weights (coalesced 1KiB per wave)
__device__ __forceinline__ bf16x8 ld_pack(const __bf16* pk, int nt, int ks,
                                          int ksteps, int lane) {
  int idx = ((nt * ksteps + ks) * 64 + lane) * 8;
  return *(const bf16x8*)(pk + idx);
}

__device__ __forceinline__ int region_of(int hh, int ww) {
  int rh = (hh < 248) ? 0 : ((hh < 252) ? 1 : 2);
  int rw = (ww < 248) ? 0 : ((ww < 252) ? 1 : 2);
  return rh * 3 + rw;
}

// ---------------- K0: pack weights to bf16 fragment order ----------------
__global__ void k_pack(const float* __restrict__ qkvw, const float* __restrict__ projw,
                       const float* __restrict__ fc1w, const float* __restrict__ fc2w,
                       __bf16* __restrict__ pk) {
  int i = blockIdx.x * 256 + threadIdx.x;
  const float* src; int K; int e; int scaleQ = 0;
  if (i < 32768)      { src = qkvw;             K = 128; e = i;          scaleQ = 1; }
  else if (i < 49152) { src = qkvw + 256 * 128; K = 128; e = i - 32768; }
  else if (i < 65536) { src = projw;            K = 128; e = i - 49152; }
  else if (i < 98304) { src = fc1w;             K = 128; e = i - 65536; }
  else                { src = fc2w;             K = 256; e = i - 98304; }
  int i8 = e & 7, ln = (e >> 3) & 63, t = e >> 9;
  int ls = (K == 256) ? 3 : 2;
  int ks = t & ((1 << ls) - 1), nt = t >> ls;
  int row = (nt << 4) + (ln & 15);
  int k = (ks << 5) + ((ln >> 4) << 3) + i8;
  float v = src[row * K + k];
  if (scaleQ && row < 128) v *= QSCALE;
  pk[i] = (__bf16)v;
}

// ---------------- K0b: fused ngram proj+merge weights ----------------
__global__ void k_packctx(const float* __restrict__ ngprojw, const float* __restrict__ ngprojb,
                          const float* __restrict__ mergew, const float* __restrict__ mergeb,
                          float* __restrict__ w12T, float* __restrict__ fb) {
  int idx = blockIdx.x * 256 + threadIdx.x;
  if (idx < 16384) {
    int which = idx >> 13;
    int r = idx & 8191;
    int e = r >> 7, o = r & 127;
    float a = 0.f;
#pragma unroll 8
    for (int d = 0; d < 64; ++d)
      a += mergew[o * 128 + which * 64 + d] * ngprojw[d * 64 + e];
    w12T[idx] = a;
  } else if (idx < 16384 + 128) {
    int o = idx - 16384;
    float a = mergeb[o];
#pragma unroll 8
    for (int d = 0; d < 64; ++d)
      a += (mergew[o * 128 + d] + mergew[o * 128 + 64 + d]) * ngprojb[d];
    fb[o] = a;
  }
}

// ---------------- K1: grouped 8x8/stride8 conv -> uni [B][32][32][64] ----------------
__global__ void k_uniconv(const float* __restrict__ x, const float* __restrict__ uw,
                          const float* __restrict__ ub, float* __restrict__ uni) {
  int bidx = blockIdx.x;               // b*1024 + oh*32 + ow
  int b = bidx >> 10, oh = (bidx >> 5) & 31, ow = bidx & 31;
  int d = threadIdx.x;                 // input channel 0..127
  const float* xb = x + (((size_t)((b << 16) + ((oh << 3) << 8) + (ow << 3))) << 7) + d;
  const float* w = uw + d * 64;
  float acc = 0.f;
#pragma unroll
  for (int kh = 0; kh < 8; ++kh)
#pragma unroll
    for (int kw = 0; kw < 8; ++kw)
      acc += xb[(size_t)(((kh << 8) + kw)) << 7] * w[kh * 8 + kw];
  acc += __shfl_xor(acc, 1);
  if (!(d & 1)) uni[((size_t)bidx << 6) + (d >> 1)] = acc + ub[d >> 1];
}

// ---------------- K2: ngram path, 8 windows/block, LDS-staged weights ----------------
__global__ void __launch_bounds__(256, 1)
k_ngram(const float* __restrict__ uni, const float* __restrict__ ngqkvw,
        const float* __restrict__ ngqkvb, const float* __restrict__ ngbias,
        const float* __restrict__ w12T, const float* __restrict__ fbg,
        float* __restrict__ ctx) {
  extern __shared__ float sm[];
  float* qkvT = sm;                     // 12288
  float* w1T  = qkvT + 12288;           // 8192
  float* w2T  = w1T + 8192;             // 8192
  float* tokl = w2T + 8192;             // 2304
  float* qs   = tokl + 2304;            // 6912
  float* prs  = qs + 6912;              // 256
  float* avgl = prs + 256;              // 1024
  float* ngb  = avgl + 1024;            // 192
  float* fbs  = ngb + 192;              // 128
  float* nbias= fbs + 128;              // 36

  const int t = threadIdx.x;
  const int bidx = blockIdx.x;
  const int b = bidx >> 7, ii = (bidx >> 2) & 31, jq = bidx & 3;
  const int j0 = jq * 8;

#pragma unroll
  for (int it = 0; it < 12; ++it) {
    int f = it * 256 + t;
    int o = f >> 4, c4 = (f & 15) << 2;
    float4 v = *(const float4*)(ngqkvw + o * 64 + c4);
    float s = (o < 64) ? 0.25f : 1.f;
    qkvT[(c4 + 0) * 192 + o] = v.x * s;
    qkvT[(c4 + 1) * 192 + o] = v.y * s;
    qkvT[(c4 + 2) * 192 + o] = v.z * s;
    qkvT[(c4 + 3) * 192 + o] = v.w * s;
  }
#pragma unroll
  for (int it = 0; it < 16; ++it) {
    int f = (it * 256 + t) << 2;
    *(float4*)(w1T + f) = *(const float4*)(w12T + f);
  }
  if (t < 192) ngb[t] = ngqkvb[t] * (t < 64 ? 0.25f : 1.f);
  if (t < 128) fbs[t] = fbg[t];
  if (t < 36)  nbias[t] = ngbias[t];
  {
    int w = t >> 6, lane = t & 63;
    int dir = w >> 1, rr = w & 1;
    int pi = ii + rr;
    int srcr = (dir == 0) ? ((pi < 32) ? pi : 30) : ((pi == 0) ? 1 : pi - 1);
#pragma unroll
    for (int cc = 0; cc < 9; ++cc) {
      int pj = j0 + cc;
      int srcc = (dir == 0) ? ((pj < 32) ? pj : 30) : ((pj == 0) ? 1 : pj - 1);
      tokl[((dir * 2 + rr) * 9 + cc) * 64 + lane] =
          uni[(size_t)((b * 32 + srcr) * 32 + srcc) * 64 + lane];
    }
  }
  __syncthreads();

  {
    int w = t >> 6, lane = t & 63;
    for (int itp = 0; itp < 9; ++itp) {
      int pos = itp * 4 + w;
      const float* tk = tokl + pos * 64;
      float a0 = ngb[lane], a1 = ngb[64 + lane], a2 = ngb[128 + lane];
#pragma unroll 4
      for (int c = 0; c < 64; ++c) {
        float tv = tk[c];
        const float* qr = qkvT + c * 192;
        a0 += qr[lane] * tv;
        a1 += qr[64 + lane] * tv;
        a2 += qr[128 + lane] * tv;
      }
      float* dst = qs + pos * 192;
      dst[lane] = a0; dst[64 + lane] = a1; dst[128 + lane] = a2;
    }
  }
  __syncthreads();

  {
    int dw = t >> 4;
    int idx = t & 15, h = idx >> 2, p = idx & 3;
    int dir = dw >> 3, jl = dw & 7;
    const float* qp = qs + ((dir * 2 + (p >> 1)) * 9 + jl + (p & 1)) * 192 + h * 16;
    float s[4];
#pragma unroll
    for (int m = 0; m < 4; ++m) {
      const float* km = qs + ((dir * 2 + (m >> 1)) * 9 + jl + (m & 1)) * 192 + 64 + h * 16;
      float a = 0.f;
#pragma unroll
      for (int e = 0; e < 16; ++e) a += qp[e] * km[e];
      int bi2 = ((p >> 1) - (m >> 1) + 1) * 3 + ((p & 1) - (m & 1) + 1);
      s[m] = a + nbias[bi2 * 4 + h];
    }
    float mx = fmaxf(fmaxf(s[0], s[1]), fmaxf(s[2], s[3]));
    float e0 = __expf(s[0] - mx), e1 = __expf(s[1] - mx);
    float e2 = __expf(s[2] - mx), e3 = __expf(s[3] - mx);
    float inv = 1.f / (e0 + e1 + e2 + e3);
    float p0 = e0 * inv, p1 = e1 * inv, p2 = e2 * inv, p3 = e3 * inv;
    p0 += __shfl_xor(p0, 1); p0 += __shfl_xor(p0, 2);
    p1 += __shfl_xor(p1, 1); p1 += __shfl_xor(p1, 2);
    p2 += __shfl_xor(p2, 1); p2 += __shfl_xor(p2, 2);
    p3 += __shfl_xor(p3, 1); p3 += __shfl_xor(p3, 2);
    if (p == 0) {
      float* d = prs + (dw * 4 + h) * 4;
      d[0] = p0; d[1] = p1; d[2] = p2; d[3] = p3;
    }
  }
  __syncthreads();

  {
    int w = t >> 6, lane = t & 63;
#pragma unroll
    for (int it = 0; it < 4; ++it) {
      int dw = it * 4 + w;
      int dir = dw >> 3, jl = dw & 7;
      int h = lane >> 4;
      float a = 0.f;
#pragma unroll
      for (int m = 0; m < 4; ++m) {
        float pm = prs[(dw * 4 + h) * 4 + m];
        float vv = qs[((dir * 2 + (m >> 1)) * 9 + jl + (m & 1)) * 192 + 128 + lane];
        a += pm * vv;
      }
      avgl[dw * 64 + lane] = a * 0.25f;
    }
  }
  __syncthreads();

  {
#pragma unroll
    for (int it = 0; it < 4; ++it) {
      int id = it * 256 + t;
      int win = id >> 7, o = id & 127;
      const float* af = avgl + win * 64;
      const float* ab = avgl + (8 + win) * 64;
      float a = fbs[o];
#pragma unroll 4
      for (int c = 0; c < 64; ++c)
        a += w1T[c * 128 + o] * af[c] + w2T[c * 128 + o] * ab[c];
      int j = j0 + win;
      ctx[((size_t)((b * 32 + ii) * 32 + j)) * 128 + o] = a;
    }
  }
}

// ---------------- K3: fused window attention + LN + FFN + LN ----------------
// LDS map (128.5 KiB, 1 block/CU) — R2-passing layout, strides de-conflicted:
//  [0,16K)   Xbf  [64][128] bf16 swz : tokens (x+ctx) -> later x1 bf16
//  [16K,32K) QO   [64][128] bf16 swz : Q then O  | Hl [64][256] with Kl in FFN
//  [32K,48K) Kl   [64][128] bf16 swz
//  [48K,64K) Vt   [128][64] bf16 swz  | Rf/Ff f32 [64][130] after attn
//  [64K,96K) Pl   [4][64][64] bf16 swz
//  [96K,128.5K) Xf [64][130] f32 : x+ctx -> x1 (stride 130: 4-way max conflicts)
__global__ void __launch_bounds__(256, 1)
k_main(const float* __restrict__ xin, const float* __restrict__ ctx,
       const __bf16* __restrict__ pk_qkv, const __bf16* __restrict__ pk_wv,
       const __bf16* __restrict__ pk_proj, const __bf16* __restrict__ pk_fc1,
       const __bf16* __restrict__ pk_fc2,
       const float* __restrict__ qkvb, const float* __restrict__ projb,
       const float* __restrict__ bt,
       const float* __restrict__ n1g, const float* __restrict__ n1b,
       const float* __restrict__ n2g, const float* __restrict__ n2b,
       const float* __restrict__ fc1b, const float* __restrict__ fc2b,
       float* __restrict__ outp) {
  extern __shared__ char smem[];
  __bf16* Xbf = (__bf16*)smem;
  __bf16* QO  = (__bf16*)(smem + 16 * 1024);
  __bf16* Kl  = (__bf16*)(smem + 32 * 1024);
  __bf16* Vt  = (__bf16*)(smem + 48 * 1024);
  __bf16* Pl  = (__bf16*)(smem + 64 * 1024);
  float*  Xf  = (float*)(smem + 96 * 1024);
  float*  Rf  = (float*)(smem + 48 * 1024);   // [64][130] f32 (aliases Vt+P-head, dead)
  __bf16* Hl  = (__bf16*)(smem + 16 * 1024);  // [64][256] bf16 swz (aliases QO+Kl, FFN)
  float*  Ff  = (float*)(smem + 48 * 1024);   // [64][130] f32

  const int widx = blockIdx.x;
  const int b = widx >> 10, wi = (widx >> 5) & 31, wj = widx & 31;
  const int tid = threadIdx.x;
  const int lane = tid & 63, wv = tid >> 6;
  const int lm = lane & 15, lg = lane >> 4;

  // ---- Phase 0: load tokens (x + ctx), write Xf (f32) and Xbf (bf16 swz) ----
  {
    int n = tid >> 2, q = tid & 3;
    int ts1 = n >> 3, ts2 = n & 7;
    int hh = ((wi << 3) + ts1 + 4) & 255;
    int ww = ((wj << 3) + ts2 + 4) & 255;
    const float* xp = xin + (((size_t)((b << 16) + (hh << 8) + ww)) << 7);
    const float* cp = ctx + (((size_t)((((b << 5) + (hh >> 3)) << 5) + (ww >> 3))) << 7);
#pragma unroll
    for (int jc = 0; jc < 4; ++jc) {
      int c = (q << 2) + jc;                // bf16 chunk 0..15 (8 elems)
      const float* xs = xp + (c << 3);
      const float* cs = cp + (c << 3);
      float4 xa = *(const float4*)xs;
      float4 xb = *(const float4*)(xs + 4);
      float4 ca = *(const float4*)cs;
      float4 cb = *(const float4*)(cs + 4);
      float v[8];
      v[0] = xa.x + ca.x; v[1] = xa.y + ca.y; v[2] = xa.z + ca.z; v[3] = xa.w + ca.w;
      v[4] = xb.x + cb.x; v[5] = xb.y + cb.y; v[6] = xb.z + cb.z; v[7] = xb.w + cb.w;
      float* xd = Xf + n * XF_LD + (c << 3);
      *(float4*)xd = make_float4(v[0], v[1], v[2], v[3]);
      *(float4*)(xd + 4) = make_float4(v[4], v[5], v[6], v[7]);
      bf16x8 p8;
#pragma unroll
      for (int e = 0; e < 8; ++e) p8[e] = (__bf16)v[e];
      *(bf16x8*)(Xbf + (n << 7) + ((c ^ (n & 7)) << 3)) = p8;
    }
  }
  __syncthreads();

  // ---- Phase 1a: Q,K = X @ Wqk (wave -> 4 ntiles of 16 cols) ----
  for (int mt = 0; mt < 4; ++mt) {
    bf16x8 af[4];
#pragma unroll
    for (int ks = 0; ks < 4; ++ks) af[ks] = ld_tile(Xbf, 16, mt * 16, ks * 4, lane);
#pragma unroll
    for (int nt2 = 0; nt2 < 4; ++nt2) {
      int ntG = (wv << 2) + nt2;            // 0..15 over 256 q/k cols
      f32x4 acc = {0.f, 0.f, 0.f, 0.f};
#pragma unroll
      for (int ks = 0; ks < 4; ++ks)
        acc = mfma16(af[ks], ld_pack(pk_qkv, ntG, ks, 4, lane), acc);
      int col = (ntG << 4) + lm;            // qkv channel 0..255
      float bias = (col < 128) ? qkvb[col] * QSCALE : qkvb[col];
      __bf16* dst = (col < 128) ? QO : Kl;
      int cc = col & 127;
#pragma unroll
      for (int r = 0; r < 4; ++r) {
        int row = mt * 16 + lg * 4 + r;
        dst[swz_idx(row, cc, 16)] = (__bf16)(acc[r] + bias);
      }
    }
  }
  // ---- Phase 1b: V^T = Wv @ X^T (wave -> 2 mtiles of 16 ch) ----
  for (int mt2 = 0; mt2 < 2; ++mt2) {
    int mtG = (wv << 1) + mt2;              // ch tile 0..7
    bf16x8 af[4];
#pragma unroll
    for (int ks = 0; ks < 4; ++ks) af[ks] = ld_pack(pk_wv, mtG, ks, 4, lane);
#pragma unroll
    for (int nt = 0; nt < 4; ++nt) {
      f32x4 acc = {0.f, 0.f, 0.f, 0.f};
#pragma unroll
      for (int ks = 0; ks < 4; ++ks)
        acc = mfma16(af[ks], ld_tile(Xbf, 16, nt * 16, ks * 4, lane), acc);
      int tok = (nt << 4) + lm;
#pragma unroll
      for (int r = 0; r < 4; ++r) {
        int ch = (mtG << 4) + lg * 4 + r;
        Vt[swz_idx(ch, tok, 8)] = (__bf16)(acc[r] + qkvb[256 + ch]);
      }
    }
  }
  __syncthreads();

  // ---- Phase 2: scores + softmax (wave = head) ----
  float rinv[4][4];
  {
    const int h = wv;
    bf16x8 aq[4], bk[4];
#pragma unroll
    for (int t = 0; t < 4; ++t) {
      aq[t] = ld_tile(QO, 16, t * 16, h * 4, lane);
      bk[t] = ld_tile(Kl, 16, t * 16, h * 4, lane);
    }
    f32x4 sc[4][4];
#pragma unroll
    for (int mt = 0; mt < 4; ++mt)
#pragma unroll
      for (int nt = 0; nt < 4; ++nt) {
        f32x4 z = {0.f, 0.f, 0.f, 0.f};
        sc[mt][nt] = mfma16(aq[mt], bk[nt], z);
      }
    int s1m[4], s2m[4], regm[4];
#pragma unroll
    for (int nt = 0; nt < 4; ++nt) {
      int m = nt * 16 + lm;
      s1m[nt] = m >> 3; s2m[nt] = m & 7;
      regm[nt] = region_of(wi * 8 + s1m[nt], wj * 8 + s2m[nt]);
    }
    const bool edge = (wi == 31) || (wj == 31);
    __bf16* Pme = Pl + (wv << 12);
#pragma unroll
    for (int mt = 0; mt < 4; ++mt) {
#pragma unroll
      for (int r = 0; r < 4; ++r) {
        int n = mt * 16 + lg * 4 + r;
        int s1n = n >> 3, s2n = n & 7;
        int regn = region_of(wi * 8 + s1n, wj * 8 + s2n);
        float v[4];
#pragma unroll
        for (int nt = 0; nt < 4; ++nt) {
          int idx = (s1n - s1m[nt] + 7) * 15 + (s2n - s2m[nt] + 7);
          float s = sc[mt][nt][r] + bt[idx * 4 + h];
          if (edge && (regn != regm[nt])) s -= 100.f;
          v[nt] = s;
        }
        float mx = fmaxf(fmaxf(v[0], v[1]), fmaxf(v[2], v[3]));
#pragma unroll
        for (int d = 1; d < 16; d <<= 1) mx = fmaxf(mx, __shfl_xor(mx, d));
        float ssum = 0.f;
#pragma unroll
        for (int nt = 0; nt < 4; ++nt) { v[nt] = __expf(v[nt] - mx); ssum += v[nt]; }
#pragma unroll
        for (int d = 1; d < 16; d <<= 1) ssum += __shfl_xor(ssum, d);
        rinv[mt][r] = 1.f / ssum;
#pragma unroll
        for (int nt = 0; nt < 4; ++nt)
          Pme[swz_idx(n, nt * 16 + lm, 8)] = (__bf16)v[nt];
      }
    }
  }

  // ---- Phase 3: O_h = P @ V_h (scale by 1/rowsum), write into QO cols h*32.. ----
  {
    const int h = wv;
    const __bf16* Pme = Pl + (wv << 12);
    bf16x8 ap[4][2], bv[2][2];
#pragma unroll
    for (int nt = 0; nt < 2; ++nt)
#pragma unroll
      for (int ks = 0; ks < 2; ++ks)
        bv[nt][ks] = ld_tile(Vt, 8, h * 32 + nt * 16, ks * 4, lane);
#pragma unroll
    for (int mt = 0; mt < 4; ++mt)
#pragma unroll
      for (int ks = 0; ks < 2; ++ks)
        ap[mt][ks] = ld_tile(Pme, 8, mt * 16, ks * 4, lane);
#pragma unroll
    for (int mt = 0; mt < 4; ++mt)
#pragma unroll
      for (int nt = 0; nt < 2; ++nt) {
        f32x4 acc = {0.f, 0.f, 0.f, 0.f};
        acc = mfma16(ap[mt][0], bv[nt][0], acc);
        acc = mfma16(ap[mt][1], bv[nt][1], acc);
        int cc = h * 32 + nt * 16 + lm;
#pragma unroll
        for (int r = 0; r < 4; ++r) {
          int row = mt * 16 + lg * 4 + r;
          QO[swz_idx(row, cc, 16)] = (__bf16)(acc[r] * rinv[mt][r]);
        }
      }
  }
  __syncthreads();

  // ---- Phase 4: R = O @ Wproj + b -> Rf f32 ----
  for (int mt = 0; mt < 4; ++mt) {
    bf16x8 ao[4];
#pragma unroll
    for (int ks = 0; ks < 4; ++ks) ao[ks] = ld_tile(QO, 16, mt * 16, ks * 4, lane);
#pragma unroll
    for (int nt2 = 0; nt2 < 2; ++nt2) {
      int ntG = (wv << 1) + nt2;
      f32x4 acc = {0.f, 0.f, 0.f, 0.f};
#pragma unroll
      for (int ks = 0; ks < 4; ++ks)
        acc = mfma16(ao[ks], ld_pack(pk_proj, ntG, ks, 4, lane), acc);
      int col = (ntG << 4) + lm;
      float pb = projb[col];
#pragma unroll
      for (int r = 0; r < 4; ++r) {
        int row = mt * 16 + lg * 4 + r;
        Rf[row * XF_LD + col] = acc[r] + pb;
      }
    }
  }
  __syncthreads();

  // ---- Phase 5: x1 = x + LN(R); residual uses PRISTINE x (reload); store f32->Xf, bf16->Xbf
  {
    int n = tid >> 2, q = tid & 3;
    int ts1 = n >> 3, ts2 = n & 7;
    int hh = ((wi << 3) + ts1 + 4) & 255;
    int ww = ((wj << 3) + ts2 + 4) & 255;
    const float* xp = xin + (((size_t)((b << 16) + (hh << 8) + ww)) << 7) + (q << 5);
    float xv[32];
#pragma unroll
    for (int j4 = 0; j4 < 8; ++j4) {
      float4 v4 = *(const float4*)(xp + (j4 << 2));
      xv[j4 * 4 + 0] = v4.x; xv[j4 * 4 + 1] = v4.y;
      xv[j4 * 4 + 2] = v4.z; xv[j4 * 4 + 3] = v4.w;
    }
    const float* rrow = Rf + n * XF_LD + (q << 5);
    float vals[32];
    float sum1 = 0.f, sum2 = 0.f;
#pragma unroll
    for (int jj = 0; jj < 32; ++jj) { float v = rrow[jj]; vals[jj] = v; sum1 += v; sum2 += v * v; }
    sum1 += __shfl_xor(sum1, 1); sum1 += __shfl_xor(sum1, 2);
    sum2 += __shfl_xor(sum2, 1); sum2 += __shfl_xor(sum2, 2);
    float mean = sum1 * 0.0078125f;
    float var = sum2 * 0.0078125f - mean * mean;
    float rstd = rsqrtf(var + 1e-5f);
    float* xrow = Xf + n * XF_LD + (q << 5);
#pragma unroll
    for (int jc = 0; jc < 4; ++jc) {
      bf16x8 p8;
#pragma unroll
      for (int e = 0; e < 8; ++e) {
        int jj = jc * 8 + e; int d = (q << 5) + jj;
        float ln = (vals[jj] - mean) * rstd * n1g[d] + n1b[d];
        float x1 = xv[jj] + ln;
        xrow[jj] = x1;
        p8[e] = (__bf16)x1;
      }
      int c = (q << 2) + jc;
      *(bf16x8*)(Xbf + (n << 7) + ((c ^ (n & 7)) << 3)) = p8;
    }
  }
  __syncthreads();

  // ---- Phase 6: H = gelu(x1 @ Wfc1 + b) -> Hl bf16 swz ----
  for (int mt = 0; mt < 4; ++mt) {
    bf16x8 a1[4];
#pragma unroll
    for (int ks = 0; ks < 4; ++ks) a1[ks] = ld_tile(Xbf, 16, mt * 16, ks * 4, lane);
#pragma unroll
    for (int nt2 = 0; nt2 < 4; ++nt2) {
      int ntG = (wv << 2) + nt2;            // 0..15 over 256 cols
      f32x4 acc = {0.f, 0.f, 0.f, 0.f};
#pragma unroll
      for (int ks = 0; ks < 4; ++ks)
        acc = mfma16(a1[ks], ld_pack(pk_fc1, ntG, ks, 4, lane), acc);
      int col = (ntG << 4) + lm;
      float b1 = fc1b[col];
#pragma unroll
      for (int r = 0; r < 4; ++r) {
        int row = mt * 16 + lg * 4 + r;
        float hv = acc[r] + b1;
        hv = 0.5f * hv * (1.f + erff(hv * 0.70710678118654752f));
        Hl[swz_idx(row, col, 32)] = (__bf16)hv;
      }
    }
  }
  __syncthreads();

  // ---- Phase 7: F = H @ Wfc2 + b -> Ff f32 ----
  for (int mt = 0; mt < 4; ++mt) {
    bf16x8 a2[8];
#pragma unroll
    for (int ks = 0; ks < 8; ++ks) a2[ks] = ld_tile(Hl, 32, mt * 16, ks * 4, lane);
#pragma unroll
    for (int nt2 = 0; nt2 < 2; ++nt2) {
      int ntG = (wv << 1) + nt2;
      f32x4 acc = {0.f, 0.f, 0.f, 0.f};
#pragma unroll
      for (int ks = 0; ks < 8; ++ks)
        acc = mfma16(a2[ks], ld_pack(pk_fc2, ntG, ks, 8, lane), acc);
      int col = (ntG << 4) + lm;
      float b2 = fc2b[col];
#pragma unroll
      for (int r = 0; r < 4; ++r) {
        int row = mt * 16 + lg * 4 + r;
        Ff[row * XF_LD + col] = acc[r] + b2;
      }
    }
  }
  __syncthreads();

  // ---- Phase 8: out = x1 + LN(F), scatter back to original positions ----
  {
    int n = tid >> 2, q = tid & 3;
    const float* frow = Ff + n * XF_LD + (q << 5);
    float vals[32];
    float sum1 = 0.f, sum2 = 0.f;
#pragma unroll
    for (int jj = 0; jj < 32; ++jj) { float v = frow[jj]; vals[jj] = v; sum1 += v; sum2 += v * v; }
    sum1 += __shfl_xor(sum1, 1); sum1 += __shfl_xor(sum1, 2);
    sum2 += __shfl_xor(sum2, 1); sum2 += __shfl_xor(sum2, 2);
    float mean = sum1 * 0.0078125f;
    float var = sum2 * 0.0078125f - mean * mean;
    float rstd = rsqrtf(var + 1e-5f);
    int ts1 = n >> 3, ts2 = n & 7;
    int hh = ((wi << 3) + ts1 + 4) & 255;
    int ww = ((wj << 3) + ts2 + 4) & 255;
    float* op = outp + (((size_t)((b << 16) + (hh << 8) + ww)) << 7) + (q << 5);
    const float* xrow = Xf + n * XF_LD + (q << 5);
    int dbase = (q << 5);
#pragma unroll
    for (int jj = 0; jj < 32; jj += 4) {
      float4 o4;
      o4.x = xrow[jj + 0] + (vals[jj + 0] - mean) * rstd * n2g[dbase + jj + 0] + n2b[dbase + jj + 0];
      o4.y = xrow[jj + 1] + (vals[jj + 1] - mean) * rstd * n2g[dbase + jj + 1] + n2b[dbase + jj + 1];
      o4.z = xrow[jj + 2] + (vals[jj + 2] - mean) * rstd * n2g[dbase + jj + 2] + n2b[dbase + jj + 2];
      o4.w = xrow[jj + 3] + (vals[jj + 3] - mean) * rstd * n2g[dbase + jj + 3] + n2b[dbase + jj + 3];
      *(float4*)(op + jj) = o4;
    }
  }
}

// ---------------- launch ----------------
extern "C" void kernel_launch(void* const* d_in, const int* in_sizes, int n_in,
                              void* d_out, int out_size, void* d_ws, size_t ws_size,
                              hipStream_t stream) {
  const float* x      = (const float*)d_in[0];
  const float* uni_w  = (const float*)d_in[1];
  const float* uni_b  = (const float*)d_in[2];
  const float* ngqkvw = (const float*)d_in[3];
  const float* ngqkvb = (const float*)d_in[4];
  const float* ngprojw= (const float*)d_in[5];
  const float* ngprojb= (const float*)d_in[6];
  const float* ngbias = (const float*)d_in[7];
  const float* mergew = (const float*)d_in[8];
  const float* mergeb = (const float*)d_in[9];
  const float* qkvw   = (const float*)d_in[10];
  const float* qkvb   = (const float*)d_in[11];
  const float* projw  = (const float*)d_in[12];
  const float* projb  = (const float*)d_in[13];
  const float* bt     = (const float*)d_in[14];
  const float* n1g    = (const float*)d_in[15];
  const float* n1b    = (const float*)d_in[16];
  const float* n2g    = (const float*)d_in[17];
  const float* n2b    = (const float*)d_in[18];
  const float* fc1w   = (const float*)d_in[19];
  const float* fc1b   = (const float*)d_in[20];
  const float* fc2w   = (const float*)d_in[21];
  const float* fc2b   = (const float*)d_in[22];

  char* ws = (char*)d_ws;
  float*  uni = (float*)ws;                   // 1 MiB : [4][32][32][64]
  float*  ctx = (float*)(ws + (1 << 20));     // 2 MiB : [4][32][32][128]
  __bf16* pk  = (__bf16*)(ws + (3 << 20));    // 256 KiB packed weights
  __bf16* pk_qkv  = pk;
  __bf16* pk_wv   = pk + 32768;
  __bf16* pk_proj = pk + 49152;
  __bf16* pk_fc1  = pk + 65536;
  __bf16* pk_fc2  = pk + 98304;
  float*  w12T = (float*)(ws + (7 << 19));    // 3.5 MiB: [2][64][128] fused ctx weights
  float*  fb   = w12T + 16384;                // fused ctx bias [128]

  k_pack<<<512, 256, 0, stream>>>(qkvw, projw, fc1w, fc2w, pk);
  k_packctx<<<65, 256, 0, stream>>>(ngprojw, ngprojb, mergew, mergeb, w12T, fb);
  k_uniconv<<<4096, 128, 0, stream>>>(x, uni_w, uni_b, uni);
  k_ngram<<<512, 256, 158096, stream>>>(uni, ngqkvw, ngqkvb, ngbias, w12T, fb, ctx);
  k_main<<<4096, 256, 131584, stream>>>(x, ctx, pk_qkv, pk_wv, pk_proj, pk_fc1, pk_fc2,
                                        qkvb, projb, bt, n1g, n1b, n2g, n2b, fc1b, fc2b,
                                        (float*)d_out);
}

// Round 6
// 537.802 us; speedup vs baseline: 3.0129x; 1.0002x over previous
//
#include <hip/hip_runtime.h>

// ---------------- types / helpers ----------------
typedef __bf16 bf16x8 __attribute__((ext_vector_type(8)));
typedef float  f32x4  __attribute__((ext_vector_type(4)));

#define QSCALE 0.17677669529663687f   // 32^-0.5 (main attn head_dim=32)
#define XF_LD 130                     // f32 tile stride: 130 ≡ 2 (mod 32) -> 4-way max

__device__ __forceinline__ f32x4 mfma16(bf16x8 a, bf16x8 b, f32x4 c) {
  return __builtin_amdgcn_mfma_f32_16x16x32_bf16(a, b, c, 0, 0, 0);
}

// row-major [rows][rowChunks*8] bf16 tile with XOR-swizzled 16B chunks
__device__ __forceinline__ int swz_idx(int row, int col, int rowChunks) {
  return row * (rowChunks << 3) + ((((col >> 3) ^ (row & 7)) << 3) | (col & 7));
}

// A/B fragment load from swizzled row-major LDS tile.
__device__ __forceinline__ bf16x8 ld_tile(const __bf16* t, int rowChunks,
                                          int rowBase, int chunkBase, int lane) {
  int row = rowBase + (lane & 15);
  int c = (chunkBase + (lane >> 4)) ^ (row & 7);
  return *(const bf16x8*)(t + row * (rowChunks << 3) + (c << 3));
}

// fragment load from pre-packed global weights (coalesced 1KiB per wave)
__device__ __forceinline__ bf16x8 ld_pack(const __bf16* pk, int nt, int ks,
                                          int ksteps, int lane) {
  int idx = ((nt * ksteps + ks) * 64 + lane) * 8;
  return *(const bf16x8*)(pk + idx);
}

__device__ __forceinline__ int region_of(int hh, int ww) {
  int rh = (hh < 248) ? 0 : ((hh < 252) ? 1 : 2);
  int rw = (ww < 248) ? 0 : ((ww < 252) ? 1 : 2);
  return rh * 3 + rw;
}

// ---------------- K0: pack weights to bf16 fragment order ----------------
__global__ void k_pack(const float* __restrict__ qkvw, const float* __restrict__ projw,
                       const float* __restrict__ fc1w, const float* __restrict__ fc2w,
                       __bf16* __restrict__ pk) {
  int i = blockIdx.x * 256 + threadIdx.x;
  const float* src; int K; int e; int scaleQ = 0;
  if (i < 32768)      { src = qkvw;             K = 128; e = i;          scaleQ = 1; }
  else if (i < 49152) { src = qkvw + 256 * 128; K = 128; e = i - 32768; }
  else if (i < 65536) { src = projw;            K = 128; e = i - 49152; }
  else if (i < 98304) { src = fc1w;             K = 128; e = i - 65536; }
  else                { src = fc2w;             K = 256; e = i - 98304; }
  int i8 = e & 7, ln = (e >> 3) & 63, t = e >> 9;
  int ls = (K == 256) ? 3 : 2;
  int ks = t & ((1 << ls) - 1), nt = t >> ls;
  int row = (nt << 4) + (ln & 15);
  int k = (ks << 5) + ((ln >> 4) << 3) + i8;
  float v = src[row * K + k];
  if (scaleQ && row < 128) v *= QSCALE;
  pk[i] = (__bf16)v;
}

// ---------------- K0b: fused ngram proj+merge weights ----------------
__global__ void k_packctx(const float* __restrict__ ngprojw, const float* __restrict__ ngprojb,
                          const float* __restrict__ mergew, const float* __restrict__ mergeb,
                          float* __restrict__ w12T, float* __restrict__ fb) {
  int idx = blockIdx.x * 256 + threadIdx.x;
  if (idx < 16384) {
    int which = idx >> 13;
    int r = idx & 8191;
    int e = r >> 7, o = r & 127;
    float a = 0.f;
#pragma unroll 8
    for (int d = 0; d < 64; ++d)
      a += mergew[o * 128 + which * 64 + d] * ngprojw[d * 64 + e];
    w12T[idx] = a;
  } else if (idx < 16384 + 128) {
    int o = idx - 16384;
    float a = mergeb[o];
#pragma unroll 8
    for (int d = 0; d < 64; ++d)
      a += (mergew[o * 128 + d] + mergew[o * 128 + 64 + d]) * ngprojb[d];
    fb[o] = a;
  }
}

// ---------------- K1: grouped 8x8/stride8 conv -> uni [B][32][32][64] ----------------
__global__ void k_uniconv(const float* __restrict__ x, const float* __restrict__ uw,
                          const float* __restrict__ ub, float* __restrict__ uni) {
  int bidx = blockIdx.x;               // b*1024 + oh*32 + ow
  int b = bidx >> 10, oh = (bidx >> 5) & 31, ow = bidx & 31;
  int d = threadIdx.x;                 // input channel 0..127
  const float* xb = x + (((size_t)((b << 16) + ((oh << 3) << 8) + (ow << 3))) << 7) + d;
  const float* w = uw + d * 64;
  float acc = 0.f;
#pragma unroll
  for (int kh = 0; kh < 8; ++kh)
#pragma unroll
    for (int kw = 0; kw < 8; ++kw)
      acc += xb[(size_t)(((kh << 8) + kw)) << 7] * w[kh * 8 + kw];
  acc += __shfl_xor(acc, 1);
  if (!(d & 1)) uni[((size_t)bidx << 6) + (d >> 1)] = acc + ub[d >> 1];
}

// ---------------- K2: ngram path, 8 windows/block, LDS-staged weights ----------------
__global__ void __launch_bounds__(256, 1)
k_ngram(const float* __restrict__ uni, const float* __restrict__ ngqkvw,
        const float* __restrict__ ngqkvb, const float* __restrict__ ngbias,
        const float* __restrict__ w12T, const float* __restrict__ fbg,
        float* __restrict__ ctx) {
  extern __shared__ float sm[];
  float* qkvT = sm;                     // 12288
  float* w1T  = qkvT + 12288;           // 8192
  float* w2T  = w1T + 8192;             // 8192
  float* tokl = w2T + 8192;             // 2304
  float* qs   = tokl + 2304;            // 6912
  float* prs  = qs + 6912;              // 256
  float* avgl = prs + 256;              // 1024
  float* ngb  = avgl + 1024;            // 192
  float* fbs  = ngb + 192;              // 128
  float* nbias= fbs + 128;              // 36

  const int t = threadIdx.x;
  const int bidx = blockIdx.x;
  const int b = bidx >> 7, ii = (bidx >> 2) & 31, jq = bidx & 3;
  const int j0 = jq * 8;

#pragma unroll
  for (int it = 0; it < 12; ++it) {
    int f = it * 256 + t;
    int o = f >> 4, c4 = (f & 15) << 2;
    float4 v = *(const float4*)(ngqkvw + o * 64 + c4);
    float s = (o < 64) ? 0.25f : 1.f;
    qkvT[(c4 + 0) * 192 + o] = v.x * s;
    qkvT[(c4 + 1) * 192 + o] = v.y * s;
    qkvT[(c4 + 2) * 192 + o] = v.z * s;
    qkvT[(c4 + 3) * 192 + o] = v.w * s;
  }
#pragma unroll
  for (int it = 0; it < 16; ++it) {
    int f = (it * 256 + t) << 2;
    *(float4*)(w1T + f) = *(const float4*)(w12T + f);
  }
  if (t < 192) ngb[t] = ngqkvb[t] * (t < 64 ? 0.25f : 1.f);
  if (t < 128) fbs[t] = fbg[t];
  if (t < 36)  nbias[t] = ngbias[t];
  {
    int w = t >> 6, lane = t & 63;
    int dir = w >> 1, rr = w & 1;
    int pi = ii + rr;
    int srcr = (dir == 0) ? ((pi < 32) ? pi : 30) : ((pi == 0) ? 1 : pi - 1);
#pragma unroll
    for (int cc = 0; cc < 9; ++cc) {
      int pj = j0 + cc;
      int srcc = (dir == 0) ? ((pj < 32) ? pj : 30) : ((pj == 0) ? 1 : pj - 1);
      tokl[((dir * 2 + rr) * 9 + cc) * 64 + lane] =
          uni[(size_t)((b * 32 + srcr) * 32 + srcc) * 64 + lane];
    }
  }
  __syncthreads();

  {
    int w = t >> 6, lane = t & 63;
    for (int itp = 0; itp < 9; ++itp) {
      int pos = itp * 4 + w;
      const float* tk = tokl + pos * 64;
      float a0 = ngb[lane], a1 = ngb[64 + lane], a2 = ngb[128 + lane];
#pragma unroll 4
      for (int c = 0; c < 64; ++c) {
        float tv = tk[c];
        const float* qr = qkvT + c * 192;
        a0 += qr[lane] * tv;
        a1 += qr[64 + lane] * tv;
        a2 += qr[128 + lane] * tv;
      }
      float* dst = qs + pos * 192;
      dst[lane] = a0; dst[64 + lane] = a1; dst[128 + lane] = a2;
    }
  }
  __syncthreads();

  {
    int dw = t >> 4;
    int idx = t & 15, h = idx >> 2, p = idx & 3;
    int dir = dw >> 3, jl = dw & 7;
    const float* qp = qs + ((dir * 2 + (p >> 1)) * 9 + jl + (p & 1)) * 192 + h * 16;
    float s[4];
#pragma unroll
    for (int m = 0; m < 4; ++m) {
      const float* km = qs + ((dir * 2 + (m >> 1)) * 9 + jl + (m & 1)) * 192 + 64 + h * 16;
      float a = 0.f;
#pragma unroll
      for (int e = 0; e < 16; ++e) a += qp[e] * km[e];
      int bi2 = ((p >> 1) - (m >> 1) + 1) * 3 + ((p & 1) - (m & 1) + 1);
      s[m] = a + nbias[bi2 * 4 + h];
    }
    float mx = fmaxf(fmaxf(s[0], s[1]), fmaxf(s[2], s[3]));
    float e0 = __expf(s[0] - mx), e1 = __expf(s[1] - mx);
    float e2 = __expf(s[2] - mx), e3 = __expf(s[3] - mx);
    float inv = 1.f / (e0 + e1 + e2 + e3);
    float p0 = e0 * inv, p1 = e1 * inv, p2 = e2 * inv, p3 = e3 * inv;
    p0 += __shfl_xor(p0, 1); p0 += __shfl_xor(p0, 2);
    p1 += __shfl_xor(p1, 1); p1 += __shfl_xor(p1, 2);
    p2 += __shfl_xor(p2, 1); p2 += __shfl_xor(p2, 2);
    p3 += __shfl_xor(p3, 1); p3 += __shfl_xor(p3, 2);
    if (p == 0) {
      float* d = prs + (dw * 4 + h) * 4;
      d[0] = p0; d[1] = p1; d[2] = p2; d[3] = p3;
    }
  }
  __syncthreads();

  {
    int w = t >> 6, lane = t & 63;
#pragma unroll
    for (int it = 0; it < 4; ++it) {
      int dw = it * 4 + w;
      int dir = dw >> 3, jl = dw & 7;
      int h = lane >> 4;
      float a = 0.f;
#pragma unroll
      for (int m = 0; m < 4; ++m) {
        float pm = prs[(dw * 4 + h) * 4 + m];
        float vv = qs[((dir * 2 + (m >> 1)) * 9 + jl + (m & 1)) * 192 + 128 + lane];
        a += pm * vv;
      }
      avgl[dw * 64 + lane] = a * 0.25f;
    }
  }
  __syncthreads();

  {
#pragma unroll
    for (int it = 0; it < 4; ++it) {
      int id = it * 256 + t;
      int win = id >> 7, o = id & 127;
      const float* af = avgl + win * 64;
      const float* ab = avgl + (8 + win) * 64;
      float a = fbs[o];
#pragma unroll 4
      for (int c = 0; c < 64; ++c)
        a += w1T[c * 128 + o] * af[c] + w2T[c * 128 + o] * ab[c];
      int j = j0 + win;
      ctx[((size_t)((b * 32 + ii) * 32 + j)) * 128 + o] = a;
    }
  }
}

// ---------------- K3: fused window attention + LN + FFN + LN ----------------
// LDS map (96 KiB, 1 block/CU) — exactly R5 minus the Xf tile (x1 now in regs):
//  [0,16K)   Xbf  [64][128] bf16 swz : tokens (x+ctx) -> later x1 bf16
//  [16K,32K) QO   [64][128] bf16 swz : Q then O  | Hl [64][256] with Kl in FFN
//  [32K,48K) Kl   [64][128] bf16 swz
//  [48K,64K) Vt   [128][64] bf16 swz  | Rf/Ff f32 [64][130] after attn (spans into Pl)
//  [64K,96K) Pl   [4][64][64] bf16 swz
__global__ void __launch_bounds__(256, 1)
k_main(const float* __restrict__ xin, const float* __restrict__ ctx,
       const __bf16* __restrict__ pk_qkv, const __bf16* __restrict__ pk_wv,
       const __bf16* __restrict__ pk_proj, const __bf16* __restrict__ pk_fc1,
       const __bf16* __restrict__ pk_fc2,
       const float* __restrict__ qkvb, const float* __restrict__ projb,
       const float* __restrict__ bt,
       const float* __restrict__ n1g, const float* __restrict__ n1b,
       const float* __restrict__ n2g, const float* __restrict__ n2b,
       const float* __restrict__ fc1b, const float* __restrict__ fc2b,
       float* __restrict__ outp) {
  extern __shared__ char smem[];
  __bf16* Xbf = (__bf16*)smem;
  __bf16* QO  = (__bf16*)(smem + 16 * 1024);
  __bf16* Kl  = (__bf16*)(smem + 32 * 1024);
  __bf16* Vt  = (__bf16*)(smem + 48 * 1024);
  __bf16* Pl  = (__bf16*)(smem + 64 * 1024);
  float*  Rf  = (float*)(smem + 48 * 1024);   // [64][130] f32 (aliases Vt+P-head, dead)
  __bf16* Hl  = (__bf16*)(smem + 16 * 1024);  // [64][256] bf16 swz (aliases QO+Kl, FFN)
  float*  Ff  = (float*)(smem + 48 * 1024);   // [64][130] f32

  const int widx = blockIdx.x;
  const int b = widx >> 10, wi = (widx >> 5) & 31, wj = widx & 31;
  const int tid = threadIdx.x;
  const int lane = tid & 63, wv = tid >> 6;
  const int lm = lane & 15, lg = lane >> 4;

  // x1 (= x + LN(R)) for this thread's 32 channels, in regs from phase 5 to 8.
  float xr[32];

  // ---- Phase 0: load tokens (x + ctx) -> Xbf (bf16 swz) only ----
  {
    int n = tid >> 2, q = tid & 3;
    int ts1 = n >> 3, ts2 = n & 7;
    int hh = ((wi << 3) + ts1 + 4) & 255;
    int ww = ((wj << 3) + ts2 + 4) & 255;
    const float* xp = xin + (((size_t)((b << 16) + (hh << 8) + ww)) << 7);
    const float* cp = ctx + (((size_t)((((b << 5) + (hh >> 3)) << 5) + (ww >> 3))) << 7);
#pragma unroll
    for (int jc = 0; jc < 4; ++jc) {
      int c = (q << 2) + jc;                // bf16 chunk 0..15 (8 elems)
      const float* xs = xp + (c << 3);
      const float* cs = cp + (c << 3);
      float4 xa = *(const float4*)xs;
      float4 xb = *(const float4*)(xs + 4);
      float4 ca = *(const float4*)cs;
      float4 cb = *(const float4*)(cs + 4);
      float v[8];
      v[0] = xa.x + ca.x; v[1] = xa.y + ca.y; v[2] = xa.z + ca.z; v[3] = xa.w + ca.w;
      v[4] = xb.x + cb.x; v[5] = xb.y + cb.y; v[6] = xb.z + cb.z; v[7] = xb.w + cb.w;
      bf16x8 p8;
#pragma unroll
      for (int e = 0; e < 8; ++e) p8[e] = (__bf16)v[e];
      *(bf16x8*)(Xbf + (n << 7) + ((c ^ (n & 7)) << 3)) = p8;
    }
  }
  __syncthreads();

  // ---- Phase 1a: Q,K = X @ Wqk (wave -> 4 ntiles of 16 cols) ----
  for (int mt = 0; mt < 4; ++mt) {
    bf16x8 af[4];
#pragma unroll
    for (int ks = 0; ks < 4; ++ks) af[ks] = ld_tile(Xbf, 16, mt * 16, ks * 4, lane);
#pragma unroll
    for (int nt2 = 0; nt2 < 4; ++nt2) {
      int ntG = (wv << 2) + nt2;            // 0..15 over 256 q/k cols
      f32x4 acc = {0.f, 0.f, 0.f, 0.f};
#pragma unroll
      for (int ks = 0; ks < 4; ++ks)
        acc = mfma16(af[ks], ld_pack(pk_qkv, ntG, ks, 4, lane), acc);
      int col = (ntG << 4) + lm;            // qkv channel 0..255
      float bias = (col < 128) ? qkvb[col] * QSCALE : qkvb[col];
      __bf16* dst = (col < 128) ? QO : Kl;
      int cc = col & 127;
#pragma unroll
      for (int r = 0; r < 4; ++r) {
        int row = mt * 16 + lg * 4 + r;
        dst[swz_idx(row, cc, 16)] = (__bf16)(acc[r] + bias);
      }
    }
  }
  // ---- Phase 1b: V^T = Wv @ X^T (wave -> 2 mtiles of 16 ch) ----
  for (int mt2 = 0; mt2 < 2; ++mt2) {
    int mtG = (wv << 1) + mt2;              // ch tile 0..7
    bf16x8 af[4];
#pragma unroll
    for (int ks = 0; ks < 4; ++ks) af[ks] = ld_pack(pk_wv, mtG, ks, 4, lane);
#pragma unroll
    for (int nt = 0; nt < 4; ++nt) {
      f32x4 acc = {0.f, 0.f, 0.f, 0.f};
#pragma unroll
      for (int ks = 0; ks < 4; ++ks)
        acc = mfma16(af[ks], ld_tile(Xbf, 16, nt * 16, ks * 4, lane), acc);
      int tok = (nt << 4) + lm;
#pragma unroll
      for (int r = 0; r < 4; ++r) {
        int ch = (mtG << 4) + lg * 4 + r;
        Vt[swz_idx(ch, tok, 8)] = (__bf16)(acc[r] + qkvb[256 + ch]);
      }
    }
  }
  __syncthreads();

  // ---- Phase 2: scores + softmax (wave = head) ----
  float rinv[4][4];
  {
    const int h = wv;
    bf16x8 aq[4], bk[4];
#pragma unroll
    for (int t = 0; t < 4; ++t) {
      aq[t] = ld_tile(QO, 16, t * 16, h * 4, lane);
      bk[t] = ld_tile(Kl, 16, t * 16, h * 4, lane);
    }
    f32x4 sc[4][4];
#pragma unroll
    for (int mt = 0; mt < 4; ++mt)
#pragma unroll
      for (int nt = 0; nt < 4; ++nt) {
        f32x4 z = {0.f, 0.f, 0.f, 0.f};
        sc[mt][nt] = mfma16(aq[mt], bk[nt], z);
      }
    int s1m[4], s2m[4], regm[4];
#pragma unroll
    for (int nt = 0; nt < 4; ++nt) {
      int m = nt * 16 + lm;
      s1m[nt] = m >> 3; s2m[nt] = m & 7;
      regm[nt] = region_of(wi * 8 + s1m[nt], wj * 8 + s2m[nt]);
    }
    const bool edge = (wi == 31) || (wj == 31);
    __bf16* Pme = Pl + (wv << 12);
#pragma unroll
    for (int mt = 0; mt < 4; ++mt) {
#pragma unroll
      for (int r = 0; r < 4; ++r) {
        int n = mt * 16 + lg * 4 + r;
        int s1n = n >> 3, s2n = n & 7;
        int regn = region_of(wi * 8 + s1n, wj * 8 + s2n);
        float v[4];
#pragma unroll
        for (int nt = 0; nt < 4; ++nt) {
          int idx = (s1n - s1m[nt] + 7) * 15 + (s2n - s2m[nt] + 7);
          float s = sc[mt][nt][r] + bt[idx * 4 + h];
          if (edge && (regn != regm[nt])) s -= 100.f;
          v[nt] = s;
        }
        float mx = fmaxf(fmaxf(v[0], v[1]), fmaxf(v[2], v[3]));
#pragma unroll
        for (int d = 1; d < 16; d <<= 1) mx = fmaxf(mx, __shfl_xor(mx, d));
        float ssum = 0.f;
#pragma unroll
        for (int nt = 0; nt < 4; ++nt) { v[nt] = __expf(v[nt] - mx); ssum += v[nt]; }
#pragma unroll
        for (int d = 1; d < 16; d <<= 1) ssum += __shfl_xor(ssum, d);
        rinv[mt][r] = 1.f / ssum;
#pragma unroll
        for (int nt = 0; nt < 4; ++nt)
          Pme[swz_idx(n, nt * 16 + lm, 8)] = (__bf16)v[nt];
      }
    }
  }

  // ---- Phase 3: O_h = P @ V_h (scale by 1/rowsum), write into QO cols h*32.. ----
  {
    const int h = wv;
    const __bf16* Pme = Pl + (wv << 12);
    bf16x8 ap[4][2], bv[2][2];
#pragma unroll
    for (int nt = 0; nt < 2; ++nt)
#pragma unroll
      for (int ks = 0; ks < 2; ++ks)
        bv[nt][ks] = ld_tile(Vt, 8, h * 32 + nt * 16, ks * 4, lane);
#pragma unroll
    for (int mt = 0; mt < 4; ++mt)
#pragma unroll
      for (int ks = 0; ks < 2; ++ks)
        ap[mt][ks] = ld_tile(Pme, 8, mt * 16, ks * 4, lane);
#pragma unroll
    for (int mt = 0; mt < 4; ++mt)
#pragma unroll
      for (int nt = 0; nt < 2; ++nt) {
        f32x4 acc = {0.f, 0.f, 0.f, 0.f};
        acc = mfma16(ap[mt][0], bv[nt][0], acc);
        acc = mfma16(ap[mt][1], bv[nt][1], acc);
        int cc = h * 32 + nt * 16 + lm;
#pragma unroll
        for (int r = 0; r < 4; ++r) {
          int row = mt * 16 + lg * 4 + r;
          QO[swz_idx(row, cc, 16)] = (__bf16)(acc[r] * rinv[mt][r]);
        }
      }
  }
  __syncthreads();

  // ---- Phase 4: R = O @ Wproj + b -> Rf f32 ----
  for (int mt = 0; mt < 4; ++mt) {
    bf16x8 ao[4];
#pragma unroll
    for (int ks = 0; ks < 4; ++ks) ao[ks] = ld_tile(QO, 16, mt * 16, ks * 4, lane);
#pragma unroll
    for (int nt2 = 0; nt2 < 2; ++nt2) {
      int ntG = (wv << 1) + nt2;
      f32x4 acc = {0.f, 0.f, 0.f, 0.f};
#pragma unroll
      for (int ks = 0; ks < 4; ++ks)
        acc = mfma16(ao[ks], ld_pack(pk_proj, ntG, ks, 4, lane), acc);
      int col = (ntG << 4) + lm;
      float pb = projb[col];
#pragma unroll
      for (int r = 0; r < 4; ++r) {
        int row = mt * 16 + lg * 4 + r;
        Rf[row * XF_LD + col] = acc[r] + pb;
      }
    }
  }
  __syncthreads();

  // ---- Phase 5: x1 = x + LN(R); pristine x reloaded; x1 -> xr regs + Xbf ----
  {
    int n = tid >> 2, q = tid & 3;
    int ts1 = n >> 3, ts2 = n & 7;
    int hh = ((wi << 3) + ts1 + 4) & 255;
    int ww = ((wj << 3) + ts2 + 4) & 255;
    const float* xp = xin + (((size_t)((b << 16) + (hh << 8) + ww)) << 7) + (q << 5);
    float xv[32];
#pragma unroll
    for (int j4 = 0; j4 < 8; ++j4) {
      float4 v4 = *(const float4*)(xp + (j4 << 2));
      xv[j4 * 4 + 0] = v4.x; xv[j4 * 4 + 1] = v4.y;
      xv[j4 * 4 + 2] = v4.z; xv[j4 * 4 + 3] = v4.w;
    }
    const float* rrow = Rf + n * XF_LD + (q << 5);
    float vals[32];
    float sum1 = 0.f, sum2 = 0.f;
#pragma unroll
    for (int jj = 0; jj < 32; ++jj) { float v = rrow[jj]; vals[jj] = v; sum1 += v; sum2 += v * v; }
    sum1 += __shfl_xor(sum1, 1); sum1 += __shfl_xor(sum1, 2);
    sum2 += __shfl_xor(sum2, 1); sum2 += __shfl_xor(sum2, 2);
    float mean = sum1 * 0.0078125f;
    float var = sum2 * 0.0078125f - mean * mean;
    float rstd = rsqrtf(var + 1e-5f);
#pragma unroll
    for (int jc = 0; jc < 4; ++jc) {
      bf16x8 p8;
#pragma unroll
      for (int e = 0; e < 8; ++e) {
        int jj = jc * 8 + e; int d = (q << 5) + jj;
        float ln = (vals[jj] - mean) * rstd * n1g[d] + n1b[d];
        float x1 = xv[jj] + ln;
        xr[jj] = x1;
        p8[e] = (__bf16)x1;
      }
      int c = (q << 2) + jc;
      *(bf16x8*)(Xbf + (n << 7) + ((c ^ (n & 7)) << 3)) = p8;
    }
  }
  __syncthreads();

  // ---- Phase 6: H = gelu(x1 @ Wfc1 + b) -> Hl bf16 swz ----
  for (int mt = 0; mt < 4; ++mt) {
    bf16x8 a1[4];
#pragma unroll
    for (int ks = 0; ks < 4; ++ks) a1[ks] = ld_tile(Xbf, 16, mt * 16, ks * 4, lane);
#pragma unroll
    for (int nt2 = 0; nt2 < 4; ++nt2) {
      int ntG = (wv << 2) + nt2;            // 0..15 over 256 cols
      f32x4 acc = {0.f, 0.f, 0.f, 0.f};
#pragma unroll
      for (int ks = 0; ks < 4; ++ks)
        acc = mfma16(a1[ks], ld_pack(pk_fc1, ntG, ks, 4, lane), acc);
      int col = (ntG << 4) + lm;
      float b1 = fc1b[col];
#pragma unroll
      for (int r = 0; r < 4; ++r) {
        int row = mt * 16 + lg * 4 + r;
        float hv = acc[r] + b1;
        hv = 0.5f * hv * (1.f + erff(hv * 0.70710678118654752f));
        Hl[swz_idx(row, col, 32)] = (__bf16)hv;
      }
    }
  }
  __syncthreads();

  // ---- Phase 7: F = H @ Wfc2 + b -> Ff f32 ----
  for (int mt = 0; mt < 4; ++mt) {
    bf16x8 a2[8];
#pragma unroll
    for (int ks = 0; ks < 8; ++ks) a2[ks] = ld_tile(Hl, 32, mt * 16, ks * 4, lane);
#pragma unroll
    for (int nt2 = 0; nt2 < 2; ++nt2) {
      int ntG = (wv << 1) + nt2;
      f32x4 acc = {0.f, 0.f, 0.f, 0.f};
#pragma unroll
      for (int ks = 0; ks < 8; ++ks)
        acc = mfma16(a2[ks], ld_pack(pk_fc2, ntG, ks, 8, lane), acc);
      int col = (ntG << 4) + lm;
      float b2 = fc2b[col];
#pragma unroll
      for (int r = 0; r < 4; ++r) {
        int row = mt * 16 + lg * 4 + r;
        Ff[row * XF_LD + col] = acc[r] + b2;
      }
    }
  }
  __syncthreads();

  // ---- Phase 8: out = x1 + LN(F), scatter back to original positions ----
  {
    int n = tid >> 2, q = tid & 3;
    const float* frow = Ff + n * XF_LD + (q << 5);
    float vals[32];
    float sum1 = 0.f, sum2 = 0.f;
#pragma unroll
    for (int jj = 0; jj < 32; ++jj) { float v = frow[jj]; vals[jj] = v; sum1 += v; sum2 += v * v; }
    sum1 += __shfl_xor(sum1, 1); sum1 += __shfl_xor(sum1, 2);
    sum2 += __shfl_xor(sum2, 1); sum2 += __shfl_xor(sum2, 2);
    float mean = sum1 * 0.0078125f;
    float var = sum2 * 0.0078125f - mean * mean;
    float rstd = rsqrtf(var + 1e-5f);
    int ts1 = n >> 3, ts2 = n & 7;
    int hh = ((wi << 3) + ts1 + 4) & 255;
    int ww = ((wj << 3) + ts2 + 4) & 255;
    float* op = outp + (((size_t)((b << 16) + (hh << 8) + ww)) << 7) + (q << 5);
    int dbase = (q << 5);
#pragma unroll
    for (int jj = 0; jj < 32; jj += 4) {
      float4 o4;
      o4.x = xr[jj + 0] + (vals[jj + 0] - mean) * rstd * n2g[dbase + jj + 0] + n2b[dbase + jj + 0];
      o4.y = xr[jj + 1] + (vals[jj + 1] - mean) * rstd * n2g[dbase + jj + 1] + n2b[dbase + jj + 1];
      o4.z = xr[jj + 2] + (vals[jj + 2] - mean) * rstd * n2g[dbase + jj + 2] + n2b[dbase + jj + 2];
      o4.w = xr[jj + 3] + (vals[jj + 3] - mean) * rstd * n2g[dbase + jj + 3] + n2b[dbase + jj + 3];
      *(float4*)(op + jj) = o4;
    }
  }
}

// ---------------- launch ----------------
extern "C" void kernel_launch(void* const* d_in, const int* in_sizes, int n_in,
                              void* d_out, int out_size, void* d_ws, size_t ws_size,
                              hipStream_t stream) {
  const float* x      = (const float*)d_in[0];
  const float* uni_w  = (const float*)d_in[1];
  const float* uni_b  = (const float*)d_in[2];
  const float* ngqkvw = (const float*)d_in[3];
  const float* ngqkvb = (const float*)d_in[4];
  const float* ngprojw= (const float*)d_in[5];
  const float* ngprojb= (const float*)d_in[6];
  const float* ngbias = (const float*)d_in[7];
  const float* mergew = (const float*)d_in[8];
  const float* mergeb = (const float*)d_in[9];
  const float* qkvw   = (const float*)d_in[10];
  const float* qkvb   = (const float*)d_in[11];
  const float* projw  = (const float*)d_in[12];
  const float* projb  = (const float*)d_in[13];
  const float* bt     = (const float*)d_in[14];
  const float* n1g    = (const float*)d_in[15];
  const float* n1b    = (const float*)d_in[16];
  const float* n2g    = (const float*)d_in[17];
  const float* n2b    = (const float*)d_in[18];
  const float* fc1w   = (const float*)d_in[19];
  const float* fc1b   = (const float*)d_in[20];
  const float* fc2w   = (const float*)d_in[21];
  const float* fc2b   = (const float*)d_in[22];

  char* ws = (char*)d_ws;
  float*  uni = (float*)ws;                   // 1 MiB : [4][32][32][64]
  float*  ctx = (float*)(ws + (1 << 20));     // 2 MiB : [4][32][32][128]
  __bf16* pk  = (__bf16*)(ws + (3 << 20));    // 256 KiB packed weights
  __bf16* pk_qkv  = pk;
  __bf16* pk_wv   = pk + 32768;
  __bf16* pk_proj = pk + 49152;
  __bf16* pk_fc1  = pk + 65536;
  __bf16* pk_fc2  = pk + 98304;
  float*  w12T = (float*)(ws + (7 << 19));    // 3.5 MiB: [2][64][128] fused ctx weights
  float*  fb   = w12T + 16384;                // fused ctx bias [128]

  k_pack<<<512, 256, 0, stream>>>(qkvw, projw, fc1w, fc2w, pk);
  k_packctx<<<65, 256, 0, stream>>>(ngprojw, ngprojb, mergew, mergeb, w12T, fb);
  k_uniconv<<<4096, 128, 0, stream>>>(x, uni_w, uni_b, uni);
  k_ngram<<<512, 256, 158096, stream>>>(uni, ngqkvw, ngqkvb, ngbias, w12T, fb, ctx);
  k_main<<<4096, 256, 98304, stream>>>(x, ctx, pk_qkv, pk_wv, pk_proj, pk_fc1, pk_fc2,
                                       qkvb, projb, bt, n1g, n1b, n2g, n2b, fc1b, fc2b,
                                       (float*)d_out);
}

// Round 8
// 429.939 us; speedup vs baseline: 3.7688x; 1.2509x over previous
//
#include <hip/hip_runtime.h>

// ---------------- types / helpers ----------------
typedef __bf16 bf16x8 __attribute__((ext_vector_type(8)));
typedef float  f32x4  __attribute__((ext_vector_type(4)));

#define QSCALE 0.17677669529663687f   // 32^-0.5 (main attn head_dim=32)
#define XF_LD 130                     // f32 tile stride: 130 ≡ 2 (mod 32) -> 4-way max

__device__ __forceinline__ f32x4 mfma16(bf16x8 a, bf16x8 b, f32x4 c) {
  return __builtin_amdgcn_mfma_f32_16x16x32_bf16(a, b, c, 0, 0, 0);
}

// row-major [rows][rowChunks*8] bf16 tile with XOR-swizzled 16B chunks
__device__ __forceinline__ int swz_idx(int row, int col, int rowChunks) {
  return row * (rowChunks << 3) + ((((col >> 3) ^ (row & 7)) << 3) | (col & 7));
}

// A/B fragment load from swizzled row-major LDS tile.
__device__ __forceinline__ bf16x8 ld_tile(const __bf16* t, int rowChunks,
                                          int rowBase, int chunkBase, int lane) {
  int row = rowBase + (lane & 15);
  int c = (chunkBase + (lane >> 4)) ^ (row & 7);
  return *(const bf16x8*)(t + row * (rowChunks << 3) + (c << 3));
}

// fragment load from pre-packed global weights (coalesced 1KiB per wave)
__device__ __forceinline__ bf16x8 ld_pack(const __bf16* pk, int nt, int ks,
                                          int ksteps, int lane) {
  int idx = ((nt * ksteps + ks) * 64 + lane) * 8;
  return *(const bf16x8*)(pk + idx);
}

__device__ __forceinline__ int region_of(int hh, int ww) {
  int rh = (hh < 248) ? 0 : ((hh < 252) ? 1 : 2);
  int rw = (ww < 248) ? 0 : ((ww < 252) ? 1 : 2);
  return rh * 3 + rw;
}

// ---------------- K0: pack weights to bf16 fragment order ----------------
__global__ void k_pack(const float* __restrict__ qkvw, const float* __restrict__ projw,
                       const float* __restrict__ fc1w, const float* __restrict__ fc2w,
                       __bf16* __restrict__ pk) {
  int i = blockIdx.x * 256 + threadIdx.x;
  const float* src; int K; int e; int scaleQ = 0;
  if (i < 32768)      { src = qkvw;             K = 128; e = i;          scaleQ = 1; }
  else if (i < 49152) { src = qkvw + 256 * 128; K = 128; e = i - 32768; }
  else if (i < 65536) { src = projw;            K = 128; e = i - 49152; }
  else if (i < 98304) { src = fc1w;             K = 128; e = i - 65536; }
  else                { src = fc2w;             K = 256; e = i - 98304; }
  int i8 = e & 7, ln = (e >> 3) & 63, t = e >> 9;
  int ls = (K == 256) ? 3 : 2;
  int ks = t & ((1 << ls) - 1), nt = t >> ls;
  int row = (nt << 4) + (ln & 15);
  int k = (ks << 5) + ((ln >> 4) << 3) + i8;
  float v = src[row * K + k];
  if (scaleQ && row < 128) v *= QSCALE;
  pk[i] = (__bf16)v;
}

// ---------------- K0b: fused ngram proj+merge weights ----------------
__global__ void k_packctx(const float* __restrict__ ngprojw, const float* __restrict__ ngprojb,
                          const float* __restrict__ mergew, const float* __restrict__ mergeb,
                          float* __restrict__ w12T, float* __restrict__ fb) {
  int idx = blockIdx.x * 256 + threadIdx.x;
  if (idx < 16384) {
    int which = idx >> 13;
    int r = idx & 8191;
    int e = r >> 7, o = r & 127;
    float a = 0.f;
#pragma unroll 8
    for (int d = 0; d < 64; ++d)
      a += mergew[o * 128 + which * 64 + d] * ngprojw[d * 64 + e];
    w12T[idx] = a;
  } else if (idx < 16384 + 128) {
    int o = idx - 16384;
    float a = mergeb[o];
#pragma unroll 8
    for (int d = 0; d < 64; ++d)
      a += (mergew[o * 128 + d] + mergew[o * 128 + 64 + d]) * ngprojb[d];
    fb[o] = a;
  }
}

// ---------------- K1: grouped 8x8/stride8 conv -> uni [B][32][32][64] ----------------
__global__ void k_uniconv(const float* __restrict__ x, const float* __restrict__ uw,
                          const float* __restrict__ ub, float* __restrict__ uni) {
  int bidx = blockIdx.x;               // b*1024 + oh*32 + ow
  int b = bidx >> 10, oh = (bidx >> 5) & 31, ow = bidx & 31;
  int d = threadIdx.x;                 // input channel 0..127
  const float* xb = x + (((size_t)((b << 16) + ((oh << 3) << 8) + (ow << 3))) << 7) + d;
  const float* w = uw + d * 64;
  float acc = 0.f;
#pragma unroll
  for (int kh = 0; kh < 8; ++kh)
#pragma unroll
    for (int kw = 0; kw < 8; ++kw)
      acc += xb[(size_t)(((kh << 8) + kw)) << 7] * w[kh * 8 + kw];
  acc += __shfl_xor(acc, 1);
  if (!(d & 1)) uni[((size_t)bidx << 6) + (d >> 1)] = acc + ub[d >> 1];
}

// ---------------- K2: ngram path, 8 windows/block, LDS-staged weights ----------------
__global__ void __launch_bounds__(256, 1)
k_ngram(const float* __restrict__ uni, const float* __restrict__ ngqkvw,
        const float* __restrict__ ngqkvb, const float* __restrict__ ngbias,
        const float* __restrict__ w12T, const float* __restrict__ fbg,
        float* __restrict__ ctx) {
  extern __shared__ float sm[];
  float* qkvT = sm;                     // 12288
  float* w1T  = qkvT + 12288;           // 8192
  float* w2T  = w1T + 8192;             // 8192
  float* tokl = w2T + 8192;             // 2304
  float* qs   = tokl + 2304;            // 6912
  float* prs  = qs + 6912;              // 256
  float* avgl = prs + 256;              // 1024
  float* ngb  = avgl + 1024;            // 192
  float* fbs  = ngb + 192;              // 128
  float* nbias= fbs + 128;              // 36

  const int t = threadIdx.x;
  const int bidx = blockIdx.x;
  const int b = bidx >> 7, ii = (bidx >> 2) & 31, jq = bidx & 3;
  const int j0 = jq * 8;

#pragma unroll
  for (int it = 0; it < 12; ++it) {
    int f = it * 256 + t;
    int o = f >> 4, c4 = (f & 15) << 2;
    float4 v = *(const float4*)(ngqkvw + o * 64 + c4);
    float s = (o < 64) ? 0.25f : 1.f;
    qkvT[(c4 + 0) * 192 + o] = v.x * s;
    qkvT[(c4 + 1) * 192 + o] = v.y * s;
    qkvT[(c4 + 2) * 192 + o] = v.z * s;
    qkvT[(c4 + 3) * 192 + o] = v.w * s;
  }
#pragma unroll
  for (int it = 0; it < 16; ++it) {
    int f = (it * 256 + t) << 2;
    *(float4*)(w1T + f) = *(const float4*)(w12T + f);
  }
  if (t < 192) ngb[t] = ngqkvb[t] * (t < 64 ? 0.25f : 1.f);
  if (t < 128) fbs[t] = fbg[t];
  if (t < 36)  nbias[t] = ngbias[t];
  {
    int w = t >> 6, lane = t & 63;
    int dir = w >> 1, rr = w & 1;
    int pi = ii + rr;
    int srcr = (dir == 0) ? ((pi < 32) ? pi : 30) : ((pi == 0) ? 1 : pi - 1);
#pragma unroll
    for (int cc = 0; cc < 9; ++cc) {
      int pj = j0 + cc;
      int srcc = (dir == 0) ? ((pj < 32) ? pj : 30) : ((pj == 0) ? 1 : pj - 1);
      tokl[((dir * 2 + rr) * 9 + cc) * 64 + lane] =
          uni[(size_t)((b * 32 + srcr) * 32 + srcc) * 64 + lane];
    }
  }
  __syncthreads();

  {
    int w = t >> 6, lane = t & 63;
    for (int itp = 0; itp < 9; ++itp) {
      int pos = itp * 4 + w;
      const float* tk = tokl + pos * 64;
      float a0 = ngb[lane], a1 = ngb[64 + lane], a2 = ngb[128 + lane];
#pragma unroll 4
      for (int c = 0; c < 64; ++c) {
        float tv = tk[c];
        const float* qr = qkvT + c * 192;
        a0 += qr[lane] * tv;
        a1 += qr[64 + lane] * tv;
        a2 += qr[128 + lane] * tv;
      }
      float* dst = qs + pos * 192;
      dst[lane] = a0; dst[64 + lane] = a1; dst[128 + lane] = a2;
    }
  }
  __syncthreads();

  {
    int dw = t >> 4;
    int idx = t & 15, h = idx >> 2, p = idx & 3;
    int dir = dw >> 3, jl = dw & 7;
    const float* qp = qs + ((dir * 2 + (p >> 1)) * 9 + jl + (p & 1)) * 192 + h * 16;
    float s[4];
#pragma unroll
    for (int m = 0; m < 4; ++m) {
      const float* km = qs + ((dir * 2 + (m >> 1)) * 9 + jl + (m & 1)) * 192 + 64 + h * 16;
      float a = 0.f;
#pragma unroll
      for (int e = 0; e < 16; ++e) a += qp[e] * km[e];
      int bi2 = ((p >> 1) - (m >> 1) + 1) * 3 + ((p & 1) - (m & 1) + 1);
      s[m] = a + nbias[bi2 * 4 + h];
    }
    float mx = fmaxf(fmaxf(s[0], s[1]), fmaxf(s[2], s[3]));
    float e0 = __expf(s[0] - mx), e1 = __expf(s[1] - mx);
    float e2 = __expf(s[2] - mx), e3 = __expf(s[3] - mx);
    float inv = 1.f / (e0 + e1 + e2 + e3);
    float p0 = e0 * inv, p1 = e1 * inv, p2 = e2 * inv, p3 = e3 * inv;
    p0 += __shfl_xor(p0, 1); p0 += __shfl_xor(p0, 2);
    p1 += __shfl_xor(p1, 1); p1 += __shfl_xor(p1, 2);
    p2 += __shfl_xor(p2, 1); p2 += __shfl_xor(p2, 2);
    p3 += __shfl_xor(p3, 1); p3 += __shfl_xor(p3, 2);
    if (p == 0) {
      float* d = prs + (dw * 4 + h) * 4;
      d[0] = p0; d[1] = p1; d[2] = p2; d[3] = p3;
    }
  }
  __syncthreads();

  {
    int w = t >> 6, lane = t & 63;
#pragma unroll
    for (int it = 0; it < 4; ++it) {
      int dw = it * 4 + w;
      int dir = dw >> 3, jl = dw & 7;
      int h = lane >> 4;
      float a = 0.f;
#pragma unroll
      for (int m = 0; m < 4; ++m) {
        float pm = prs[(dw * 4 + h) * 4 + m];
        float vv = qs[((dir * 2 + (m >> 1)) * 9 + jl + (m & 1)) * 192 + 128 + lane];
        a += pm * vv;
      }
      avgl[dw * 64 + lane] = a * 0.25f;
    }
  }
  __syncthreads();

  {
#pragma unroll
    for (int it = 0; it < 4; ++it) {
      int id = it * 256 + t;
      int win = id >> 7, o = id & 127;
      const float* af = avgl + win * 64;
      const float* ab = avgl + (8 + win) * 64;
      float a = fbs[o];
#pragma unroll 4
      for (int c = 0; c < 64; ++c)
        a += w1T[c * 128 + o] * af[c] + w2T[c * 128 + o] * ab[c];
      int j = j0 + win;
      ctx[((size_t)((b * 32 + ii) * 32 + j)) * 128 + o] = a;
    }
  }
}

// ---------------- K3: fused window attention + LN + FFN + LN ----------------
// 512 threads (8 waves) per window -> 2 waves/SIMD at 1 block/CU.
// LDS map IDENTICAL to passing R6 (96 KiB):
//  [0,16K)   Xbf  [64][128] bf16 swz : tokens (x+ctx) -> later x1 bf16
//  [16K,32K) QO   [64][128] bf16 swz : Q then O  | Hl [64][256] with Kl in FFN
//  [32K,48K) Kl   [64][128] bf16 swz
//  [48K,64K) Vt   [128][64] bf16 swz  | Rf/Ff f32 [64][130] after attn (spans into Pl)
//  [64K,96K) Pl   [4][64][64] bf16 swz (per-head; wave pair owns disjoint row halves)
__global__ void __launch_bounds__(512, 2)
k_main(const float* __restrict__ xin, const float* __restrict__ ctx,
       const __bf16* __restrict__ pk_qkv, const __bf16* __restrict__ pk_wv,
       const __bf16* __restrict__ pk_proj, const __bf16* __restrict__ pk_fc1,
       const __bf16* __restrict__ pk_fc2,
       const float* __restrict__ qkvb, const float* __restrict__ projb,
       const float* __restrict__ bt,
       const float* __restrict__ n1g, const float* __restrict__ n1b,
       const float* __restrict__ n2g, const float* __restrict__ n2b,
       const float* __restrict__ fc1b, const float* __restrict__ fc2b,
       float* __restrict__ outp) {
  extern __shared__ char smem[];
  __bf16* Xbf = (__bf16*)smem;
  __bf16* QO  = (__bf16*)(smem + 16 * 1024);
  __bf16* Kl  = (__bf16*)(smem + 32 * 1024);
  __bf16* Vt  = (__bf16*)(smem + 48 * 1024);
  __bf16* Pl  = (__bf16*)(smem + 64 * 1024);
  float*  Rf  = (float*)(smem + 48 * 1024);   // [64][130] f32 (over dead Vt+Pl-head)
  __bf16* Hl  = (__bf16*)(smem + 16 * 1024);  // [64][256] bf16 swz (over dead QO+Kl)
  float*  Ff  = (float*)(smem + 48 * 1024);   // [64][130] f32

  const int widx = blockIdx.x;
  const int b = widx >> 10, wi = (widx >> 5) & 31, wj = widx & 31;
  const int tid = threadIdx.x;
  const int lane = tid & 63, wv = tid >> 6;   // 8 waves
  const int lm = lane & 15, lg = lane >> 4;

  // x1 (= x + LN(R)) for this thread's 16 channels, in regs from phase 5 to 8.
  float xr[16];

  // ---- Phase 0: load tokens (x + ctx) -> Xbf (bf16 swz); thread = (row n, 16-col q8)
  {
    int n = tid >> 3, q8 = tid & 7;
    int ts1 = n >> 3, ts2 = n & 7;
    int hh = ((wi << 3) + ts1 + 4) & 255;
    int ww = ((wj << 3) + ts2 + 4) & 255;
    const float* xp = xin + (((size_t)((b << 16) + (hh << 8) + ww)) << 7);
    const float* cp = ctx + (((size_t)((((b << 5) + (hh >> 3)) << 5) + (ww >> 3))) << 7);
#pragma unroll
    for (int jc = 0; jc < 2; ++jc) {
      int c = (q8 << 1) + jc;               // bf16 chunk 0..15 (8 elems)
      const float* xs = xp + (c << 3);
      const float* cs = cp + (c << 3);
      float4 xa = *(const float4*)xs;
      float4 xb = *(const float4*)(xs + 4);
      float4 ca = *(const float4*)cs;
      float4 cb = *(const float4*)(cs + 4);
      float v[8];
      v[0] = xa.x + ca.x; v[1] = xa.y + ca.y; v[2] = xa.z + ca.z; v[3] = xa.w + ca.w;
      v[4] = xb.x + cb.x; v[5] = xb.y + cb.y; v[6] = xb.z + cb.z; v[7] = xb.w + cb.w;
      bf16x8 p8;
#pragma unroll
      for (int e = 0; e < 8; ++e) p8[e] = (__bf16)v[e];
      *(bf16x8*)(Xbf + (n << 7) + ((c ^ (n & 7)) << 3)) = p8;
    }
  }
  __syncthreads();

  // ---- Phase 1a: Q,K = X @ Wqk (wave -> 2 ntiles of 16 cols) ----
  for (int mt = 0; mt < 4; ++mt) {
    bf16x8 af[4];
#pragma unroll
    for (int ks = 0; ks < 4; ++ks) af[ks] = ld_tile(Xbf, 16, mt * 16, ks * 4, lane);
#pragma unroll
    for (int nt2 = 0; nt2 < 2; ++nt2) {
      int ntG = (wv << 1) + nt2;            // 0..15 over 256 q/k cols
      f32x4 acc = {0.f, 0.f, 0.f, 0.f};
#pragma unroll
      for (int ks = 0; ks < 4; ++ks)
        acc = mfma16(af[ks], ld_pack(pk_qkv, ntG, ks, 4, lane), acc);
      int col = (ntG << 4) + lm;            // qkv channel 0..255
      float bias = (col < 128) ? qkvb[col] * QSCALE : qkvb[col];
      __bf16* dst = (col < 128) ? QO : Kl;
      int cc = col & 127;
#pragma unroll
      for (int r = 0; r < 4; ++r) {
        int row = mt * 16 + lg * 4 + r;
        dst[swz_idx(row, cc, 16)] = (__bf16)(acc[r] + bias);
      }
    }
  }
  // ---- Phase 1b: V^T = Wv @ X^T (wave -> 1 mtile of 16 ch) ----
  {
    int mtG = wv;                           // ch tile 0..7
    bf16x8 af[4];
#pragma unroll
    for (int ks = 0; ks < 4; ++ks) af[ks] = ld_pack(pk_wv, mtG, ks, 4, lane);
#pragma unroll
    for (int nt = 0; nt < 4; ++nt) {
      f32x4 acc = {0.f, 0.f, 0.f, 0.f};
#pragma unroll
      for (int ks = 0; ks < 4; ++ks)
        acc = mfma16(af[ks], ld_tile(Xbf, 16, nt * 16, ks * 4, lane), acc);
      int tok = (nt << 4) + lm;
#pragma unroll
      for (int r = 0; r < 4; ++r) {
        int ch = (mtG << 4) + lg * 4 + r;
        Vt[swz_idx(ch, tok, 8)] = (__bf16)(acc[r] + qkvb[256 + ch]);
      }
    }
  }
  __syncthreads();

  // ---- Phase 2: scores + softmax. Wave pair per head; wave owns 32-row half ----
  float rinv[2][4];
  const int h = wv >> 1, mh = wv & 1;       // head, row-half
  __bf16* Pme = Pl + (h << 12);             // head's P buffer (pair-shared, rows disjoint)
  {
    bf16x8 aq[2], bk[4];
#pragma unroll
    for (int mi = 0; mi < 2; ++mi)
      aq[mi] = ld_tile(QO, 16, (mh * 2 + mi) * 16, h * 4, lane);
#pragma unroll
    for (int nt = 0; nt < 4; ++nt)
      bk[nt] = ld_tile(Kl, 16, nt * 16, h * 4, lane);
    f32x4 sc[2][4];
#pragma unroll
    for (int mi = 0; mi < 2; ++mi)
#pragma unroll
      for (int nt = 0; nt < 4; ++nt) {
        f32x4 z = {0.f, 0.f, 0.f, 0.f};
        sc[mi][nt] = mfma16(aq[mi], bk[nt], z);
      }
    int s1m[4], s2m[4], regm[4];
#pragma unroll
    for (int nt = 0; nt < 4; ++nt) {
      int m = nt * 16 + lm;
      s1m[nt] = m >> 3; s2m[nt] = m & 7;
      regm[nt] = region_of(wi * 8 + s1m[nt], wj * 8 + s2m[nt]);
    }
    const bool edge = (wi == 31) || (wj == 31);
#pragma unroll
    for (int mi = 0; mi < 2; ++mi) {
#pragma unroll
      for (int r = 0; r < 4; ++r) {
        int n = (mh * 2 + mi) * 16 + lg * 4 + r;
        int s1n = n >> 3, s2n = n & 7;
        int regn = region_of(wi * 8 + s1n, wj * 8 + s2n);
        float v[4];
#pragma unroll
        for (int nt = 0; nt < 4; ++nt) {
          int idx = (s1n - s1m[nt] + 7) * 15 + (s2n - s2m[nt] + 7);
          float s = sc[mi][nt][r] + bt[idx * 4 + h];
          if (edge && (regn != regm[nt])) s -= 100.f;
          v[nt] = s;
        }
        float mx = fmaxf(fmaxf(v[0], v[1]), fmaxf(v[2], v[3]));
#pragma unroll
        for (int d = 1; d < 16; d <<= 1) mx = fmaxf(mx, __shfl_xor(mx, d));
        float ssum = 0.f;
#pragma unroll
        for (int nt = 0; nt < 4; ++nt) { v[nt] = __expf(v[nt] - mx); ssum += v[nt]; }
#pragma unroll
        for (int d = 1; d < 16; d <<= 1) ssum += __shfl_xor(ssum, d);
        rinv[mi][r] = 1.f / ssum;
#pragma unroll
        for (int nt = 0; nt < 4; ++nt)
          Pme[swz_idx(n, nt * 16 + lm, 8)] = (__bf16)v[nt];
      }
    }
  }

  // ---- Phase 3: O_h = P @ V_h (own 32-row half; own P rows only) ----
  {
    bf16x8 ap[2][2], bv[2][2];
#pragma unroll
    for (int nt = 0; nt < 2; ++nt)
#pragma unroll
      for (int ks = 0; ks < 2; ++ks)
        bv[nt][ks] = ld_tile(Vt, 8, h * 32 + nt * 16, ks * 4, lane);
#pragma unroll
    for (int mi = 0; mi < 2; ++mi)
#pragma unroll
      for (int ks = 0; ks < 2; ++ks)
        ap[mi][ks] = ld_tile(Pme, 8, (mh * 2 + mi) * 16, ks * 4, lane);
#pragma unroll
    for (int mi = 0; mi < 2; ++mi)
#pragma unroll
      for (int nt = 0; nt < 2; ++nt) {
        f32x4 acc = {0.f, 0.f, 0.f, 0.f};
        acc = mfma16(ap[mi][0], bv[nt][0], acc);
        acc = mfma16(ap[mi][1], bv[nt][1], acc);
        int cc = h * 32 + nt * 16 + lm;
#pragma unroll
        for (int r = 0; r < 4; ++r) {
          int row = (mh * 2 + mi) * 16 + lg * 4 + r;
          QO[swz_idx(row, cc, 16)] = (__bf16)(acc[r] * rinv[mi][r]);
        }
      }
  }
  __syncthreads();

  // ---- Phase 4: R = O @ Wproj + b -> Rf f32 (wave -> 1 ntile) ----
  for (int mt = 0; mt < 4; ++mt) {
    bf16x8 ao[4];
#pragma unroll
    for (int ks = 0; ks < 4; ++ks) ao[ks] = ld_tile(QO, 16, mt * 16, ks * 4, lane);
    {
      int ntG = wv;
      f32x4 acc = {0.f, 0.f, 0.f, 0.f};
#pragma unroll
      for (int ks = 0; ks < 4; ++ks)
        acc = mfma16(ao[ks], ld_pack(pk_proj, ntG, ks, 4, lane), acc);
      int col = (ntG << 4) + lm;
      float pb = projb[col];
#pragma unroll
      for (int r = 0; r < 4; ++r) {
        int row = mt * 16 + lg * 4 + r;
        Rf[row * XF_LD + col] = acc[r] + pb;
      }
    }
  }
  __syncthreads();

  // ---- Phase 5: x1 = x + LN(R); pristine x reloaded; x1 -> xr regs + Xbf ----
  {
    int n = tid >> 3, q8 = tid & 7;
    int ts1 = n >> 3, ts2 = n & 7;
    int hh = ((wi << 3) + ts1 + 4) & 255;
    int ww = ((wj << 3) + ts2 + 4) & 255;
    const float* xp = xin + (((size_t)((b << 16) + (hh << 8) + ww)) << 7) + (q8 << 4);
    float xv[16];
#pragma unroll
    for (int j4 = 0; j4 < 4; ++j4) {
      float4 v4 = *(const float4*)(xp + (j4 << 2));
      xv[j4 * 4 + 0] = v4.x; xv[j4 * 4 + 1] = v4.y;
      xv[j4 * 4 + 2] = v4.z; xv[j4 * 4 + 3] = v4.w;
    }
    const float* rrow = Rf + n * XF_LD + (q8 << 4);
    float vals[16];
    float sum1 = 0.f, sum2 = 0.f;
#pragma unroll
    for (int jj = 0; jj < 16; ++jj) { float v = rrow[jj]; vals[jj] = v; sum1 += v; sum2 += v * v; }
    sum1 += __shfl_xor(sum1, 1); sum1 += __shfl_xor(sum1, 2); sum1 += __shfl_xor(sum1, 4);
    sum2 += __shfl_xor(sum2, 1); sum2 += __shfl_xor(sum2, 2); sum2 += __shfl_xor(sum2, 4);
    float mean = sum1 * 0.0078125f;
    float var = sum2 * 0.0078125f - mean * mean;
    float rstd = rsqrtf(var + 1e-5f);
#pragma unroll
    for (int jc = 0; jc < 2; ++jc) {
      bf16x8 p8;
#pragma unroll
      for (int e = 0; e < 8; ++e) {
        int jj = jc * 8 + e; int d = (q8 << 4) + jj;
        float ln = (vals[jj] - mean) * rstd * n1g[d] + n1b[d];
        float x1 = xv[jj] + ln;
        xr[jj] = x1;
        p8[e] = (__bf16)x1;
      }
      int c = (q8 << 1) + jc;
      *(bf16x8*)(Xbf + (n << 7) + ((c ^ (n & 7)) << 3)) = p8;
    }
  }
  __syncthreads();

  // ---- Phase 6: H = gelu(x1 @ Wfc1 + b) -> Hl bf16 swz (wave -> 2 ntiles) ----
  for (int mt = 0; mt < 4; ++mt) {
    bf16x8 a1[4];
#pragma unroll
    for (int ks = 0; ks < 4; ++ks) a1[ks] = ld_tile(Xbf, 16, mt * 16, ks * 4, lane);
#pragma unroll
    for (int nt2 = 0; nt2 < 2; ++nt2) {
      int ntG = (wv << 1) + nt2;            // 0..15 over 256 cols
      f32x4 acc = {0.f, 0.f, 0.f, 0.f};
#pragma unroll
      for (int ks = 0; ks < 4; ++ks)
        acc = mfma16(a1[ks], ld_pack(pk_fc1, ntG, ks, 4, lane), acc);
      int col = (ntG << 4) + lm;
      float b1 = fc1b[col];
#pragma unroll
      for (int r = 0; r < 4; ++r) {
        int row = mt * 16 + lg * 4 + r;
        float hv = acc[r] + b1;
        hv = 0.5f * hv * (1.f + erff(hv * 0.70710678118654752f));
        Hl[swz_idx(row, col, 32)] = (__bf16)hv;
      }
    }
  }
  __syncthreads();

  // ---- Phase 7: F = H @ Wfc2 + b -> Ff f32 (wave -> 1 ntile) ----
  for (int mt = 0; mt < 4; ++mt) {
    bf16x8 a2[8];
#pragma unroll
    for (int ks = 0; ks < 8; ++ks) a2[ks] = ld_tile(Hl, 32, mt * 16, ks * 4, lane);
    {
      int ntG = wv;
      f32x4 acc = {0.f, 0.f, 0.f, 0.f};
#pragma unroll
      for (int ks = 0; ks < 8; ++ks)
        acc = mfma16(a2[ks], ld_pack(pk_fc2, ntG, ks, 8, lane), acc);
      int col = (ntG << 4) + lm;
      float b2 = fc2b[col];
#pragma unroll
      for (int r = 0; r < 4; ++r) {
        int row = mt * 16 + lg * 4 + r;
        Ff[row * XF_LD + col] = acc[r] + b2;
      }
    }
  }
  __syncthreads();

  // ---- Phase 8: out = x1 + LN(F), scatter back to original positions ----
  {
    int n = tid >> 3, q8 = tid & 7;
    const float* frow = Ff + n * XF_LD + (q8 << 4);
    float vals[16];
    float sum1 = 0.f, sum2 = 0.f;
#pragma unroll
    for (int jj = 0; jj < 16; ++jj) { float v = frow[jj]; vals[jj] = v; sum1 += v; sum2 += v * v; }
    sum1 += __shfl_xor(sum1, 1); sum1 += __shfl_xor(sum1, 2); sum1 += __shfl_xor(sum1, 4);
    sum2 += __shfl_xor(sum2, 1); sum2 += __shfl_xor(sum2, 2); sum2 += __shfl_xor(sum2, 4);
    float mean = sum1 * 0.0078125f;
    float var = sum2 * 0.0078125f - mean * mean;
    float rstd = rsqrtf(var + 1e-5f);
    int ts1 = n >> 3, ts2 = n & 7;
    int hh = ((wi << 3) + ts1 + 4) & 255;
    int ww = ((wj << 3) + ts2 + 4) & 255;
    float* op = outp + (((size_t)((b << 16) + (hh << 8) + ww)) << 7) + (q8 << 4);
    int dbase = (q8 << 4);
#pragma unroll
    for (int jj = 0; jj < 16; jj += 4) {
      float4 o4;
      o4.x = xr[jj + 0] + (vals[jj + 0] - mean) * rstd * n2g[dbase + jj + 0] + n2b[dbase + jj + 0];
      o4.y = xr[jj + 1] + (vals[jj + 1] - mean) * rstd * n2g[dbase + jj + 1] + n2b[dbase + jj + 1];
      o4.z = xr[jj + 2] + (vals[jj + 2] - mean) * rstd * n2g[dbase + jj + 2] + n2b[dbase + jj + 2];
      o4.w = xr[jj + 3] + (vals[jj + 3] - mean) * rstd * n2g[dbase + jj + 3] + n2b[dbase + jj + 3];
      *(float4*)(op + jj) = o4;
    }
  }
}

// ---------------- launch ----------------
extern "C" void kernel_launch(void* const* d_in, const int* in_sizes, int n_in,
                              void* d_out, int out_size, void* d_ws, size_t ws_size,
                              hipStream_t stream) {
  const float* x      = (const float*)d_in[0];
  const float* uni_w  = (const float*)d_in[1];
  const float* uni_b  = (const float*)d_in[2];
  const float* ngqkvw = (const float*)d_in[3];
  const float* ngqkvb = (const float*)d_in[4];
  const float* ngprojw= (const float*)d_in[5];
  const float* ngprojb= (const float*)d_in[6];
  const float* ngbias = (const float*)d_in[7];
  const float* mergew = (const float*)d_in[8];
  const float* mergeb = (const float*)d_in[9];
  const float* qkvw   = (const float*)d_in[10];
  const float* qkvb   = (const float*)d_in[11];
  const float* projw  = (const float*)d_in[12];
  const float* projb  = (const float*)d_in[13];
  const float* bt     = (const float*)d_in[14];
  const float* n1g    = (const float*)d_in[15];
  const float* n1b    = (const float*)d_in[16];
  const float* n2g    = (const float*)d_in[17];
  const float* n2b    = (const float*)d_in[18];
  const float* fc1w   = (const float*)d_in[19];
  const float* fc1b   = (const float*)d_in[20];
  const float* fc2w   = (const float*)d_in[21];
  const float* fc2b   = (const float*)d_in[22];

  char* ws = (char*)d_ws;
  float*  uni = (float*)ws;                   // 1 MiB : [4][32][32][64]
  float*  ctx = (float*)(ws + (1 << 20));     // 2 MiB : [4][32][32][128]
  __bf16* pk  = (__bf16*)(ws + (3 << 20));    // 256 KiB packed weights
  __bf16* pk_qkv  = pk;
  __bf16* pk_wv   = pk + 32768;
  __bf16* pk_proj = pk + 49152;
  __bf16* pk_fc1  = pk + 65536;
  __bf16* pk_fc2  = pk + 98304;
  float*  w12T = (float*)(ws + (7 << 19));    // 3.5 MiB: [2][64][128] fused ctx weights
  float*  fb   = w12T + 16384;                // fused ctx bias [128]

  k_pack<<<512, 256, 0, stream>>>(qkvw, projw, fc1w, fc2w, pk);
  k_packctx<<<65, 256, 0, stream>>>(ngprojw, ngprojb, mergew, mergeb, w12T, fb);
  k_uniconv<<<4096, 128, 0, stream>>>(x, uni_w, uni_b, uni);
  k_ngram<<<512, 256, 158096, stream>>>(uni, ngqkvw, ngqkvb, ngbias, w12T, fb, ctx);
  k_main<<<4096, 512, 98304, stream>>>(x, ctx, pk_qkv, pk_wv, pk_proj, pk_fc1, pk_fc2,
                                       qkvb, projb, bt, n1g, n1b, n2g, n2b, fc1b, fc2b,
                                       (float*)d_out);
}

// Round 9
// 348.908 us; speedup vs baseline: 4.6440x; 1.2322x over previous
//
#include <hip/hip_runtime.h>

// ---------------- types / helpers ----------------
typedef __bf16 bf16x8 __attribute__((ext_vector_type(8)));
typedef float  f32x4  __attribute__((ext_vector_type(4)));

#define QSCALE 0.17677669529663687f   // 32^-0.5 (main attn head_dim=32)
#define XF_LD 130                     // f32 tile stride: 130 ≡ 2 (mod 32) -> 4-way max

__device__ __forceinline__ f32x4 mfma16(bf16x8 a, bf16x8 b, f32x4 c) {
  return __builtin_amdgcn_mfma_f32_16x16x32_bf16(a, b, c, 0, 0, 0);
}

// row-major [rows][rowChunks*8] bf16 tile with XOR-swizzled 16B chunks
__device__ __forceinline__ int swz_idx(int row, int col, int rowChunks) {
  return row * (rowChunks << 3) + ((((col >> 3) ^ (row & 7)) << 3) | (col & 7));
}

// A/B fragment load from swizzled row-major LDS tile.
__device__ __forceinline__ bf16x8 ld_tile(const __bf16* t, int rowChunks,
                                          int rowBase, int chunkBase, int lane) {
  int row = rowBase + (lane & 15);
  int c = (chunkBase + (lane >> 4)) ^ (row & 7);
  return *(const bf16x8*)(t + row * (rowChunks << 3) + (c << 3));
}

// fragment load from pre-packed global weights (coalesced 1KiB per wave)
__device__ __forceinline__ bf16x8 ld_pack(const __bf16* pk, int nt, int ks,
                                          int ksteps, int lane) {
  int idx = ((nt * ksteps + ks) * 64 + lane) * 8;
  return *(const bf16x8*)(pk + idx);
}

__device__ __forceinline__ int region_of(int hh, int ww) {
  int rh = (hh < 248) ? 0 : ((hh < 252) ? 1 : 2);
  int rw = (ww < 248) ? 0 : ((ww < 252) ? 1 : 2);
  return rh * 3 + rw;
}

// ---------------- K0: pack weights to bf16 fragment order ----------------
__global__ void k_pack(const float* __restrict__ qkvw, const float* __restrict__ projw,
                       const float* __restrict__ fc1w, const float* __restrict__ fc2w,
                       __bf16* __restrict__ pk) {
  int i = blockIdx.x * 256 + threadIdx.x;
  const float* src; int K; int e; int scaleQ = 0;
  if (i < 32768)      { src = qkvw;             K = 128; e = i;          scaleQ = 1; }
  else if (i < 49152) { src = qkvw + 256 * 128; K = 128; e = i - 32768; }
  else if (i < 65536) { src = projw;            K = 128; e = i - 49152; }
  else if (i < 98304) { src = fc1w;             K = 128; e = i - 65536; }
  else                { src = fc2w;             K = 256; e = i - 98304; }
  int i8 = e & 7, ln = (e >> 3) & 63, t = e >> 9;
  int ls = (K == 256) ? 3 : 2;
  int ks = t & ((1 << ls) - 1), nt = t >> ls;
  int row = (nt << 4) + (ln & 15);
  int k = (ks << 5) + ((ln >> 4) << 3) + i8;
  float v = src[row * K + k];
  if (scaleQ && row < 128) v *= QSCALE;
  pk[i] = (__bf16)v;
}

// ---------------- K0b: fused ngram proj+merge weights ----------------
__global__ void k_packctx(const float* __restrict__ ngprojw, const float* __restrict__ ngprojb,
                          const float* __restrict__ mergew, const float* __restrict__ mergeb,
                          float* __restrict__ w12T, float* __restrict__ fb) {
  int idx = blockIdx.x * 256 + threadIdx.x;
  if (idx < 16384) {
    int which = idx >> 13;
    int r = idx & 8191;
    int e = r >> 7, o = r & 127;
    float a = 0.f;
#pragma unroll 8
    for (int d = 0; d < 64; ++d)
      a += mergew[o * 128 + which * 64 + d] * ngprojw[d * 64 + e];
    w12T[idx] = a;
  } else if (idx < 16384 + 128) {
    int o = idx - 16384;
    float a = mergeb[o];
#pragma unroll 8
    for (int d = 0; d < 64; ++d)
      a += (mergew[o * 128 + d] + mergew[o * 128 + 64 + d]) * ngprojb[d];
    fb[o] = a;
  }
}

// ---------------- K1: grouped 8x8/stride8 conv -> uni [B][32][32][64] ----------------
__global__ void k_uniconv(const float* __restrict__ x, const float* __restrict__ uw,
                          const float* __restrict__ ub, float* __restrict__ uni) {
  int bidx = blockIdx.x;               // b*1024 + oh*32 + ow
  int b = bidx >> 10, oh = (bidx >> 5) & 31, ow = bidx & 31;
  int d = threadIdx.x;                 // input channel 0..127
  const float* xb = x + (((size_t)((b << 16) + ((oh << 3) << 8) + (ow << 3))) << 7) + d;
  const float* w = uw + d * 64;
  float acc = 0.f;
#pragma unroll
  for (int kh = 0; kh < 8; ++kh)
#pragma unroll
    for (int kw = 0; kw < 8; ++kw)
      acc += xb[(size_t)(((kh << 8) + kw)) << 7] * w[kh * 8 + kw];
  acc += __shfl_xor(acc, 1);
  if (!(d & 1)) uni[((size_t)bidx << 6) + (d >> 1)] = acc + ub[d >> 1];
}

// ---------------- K2: ngram path, 8 windows/block, LDS-staged weights ----------------
__global__ void __launch_bounds__(256, 1)
k_ngram(const float* __restrict__ uni, const float* __restrict__ ngqkvw,
        const float* __restrict__ ngqkvb, const float* __restrict__ ngbias,
        const float* __restrict__ w12T, const float* __restrict__ fbg,
        float* __restrict__ ctx) {
  extern __shared__ float sm[];
  float* qkvT = sm;                     // 12288
  float* w1T  = qkvT + 12288;           // 8192
  float* w2T  = w1T + 8192;             // 8192
  float* tokl = w2T + 8192;             // 2304
  float* qs   = tokl + 2304;            // 6912
  float* prs  = qs + 6912;              // 256
  float* avgl = prs + 256;              // 1024
  float* ngb  = avgl + 1024;            // 192
  float* fbs  = ngb + 192;              // 128
  float* nbias= fbs + 128;              // 36

  const int t = threadIdx.x;
  const int bidx = blockIdx.x;
  const int b = bidx >> 7, ii = (bidx >> 2) & 31, jq = bidx & 3;
  const int j0 = jq * 8;

#pragma unroll
  for (int it = 0; it < 12; ++it) {
    int f = it * 256 + t;
    int o = f >> 4, c4 = (f & 15) << 2;
    float4 v = *(const float4*)(ngqkvw + o * 64 + c4);
    float s = (o < 64) ? 0.25f : 1.f;
    qkvT[(c4 + 0) * 192 + o] = v.x * s;
    qkvT[(c4 + 1) * 192 + o] = v.y * s;
    qkvT[(c4 + 2) * 192 + o] = v.z * s;
    qkvT[(c4 + 3) * 192 + o] = v.w * s;
  }
#pragma unroll
  for (int it = 0; it < 16; ++it) {
    int f = (it * 256 + t) << 2;
    *(float4*)(w1T + f) = *(const float4*)(w12T + f);
  }
  if (t < 192) ngb[t] = ngqkvb[t] * (t < 64 ? 0.25f : 1.f);
  if (t < 128) fbs[t] = fbg[t];
  if (t < 36)  nbias[t] = ngbias[t];
  {
    int w = t >> 6, lane = t & 63;
    int dir = w >> 1, rr = w & 1;
    int pi = ii + rr;
    int srcr = (dir == 0) ? ((pi < 32) ? pi : 30) : ((pi == 0) ? 1 : pi - 1);
#pragma unroll
    for (int cc = 0; cc < 9; ++cc) {
      int pj = j0 + cc;
      int srcc = (dir == 0) ? ((pj < 32) ? pj : 30) : ((pj == 0) ? 1 : pj - 1);
      tokl[((dir * 2 + rr) * 9 + cc) * 64 + lane] =
          uni[(size_t)((b * 32 + srcr) * 32 + srcc) * 64 + lane];
    }
  }
  __syncthreads();

  {
    int w = t >> 6, lane = t & 63;
    for (int itp = 0; itp < 9; ++itp) {
      int pos = itp * 4 + w;
      const float* tk = tokl + pos * 64;
      float a0 = ngb[lane], a1 = ngb[64 + lane], a2 = ngb[128 + lane];
#pragma unroll 4
      for (int c = 0; c < 64; ++c) {
        float tv = tk[c];
        const float* qr = qkvT + c * 192;
        a0 += qr[lane] * tv;
        a1 += qr[64 + lane] * tv;
        a2 += qr[128 + lane] * tv;
      }
      float* dst = qs + pos * 192;
      dst[lane] = a0; dst[64 + lane] = a1; dst[128 + lane] = a2;
    }
  }
  __syncthreads();

  {
    int dw = t >> 4;
    int idx = t & 15, h = idx >> 2, p = idx & 3;
    int dir = dw >> 3, jl = dw & 7;
    const float* qp = qs + ((dir * 2 + (p >> 1)) * 9 + jl + (p & 1)) * 192 + h * 16;
    float s[4];
#pragma unroll
    for (int m = 0; m < 4; ++m) {
      const float* km = qs + ((dir * 2 + (m >> 1)) * 9 + jl + (m & 1)) * 192 + 64 + h * 16;
      float a = 0.f;
#pragma unroll
      for (int e = 0; e < 16; ++e) a += qp[e] * km[e];
      int bi2 = ((p >> 1) - (m >> 1) + 1) * 3 + ((p & 1) - (m & 1) + 1);
      s[m] = a + nbias[bi2 * 4 + h];
    }
    float mx = fmaxf(fmaxf(s[0], s[1]), fmaxf(s[2], s[3]));
    float e0 = __expf(s[0] - mx), e1 = __expf(s[1] - mx);
    float e2 = __expf(s[2] - mx), e3 = __expf(s[3] - mx);
    float inv = 1.f / (e0 + e1 + e2 + e3);
    float p0 = e0 * inv, p1 = e1 * inv, p2 = e2 * inv, p3 = e3 * inv;
    p0 += __shfl_xor(p0, 1); p0 += __shfl_xor(p0, 2);
    p1 += __shfl_xor(p1, 1); p1 += __shfl_xor(p1, 2);
    p2 += __shfl_xor(p2, 1); p2 += __shfl_xor(p2, 2);
    p3 += __shfl_xor(p3, 1); p3 += __shfl_xor(p3, 2);
    if (p == 0) {
      float* d = prs + (dw * 4 + h) * 4;
      d[0] = p0; d[1] = p1; d[2] = p2; d[3] = p3;
    }
  }
  __syncthreads();

  {
    int w = t >> 6, lane = t & 63;
#pragma unroll
    for (int it = 0; it < 4; ++it) {
      int dw = it * 4 + w;
      int dir = dw >> 3, jl = dw & 7;
      int h = lane >> 4;
      float a = 0.f;
#pragma unroll
      for (int m = 0; m < 4; ++m) {
        float pm = prs[(dw * 4 + h) * 4 + m];
        float vv = qs[((dir * 2 + (m >> 1)) * 9 + jl + (m & 1)) * 192 + 128 + lane];
        a += pm * vv;
      }
      avgl[dw * 64 + lane] = a * 0.25f;
    }
  }
  __syncthreads();

  {
#pragma unroll
    for (int it = 0; it < 4; ++it) {
      int id = it * 256 + t;
      int win = id >> 7, o = id & 127;
      const float* af = avgl + win * 64;
      const float* ab = avgl + (8 + win) * 64;
      float a = fbs[o];
#pragma unroll 4
      for (int c = 0; c < 64; ++c)
        a += w1T[c * 128 + o] * af[c] + w2T[c * 128 + o] * ab[c];
      int j = j0 + win;
      ctx[((size_t)((b * 32 + ii) * 32 + j)) * 128 + o] = a;
    }
  }
}

// ---------------- K3: fused window attention + LN + FFN + LN ----------------
// 1024 threads (16 waves) per window -> 4 waves/SIMD at 1 block/CU.
// LDS map IDENTICAL to passing R8 (96 KiB); Rf/Ff stay based at 48K:
//  [0,16K)   Xbf  [64][128] bf16 swz : tokens (x+ctx) -> later x1 bf16
//  [16K,32K) QO   [64][128] bf16 swz : Q then O  | Hl [64][256] with Kl in FFN
//  [32K,48K) Kl   [64][128] bf16 swz
//  [48K,64K) Vt   [128][64] bf16 swz  | Rf/Ff f32 [64][130] after attn (spans into Pl)
//  [64K,96K) Pl   [4][64][64] bf16 swz (per-head; 4 waves own disjoint row quarters)
__global__ void __launch_bounds__(1024, 2)
k_main(const float* __restrict__ xin, const float* __restrict__ ctx,
       const __bf16* __restrict__ pk_qkv, const __bf16* __restrict__ pk_wv,
       const __bf16* __restrict__ pk_proj, const __bf16* __restrict__ pk_fc1,
       const __bf16* __restrict__ pk_fc2,
       const float* __restrict__ qkvb, const float* __restrict__ projb,
       const float* __restrict__ bt,
       const float* __restrict__ n1g, const float* __restrict__ n1b,
       const float* __restrict__ n2g, const float* __restrict__ n2b,
       const float* __restrict__ fc1b, const float* __restrict__ fc2b,
       float* __restrict__ outp) {
  extern __shared__ char smem[];
  __bf16* Xbf = (__bf16*)smem;
  __bf16* QO  = (__bf16*)(smem + 16 * 1024);
  __bf16* Kl  = (__bf16*)(smem + 32 * 1024);
  __bf16* Vt  = (__bf16*)(smem + 48 * 1024);
  __bf16* Pl  = (__bf16*)(smem + 64 * 1024);
  float*  Rf  = (float*)(smem + 48 * 1024);   // [64][130] f32 (over dead Vt+Pl-head)
  __bf16* Hl  = (__bf16*)(smem + 16 * 1024);  // [64][256] bf16 swz (over dead QO+Kl)
  float*  Ff  = (float*)(smem + 48 * 1024);   // [64][130] f32

  const int widx = blockIdx.x;
  const int b = widx >> 10, wi = (widx >> 5) & 31, wj = widx & 31;
  const int tid = threadIdx.x;
  const int lane = tid & 63, wv = tid >> 6;   // 16 waves
  const int lm = lane & 15, lg = lane >> 4;

  // x1 (= x + LN(R)) for this thread's 8 channels, in regs from phase 5 to 8.
  float xr[8];

  // ---- Phase 0: load tokens (x + ctx) -> Xbf; thread = (row n, chunk q16) ----
  {
    int n = tid >> 4, c = tid & 15;
    int ts1 = n >> 3, ts2 = n & 7;
    int hh = ((wi << 3) + ts1 + 4) & 255;
    int ww = ((wj << 3) + ts2 + 4) & 255;
    const float* xs = xin + (((size_t)((b << 16) + (hh << 8) + ww)) << 7) + (c << 3);
    const float* cs = ctx + (((size_t)((((b << 5) + (hh >> 3)) << 5) + (ww >> 3))) << 7) + (c << 3);
    float4 xa = *(const float4*)xs;
    float4 xb = *(const float4*)(xs + 4);
    float4 ca = *(const float4*)cs;
    float4 cb = *(const float4*)(cs + 4);
    float v[8];
    v[0] = xa.x + ca.x; v[1] = xa.y + ca.y; v[2] = xa.z + ca.z; v[3] = xa.w + ca.w;
    v[4] = xb.x + cb.x; v[5] = xb.y + cb.y; v[6] = xb.z + cb.z; v[7] = xb.w + cb.w;
    bf16x8 p8;
#pragma unroll
    for (int e = 0; e < 8; ++e) p8[e] = (__bf16)v[e];
    *(bf16x8*)(Xbf + (n << 7) + ((c ^ (n & 7)) << 3)) = p8;
  }
  __syncthreads();

  // ---- Phase 1a: Q,K = X @ Wqk (wave -> 1 ntile of 16 cols) ----
  {
    int ntG = wv;                           // 0..15 over 256 q/k cols
    int col = (ntG << 4) + lm;
    float bias = (col < 128) ? qkvb[col] * QSCALE : qkvb[col];
    __bf16* dst = (col < 128) ? QO : Kl;
    int cc = col & 127;
    for (int mt = 0; mt < 4; ++mt) {
      bf16x8 af[4];
#pragma unroll
      for (int ks = 0; ks < 4; ++ks) af[ks] = ld_tile(Xbf, 16, mt * 16, ks * 4, lane);
      f32x4 acc = {0.f, 0.f, 0.f, 0.f};
#pragma unroll
      for (int ks = 0; ks < 4; ++ks)
        acc = mfma16(af[ks], ld_pack(pk_qkv, ntG, ks, 4, lane), acc);
#pragma unroll
      for (int r = 0; r < 4; ++r) {
        int row = mt * 16 + lg * 4 + r;
        dst[swz_idx(row, cc, 16)] = (__bf16)(acc[r] + bias);
      }
    }
  }
  // ---- Phase 1b: V^T = Wv @ X^T (wave pair per ch-tile; nt split) ----
  {
    int mtG = wv >> 1;                      // ch tile 0..7
    bf16x8 af[4];
#pragma unroll
    for (int ks = 0; ks < 4; ++ks) af[ks] = ld_pack(pk_wv, mtG, ks, 4, lane);
#pragma unroll
    for (int nt2 = 0; nt2 < 2; ++nt2) {
      int nt = ((wv & 1) << 1) + nt2;       // own 2 of 4 token tiles
      f32x4 acc = {0.f, 0.f, 0.f, 0.f};
#pragma unroll
      for (int ks = 0; ks < 4; ++ks)
        acc = mfma16(af[ks], ld_tile(Xbf, 16, nt * 16, ks * 4, lane), acc);
      int tok = (nt << 4) + lm;
#pragma unroll
      for (int r = 0; r < 4; ++r) {
        int ch = (mtG << 4) + lg * 4 + r;
        Vt[swz_idx(ch, tok, 8)] = (__bf16)(acc[r] + qkvb[256 + ch]);
      }
    }
  }
  __syncthreads();

  // ---- Phase 2: scores + softmax. Wave = (head h, row-quarter mq) ----
  float rinv[4];
  const int h = wv >> 2, mq = wv & 3;       // head, 16-row quarter
  __bf16* Pme = Pl + (h << 12);             // head's P buffer (quarters disjoint)
  {
    bf16x8 aq = ld_tile(QO, 16, mq * 16, h * 4, lane);
    bf16x8 bk[4];
#pragma unroll
    for (int nt = 0; nt < 4; ++nt)
      bk[nt] = ld_tile(Kl, 16, nt * 16, h * 4, lane);
    f32x4 sc[4];
#pragma unroll
    for (int nt = 0; nt < 4; ++nt) {
      f32x4 z = {0.f, 0.f, 0.f, 0.f};
      sc[nt] = mfma16(aq, bk[nt], z);
    }
    int s1m[4], s2m[4], regm[4];
#pragma unroll
    for (int nt = 0; nt < 4; ++nt) {
      int m = nt * 16 + lm;
      s1m[nt] = m >> 3; s2m[nt] = m & 7;
      regm[nt] = region_of(wi * 8 + s1m[nt], wj * 8 + s2m[nt]);
    }
    const bool edge = (wi == 31) || (wj == 31);
#pragma unroll
    for (int r = 0; r < 4; ++r) {
      int n = mq * 16 + lg * 4 + r;
      int s1n = n >> 3, s2n = n & 7;
      int regn = region_of(wi * 8 + s1n, wj * 8 + s2n);
      float v[4];
#pragma unroll
      for (int nt = 0; nt < 4; ++nt) {
        int idx = (s1n - s1m[nt] + 7) * 15 + (s2n - s2m[nt] + 7);
        float s = sc[nt][r] + bt[idx * 4 + h];
        if (edge && (regn != regm[nt])) s -= 100.f;
        v[nt] = s;
      }
      float mx = fmaxf(fmaxf(v[0], v[1]), fmaxf(v[2], v[3]));
#pragma unroll
      for (int d = 1; d < 16; d <<= 1) mx = fmaxf(mx, __shfl_xor(mx, d));
      float ssum = 0.f;
#pragma unroll
      for (int nt = 0; nt < 4; ++nt) { v[nt] = __expf(v[nt] - mx); ssum += v[nt]; }
#pragma unroll
      for (int d = 1; d < 16; d <<= 1) ssum += __shfl_xor(ssum, d);
      rinv[r] = 1.f / ssum;
#pragma unroll
      for (int nt = 0; nt < 4; ++nt)
        Pme[swz_idx(n, nt * 16 + lm, 8)] = (__bf16)v[nt];
    }
  }

  // ---- Phase 3: O_h = P @ V_h (own 16-row quarter; own P rows only) ----
  {
    bf16x8 ap[2], bv[2][2];
#pragma unroll
    for (int nt = 0; nt < 2; ++nt)
#pragma unroll
      for (int ks = 0; ks < 2; ++ks)
        bv[nt][ks] = ld_tile(Vt, 8, h * 32 + nt * 16, ks * 4, lane);
#pragma unroll
    for (int ks = 0; ks < 2; ++ks)
      ap[ks] = ld_tile(Pme, 8, mq * 16, ks * 4, lane);
#pragma unroll
    for (int nt = 0; nt < 2; ++nt) {
      f32x4 acc = {0.f, 0.f, 0.f, 0.f};
      acc = mfma16(ap[0], bv[nt][0], acc);
      acc = mfma16(ap[1], bv[nt][1], acc);
      int cc = h * 32 + nt * 16 + lm;
#pragma unroll
      for (int r = 0; r < 4; ++r) {
        int row = mq * 16 + lg * 4 + r;
        QO[swz_idx(row, cc, 16)] = (__bf16)(acc[r] * rinv[r]);
      }
    }
  }
  __syncthreads();

  // ---- Phase 4: R = O @ Wproj + b -> Rf f32 (wave pair per ntile; mt split) ----
  {
    int ntG = wv >> 1;
    int col = (ntG << 4) + lm;
    float pb = projb[col];
#pragma unroll
    for (int mt2 = 0; mt2 < 2; ++mt2) {
      int mt = ((wv & 1) << 1) + mt2;
      bf16x8 ao[4];
#pragma unroll
      for (int ks = 0; ks < 4; ++ks) ao[ks] = ld_tile(QO, 16, mt * 16, ks * 4, lane);
      f32x4 acc = {0.f, 0.f, 0.f, 0.f};
#pragma unroll
      for (int ks = 0; ks < 4; ++ks)
        acc = mfma16(ao[ks], ld_pack(pk_proj, ntG, ks, 4, lane), acc);
#pragma unroll
      for (int r = 0; r < 4; ++r) {
        int row = mt * 16 + lg * 4 + r;
        Rf[row * XF_LD + col] = acc[r] + pb;
      }
    }
  }
  __syncthreads();

  // ---- Phase 5: x1 = x + LN(R); pristine x reloaded; x1 -> xr regs + Xbf ----
  {
    int n = tid >> 4, c = tid & 15;
    int ts1 = n >> 3, ts2 = n & 7;
    int hh = ((wi << 3) + ts1 + 4) & 255;
    int ww = ((wj << 3) + ts2 + 4) & 255;
    const float* xp = xin + (((size_t)((b << 16) + (hh << 8) + ww)) << 7) + (c << 3);
    float xv[8];
    {
      float4 v4 = *(const float4*)xp;
      float4 w4 = *(const float4*)(xp + 4);
      xv[0] = v4.x; xv[1] = v4.y; xv[2] = v4.z; xv[3] = v4.w;
      xv[4] = w4.x; xv[5] = w4.y; xv[6] = w4.z; xv[7] = w4.w;
    }
    const float* rrow = Rf + n * XF_LD + (c << 3);
    float vals[8];
    float sum1 = 0.f, sum2 = 0.f;
#pragma unroll
    for (int jj = 0; jj < 8; ++jj) { float v = rrow[jj]; vals[jj] = v; sum1 += v; sum2 += v * v; }
    sum1 += __shfl_xor(sum1, 1); sum1 += __shfl_xor(sum1, 2);
    sum1 += __shfl_xor(sum1, 4); sum1 += __shfl_xor(sum1, 8);
    sum2 += __shfl_xor(sum2, 1); sum2 += __shfl_xor(sum2, 2);
    sum2 += __shfl_xor(sum2, 4); sum2 += __shfl_xor(sum2, 8);
    float mean = sum1 * 0.0078125f;
    float var = sum2 * 0.0078125f - mean * mean;
    float rstd = rsqrtf(var + 1e-5f);
    bf16x8 p8;
#pragma unroll
    for (int e = 0; e < 8; ++e) {
      int d = (c << 3) + e;
      float ln = (vals[e] - mean) * rstd * n1g[d] + n1b[d];
      float x1 = xv[e] + ln;
      xr[e] = x1;
      p8[e] = (__bf16)x1;
    }
    *(bf16x8*)(Xbf + (n << 7) + ((c ^ (n & 7)) << 3)) = p8;
  }
  __syncthreads();

  // ---- Phase 6: H = gelu(x1 @ Wfc1 + b) -> Hl bf16 swz (wave -> 1 ntile) ----
  {
    int ntG = wv;                           // 0..15 over 256 cols
    int col = (ntG << 4) + lm;
    float b1 = fc1b[col];
    for (int mt = 0; mt < 4; ++mt) {
      bf16x8 a1[4];
#pragma unroll
      for (int ks = 0; ks < 4; ++ks) a1[ks] = ld_tile(Xbf, 16, mt * 16, ks * 4, lane);
      f32x4 acc = {0.f, 0.f, 0.f, 0.f};
#pragma unroll
      for (int ks = 0; ks < 4; ++ks)
        acc = mfma16(a1[ks], ld_pack(pk_fc1, ntG, ks, 4, lane), acc);
#pragma unroll
      for (int r = 0; r < 4; ++r) {
        int row = mt * 16 + lg * 4 + r;
        float hv = acc[r] + b1;
        hv = 0.5f * hv * (1.f + erff(hv * 0.70710678118654752f));
        Hl[swz_idx(row, col, 32)] = (__bf16)hv;
      }
    }
  }
  __syncthreads();

  // ---- Phase 7: F = H @ Wfc2 + b -> Ff f32 (wave pair per ntile; mt split) ----
  {
    int ntG = wv >> 1;
    int col = (ntG << 4) + lm;
    float b2 = fc2b[col];
#pragma unroll
    for (int mt2 = 0; mt2 < 2; ++mt2) {
      int mt = ((wv & 1) << 1) + mt2;
      bf16x8 a2[8];
#pragma unroll
      for (int ks = 0; ks < 8; ++ks) a2[ks] = ld_tile(Hl, 32, mt * 16, ks * 4, lane);
      f32x4 acc = {0.f, 0.f, 0.f, 0.f};
#pragma unroll
      for (int ks = 0; ks < 8; ++ks)
        acc = mfma16(a2[ks], ld_pack(pk_fc2, ntG, ks, 8, lane), acc);
#pragma unroll
      for (int r = 0; r < 4; ++r) {
        int row = mt * 16 + lg * 4 + r;
        Ff[row * XF_LD + col] = acc[r] + b2;
      }
    }
  }
  __syncthreads();

  // ---- Phase 8: out = x1 + LN(F), scatter back to original positions ----
  {
    int n = tid >> 4, c = tid & 15;
    const float* frow = Ff + n * XF_LD + (c << 3);
    float vals[8];
    float sum1 = 0.f, sum2 = 0.f;
#pragma unroll
    for (int jj = 0; jj < 8; ++jj) { float v = frow[jj]; vals[jj] = v; sum1 += v; sum2 += v * v; }
    sum1 += __shfl_xor(sum1, 1); sum1 += __shfl_xor(sum1, 2);
    sum1 += __shfl_xor(sum1, 4); sum1 += __shfl_xor(sum1, 8);
    sum2 += __shfl_xor(sum2, 1); sum2 += __shfl_xor(sum2, 2);
    sum2 += __shfl_xor(sum2, 4); sum2 += __shfl_xor(sum2, 8);
    float mean = sum1 * 0.0078125f;
    float var = sum2 * 0.0078125f - mean * mean;
    float rstd = rsqrtf(var + 1e-5f);
    int ts1 = n >> 3, ts2 = n & 7;
    int hh = ((wi << 3) + ts1 + 4) & 255;
    int ww = ((wj << 3) + ts2 + 4) & 255;
    float* op = outp + (((size_t)((b << 16) + (hh << 8) + ww)) << 7) + (c << 3);
    int dbase = (c << 3);
    float4 o4a, o4b;
    o4a.x = xr[0] + (vals[0] - mean) * rstd * n2g[dbase + 0] + n2b[dbase + 0];
    o4a.y = xr[1] + (vals[1] - mean) * rstd * n2g[dbase + 1] + n2b[dbase + 1];
    o4a.z = xr[2] + (vals[2] - mean) * rstd * n2g[dbase + 2] + n2b[dbase + 2];
    o4a.w = xr[3] + (vals[3] - mean) * rstd * n2g[dbase + 3] + n2b[dbase + 3];
    o4b.x = xr[4] + (vals[4] - mean) * rstd * n2g[dbase + 4] + n2b[dbase + 4];
    o4b.y = xr[5] + (vals[5] - mean) * rstd * n2g[dbase + 5] + n2b[dbase + 5];
    o4b.z = xr[6] + (vals[6] - mean) * rstd * n2g[dbase + 6] + n2b[dbase + 6];
    o4b.w = xr[7] + (vals[7] - mean) * rstd * n2g[dbase + 7] + n2b[dbase + 7];
    *(float4*)op = o4a;
    *(float4*)(op + 4) = o4b;
  }
}

// ---------------- launch ----------------
extern "C" void kernel_launch(void* const* d_in, const int* in_sizes, int n_in,
                              void* d_out, int out_size, void* d_ws, size_t ws_size,
                              hipStream_t stream) {
  const float* x      = (const float*)d_in[0];
  const float* uni_w  = (const float*)d_in[1];
  const float* uni_b  = (const float*)d_in[2];
  const float* ngqkvw = (const float*)d_in[3];
  const float* ngqkvb = (const float*)d_in[4];
  const float* ngprojw= (const float*)d_in[5];
  const float* ngprojb= (const float*)d_in[6];
  const float* ngbias = (const float*)d_in[7];
  const float* mergew = (const float*)d_in[8];
  const float* mergeb = (const float*)d_in[9];
  const float* qkvw   = (const float*)d_in[10];
  const float* qkvb   = (const float*)d_in[11];
  const float* projw  = (const float*)d_in[12];
  const float* projb  = (const float*)d_in[13];
  const float* bt     = (const float*)d_in[14];
  const float* n1g    = (const float*)d_in[15];
  const float* n1b    = (const float*)d_in[16];
  const float* n2g    = (const float*)d_in[17];
  const float* n2b    = (const float*)d_in[18];
  const float* fc1w   = (const float*)d_in[19];
  const float* fc1b   = (const float*)d_in[20];
  const float* fc2w   = (const float*)d_in[21];
  const float* fc2b   = (const float*)d_in[22];

  char* ws = (char*)d_ws;
  float*  uni = (float*)ws;                   // 1 MiB : [4][32][32][64]
  float*  ctx = (float*)(ws + (1 << 20));     // 2 MiB : [4][32][32][128]
  __bf16* pk  = (__bf16*)(ws + (3 << 20));    // 256 KiB packed weights
  __bf16* pk_qkv  = pk;
  __bf16* pk_wv   = pk + 32768;
  __bf16* pk_proj = pk + 49152;
  __bf16* pk_fc1  = pk + 65536;
  __bf16* pk_fc2  = pk + 98304;
  float*  w12T = (float*)(ws + (7 << 19));    // 3.5 MiB: [2][64][128] fused ctx weights
  float*  fb   = w12T + 16384;                // fused ctx bias [128]

  k_pack<<<512, 256, 0, stream>>>(qkvw, projw, fc1w, fc2w, pk);
  k_packctx<<<65, 256, 0, stream>>>(ngprojw, ngprojb, mergew, mergeb, w12T, fb);
  k_uniconv<<<4096, 128, 0, stream>>>(x, uni_w, uni_b, uni);
  k_ngram<<<512, 256, 158096, stream>>>(uni, ngqkvw, ngqkvb, ngbias, w12T, fb, ctx);
  k_main<<<4096, 1024, 98304, stream>>>(x, ctx, pk_qkv, pk_wv, pk_proj, pk_fc1, pk_fc2,
                                        qkvb, projb, bt, n1g, n1b, n2g, n2b, fc1b, fc2b,
                                        (float*)d_out);
}

// Round 10
// 332.447 us; speedup vs baseline: 4.8740x; 1.0495x over previous
//
#include <hip/hip_runtime.h>

// ---------------- types / helpers ----------------
typedef __bf16 bf16x8 __attribute__((ext_vector_type(8)));
typedef float  f32x4  __attribute__((ext_vector_type(4)));

#define QSCALE 0.17677669529663687f   // 32^-0.5 (main attn head_dim=32)
#define XF_LD 130                     // f32 tile stride: 130 ≡ 2 (mod 32) -> 4-way max

__device__ __forceinline__ f32x4 mfma16(bf16x8 a, bf16x8 b, f32x4 c) {
  return __builtin_amdgcn_mfma_f32_16x16x32_bf16(a, b, c, 0, 0, 0);
}

// row-major [rows][rowChunks*8] bf16 tile with XOR-swizzled 16B chunks
__device__ __forceinline__ int swz_idx(int row, int col, int rowChunks) {
  return row * (rowChunks << 3) + ((((col >> 3) ^ (row & 7)) << 3) | (col & 7));
}

// A/B fragment load from swizzled row-major LDS tile.
__device__ __forceinline__ bf16x8 ld_tile(const __bf16* t, int rowChunks,
                                          int rowBase, int chunkBase, int lane) {
  int row = rowBase + (lane & 15);
  int c = (chunkBase + (lane >> 4)) ^ (row & 7);
  return *(const bf16x8*)(t + row * (rowChunks << 3) + (c << 3));
}

// fragment load from pre-packed global weights (coalesced 1KiB per wave)
__device__ __forceinline__ bf16x8 ld_pack(const __bf16* pk, int nt, int ks,
                                          int ksteps, int lane) {
  int idx = ((nt * ksteps + ks) * 64 + lane) * 8;
  return *(const bf16x8*)(pk + idx);
}

// ---------------- K_prep: fused uniconv + weight packs + bias/mask table ------
// blocks [0,2048): uniconv (2 output pixels / 256-thr block)
// blocks [2048,2560): pack main weights -> bf16 fragment order
// blocks [2560,2816): build btf[variant][h][n][m] bias+mask table (rolled coords)
// blocks [2816,2881): fused ngram proj+merge weights
__global__ void k_prep(const float* __restrict__ qkvw, const float* __restrict__ projw,
                       const float* __restrict__ fc1w, const float* __restrict__ fc2w,
                       const float* __restrict__ ngprojw, const float* __restrict__ ngprojb,
                       const float* __restrict__ mergew, const float* __restrict__ mergeb,
                       const float* __restrict__ bt,
                       const float* __restrict__ x, const float* __restrict__ uw,
                       const float* __restrict__ ub,
                       __bf16* __restrict__ pk, float* __restrict__ w12T,
                       float* __restrict__ fb, float* __restrict__ btf,
                       float* __restrict__ uni) {
  int blk = blockIdx.x;
  if (blk < 2048) {
    // ---- uniconv: grouped 8x8/stride8 conv -> uni [B][32][32][64] ----
    int bidx = blk * 2 + (threadIdx.x >> 7);  // b*1024 + oh*32 + ow
    int b = bidx >> 10, oh = (bidx >> 5) & 31, ow = bidx & 31;
    int d = threadIdx.x & 127;                // input channel 0..127
    const float* xb = x + (((size_t)((b << 16) + ((oh << 3) << 8) + (ow << 3))) << 7) + d;
    const float* w = uw + d * 64;
    float acc = 0.f;
#pragma unroll
    for (int kh = 0; kh < 8; ++kh)
#pragma unroll
      for (int kw = 0; kw < 8; ++kw)
        acc += xb[(size_t)(((kh << 8) + kw)) << 7] * w[kh * 8 + kw];
    acc += __shfl_xor(acc, 1);
    if (!(d & 1)) uni[((size_t)bidx << 6) + (d >> 1)] = acc + ub[d >> 1];
  } else if (blk < 2560) {
    // ---- pack main weights ----
    int i = (blk - 2048) * 256 + threadIdx.x;
    const float* src; int K; int e; int scaleQ = 0;
    if (i < 32768)      { src = qkvw;             K = 128; e = i;          scaleQ = 1; }
    else if (i < 49152) { src = qkvw + 256 * 128; K = 128; e = i - 32768; }
    else if (i < 65536) { src = projw;            K = 128; e = i - 49152; }
    else if (i < 98304) { src = fc1w;             K = 128; e = i - 65536; }
    else                { src = fc2w;             K = 256; e = i - 98304; }
    int i8 = e & 7, ln = (e >> 3) & 63, t = e >> 9;
    int ls = (K == 256) ? 3 : 2;
    int ks = t & ((1 << ls) - 1), nt = t >> ls;
    int row = (nt << 4) + (ln & 15);
    int k = (ks << 5) + ((ln >> 4) << 3) + i8;
    float v = src[row * K + k];
    if (scaleQ && row < 128) v *= QSCALE;
    pk[i] = (__bf16)v;
  } else if (blk < 2816) {
    // ---- btf: bias + shift-mask, in ROLLED window coords (matches reference) ----
    int idx = (blk - 2560) * 256 + threadIdx.x;   // v<<14 | h<<12 | n<<6 | m
    int v = idx >> 14, h = (idx >> 12) & 3, n = (idx >> 6) & 63, m = idx & 63;
    int s1n = n >> 3, s2n = n & 7, s1m = m >> 3, s2m = m & 7;
    int rpi = (s1n - s1m + 7) * 15 + (s2n - s2m + 7);
    float val = bt[rpi * 4 + h];
    if (((v & 1) && ((s1n < 4) != (s1m < 4))) ||
        ((v & 2) && ((s2n < 4) != (s2m < 4))))
      val -= 100.f;
    btf[idx] = val;
  } else {
    // ---- fused ngram proj+merge weights ----
    int idx = (blk - 2816) * 256 + threadIdx.x;
    if (idx < 16384) {
      int which = idx >> 13;
      int r = idx & 8191;
      int e = r >> 7, o = r & 127;
      float a = 0.f;
#pragma unroll 8
      for (int d = 0; d < 64; ++d)
        a += mergew[o * 128 + which * 64 + d] * ngprojw[d * 64 + e];
      w12T[idx] = a;
    } else if (idx < 16384 + 128) {
      int o = idx - 16384;
      float a = mergeb[o];
#pragma unroll 8
      for (int d = 0; d < 64; ++d)
        a += (mergew[o * 128 + d] + mergew[o * 128 + 64 + d]) * ngprojb[d];
      fb[o] = a;
    }
  }
}

// ---------------- K2: ngram path, 8 windows/block, LDS-staged weights ----------------
__global__ void __launch_bounds__(256, 1)
k_ngram(const float* __restrict__ uni, const float* __restrict__ ngqkvw,
        const float* __restrict__ ngqkvb, const float* __restrict__ ngbias,
        const float* __restrict__ w12T, const float* __restrict__ fbg,
        float* __restrict__ ctx) {
  extern __shared__ float sm[];
  float* qkvT = sm;                     // 12288
  float* w1T  = qkvT + 12288;           // 8192
  float* w2T  = w1T + 8192;             // 8192
  float* tokl = w2T + 8192;             // 2304
  float* qs   = tokl + 2304;            // 6912
  float* prs  = qs + 6912;              // 256
  float* avgl = prs + 256;              // 1024
  float* ngb  = avgl + 1024;            // 192
  float* fbs  = ngb + 192;              // 128
  float* nbias= fbs + 128;              // 36

  const int t = threadIdx.x;
  const int bidx = blockIdx.x;
  const int b = bidx >> 7, ii = (bidx >> 2) & 31, jq = bidx & 3;
  const int j0 = jq * 8;

#pragma unroll
  for (int it = 0; it < 12; ++it) {
    int f = it * 256 + t;
    int o = f >> 4, c4 = (f & 15) << 2;
    float4 v = *(const float4*)(ngqkvw + o * 64 + c4);
    float s = (o < 64) ? 0.25f : 1.f;
    qkvT[(c4 + 0) * 192 + o] = v.x * s;
    qkvT[(c4 + 1) * 192 + o] = v.y * s;
    qkvT[(c4 + 2) * 192 + o] = v.z * s;
    qkvT[(c4 + 3) * 192 + o] = v.w * s;
  }
#pragma unroll
  for (int it = 0; it < 16; ++it) {
    int f = (it * 256 + t) << 2;
    *(float4*)(w1T + f) = *(const float4*)(w12T + f);
  }
  if (t < 192) ngb[t] = ngqkvb[t] * (t < 64 ? 0.25f : 1.f);
  if (t < 128) fbs[t] = fbg[t];
  if (t < 36)  nbias[t] = ngbias[t];
  {
    int w = t >> 6, lane = t & 63;
    int dir = w >> 1, rr = w & 1;
    int pi = ii + rr;
    int srcr = (dir == 0) ? ((pi < 32) ? pi : 30) : ((pi == 0) ? 1 : pi - 1);
#pragma unroll
    for (int cc = 0; cc < 9; ++cc) {
      int pj = j0 + cc;
      int srcc = (dir == 0) ? ((pj < 32) ? pj : 30) : ((pj == 0) ? 1 : pj - 1);
      tokl[((dir * 2 + rr) * 9 + cc) * 64 + lane] =
          uni[(size_t)((b * 32 + srcr) * 32 + srcc) * 64 + lane];
    }
  }
  __syncthreads();

  {
    int w = t >> 6, lane = t & 63;
    for (int itp = 0; itp < 9; ++itp) {
      int pos = itp * 4 + w;
      const float* tk = tokl + pos * 64;
      float a0 = ngb[lane], a1 = ngb[64 + lane], a2 = ngb[128 + lane];
#pragma unroll 4
      for (int c = 0; c < 64; ++c) {
        float tv = tk[c];
        const float* qr = qkvT + c * 192;
        a0 += qr[lane] * tv;
        a1 += qr[64 + lane] * tv;
        a2 += qr[128 + lane] * tv;
      }
      float* dst = qs + pos * 192;
      dst[lane] = a0; dst[64 + lane] = a1; dst[128 + lane] = a2;
    }
  }
  __syncthreads();

  {
    int dw = t >> 4;
    int idx = t & 15, h = idx >> 2, p = idx & 3;
    int dir = dw >> 3, jl = dw & 7;
    const float* qp = qs + ((dir * 2 + (p >> 1)) * 9 + jl + (p & 1)) * 192 + h * 16;
    float s[4];
#pragma unroll
    for (int m = 0; m < 4; ++m) {
      const float* km = qs + ((dir * 2 + (m >> 1)) * 9 + jl + (m & 1)) * 192 + 64 + h * 16;
      float a = 0.f;
#pragma unroll
      for (int e = 0; e < 16; ++e) a += qp[e] * km[e];
      int bi2 = ((p >> 1) - (m >> 1) + 1) * 3 + ((p & 1) - (m & 1) + 1);
      s[m] = a + nbias[bi2 * 4 + h];
    }
    float mx = fmaxf(fmaxf(s[0], s[1]), fmaxf(s[2], s[3]));
    float e0 = __expf(s[0] - mx), e1 = __expf(s[1] - mx);
    float e2 = __expf(s[2] - mx), e3 = __expf(s[3] - mx);
    float inv = 1.f / (e0 + e1 + e2 + e3);
    float p0 = e0 * inv, p1 = e1 * inv, p2 = e2 * inv, p3 = e3 * inv;
    p0 += __shfl_xor(p0, 1); p0 += __shfl_xor(p0, 2);
    p1 += __shfl_xor(p1, 1); p1 += __shfl_xor(p1, 2);
    p2 += __shfl_xor(p2, 1); p2 += __shfl_xor(p2, 2);
    p3 += __shfl_xor(p3, 1); p3 += __shfl_xor(p3, 2);
    if (p == 0) {
      float* d = prs + (dw * 4 + h) * 4;
      d[0] = p0; d[1] = p1; d[2] = p2; d[3] = p3;
    }
  }
  __syncthreads();

  {
    int w = t >> 6, lane = t & 63;
#pragma unroll
    for (int it = 0; it < 4; ++it) {
      int dw = it * 4 + w;
      int dir = dw >> 3, jl = dw & 7;
      int h = lane >> 4;
      float a = 0.f;
#pragma unroll
      for (int m = 0; m < 4; ++m) {
        float pm = prs[(dw * 4 + h) * 4 + m];
        float vv = qs[((dir * 2 + (m >> 1)) * 9 + jl + (m & 1)) * 192 + 128 + lane];
        a += pm * vv;
      }
      avgl[dw * 64 + lane] = a * 0.25f;
    }
  }
  __syncthreads();

  {
#pragma unroll
    for (int it = 0; it < 4; ++it) {
      int id = it * 256 + t;
      int win = id >> 7, o = id & 127;
      const float* af = avgl + win * 64;
      const float* ab = avgl + (8 + win) * 64;
      float a = fbs[o];
#pragma unroll 4
      for (int c = 0; c < 64; ++c)
        a += w1T[c * 128 + o] * af[c] + w2T[c * 128 + o] * ab[c];
      int j = j0 + win;
      ctx[((size_t)((b * 32 + ii) * 32 + j)) * 128 + o] = a;
    }
  }
}

// ---------------- K3: fused window attention + LN + FFN + LN ----------------
// 1024 threads (16 waves) per window -> 4 waves/SIMD at 1 block/CU.
// LDS map IDENTICAL to passing R9 (96 KiB); Rf/Ff stay based at 48K.
__global__ void __launch_bounds__(1024, 2)
k_main(const float* __restrict__ xin, const float* __restrict__ ctx,
       const __bf16* __restrict__ pk_qkv, const __bf16* __restrict__ pk_wv,
       const __bf16* __restrict__ pk_proj, const __bf16* __restrict__ pk_fc1,
       const __bf16* __restrict__ pk_fc2,
       const float* __restrict__ qkvb, const float* __restrict__ projb,
       const float* __restrict__ btf,
       const float* __restrict__ n1g, const float* __restrict__ n1b,
       const float* __restrict__ n2g, const float* __restrict__ n2b,
       const float* __restrict__ fc1b, const float* __restrict__ fc2b,
       float* __restrict__ outp) {
  extern __shared__ char smem[];
  __bf16* Xbf = (__bf16*)smem;
  __bf16* QO  = (__bf16*)(smem + 16 * 1024);
  __bf16* Kl  = (__bf16*)(smem + 32 * 1024);
  __bf16* Vt  = (__bf16*)(smem + 48 * 1024);
  __bf16* Pl  = (__bf16*)(smem + 64 * 1024);
  float*  Rf  = (float*)(smem + 48 * 1024);   // [64][130] f32 (over dead Vt+Pl-head)
  __bf16* Hl  = (__bf16*)(smem + 16 * 1024);  // [64][256] bf16 swz (over dead QO+Kl)
  float*  Ff  = (float*)(smem + 48 * 1024);   // [64][130] f32

  const int widx = blockIdx.x;
  const int b = widx >> 10, wi = (widx >> 5) & 31, wj = widx & 31;
  const int tid = threadIdx.x;
  const int lane = tid & 63, wv = tid >> 6;   // 16 waves
  const int lm = lane & 15, lg = lane >> 4;

  // x1 (= x + LN(R)) for this thread's 8 channels, in regs from phase 5 to 8.
  float xr[8];

  // ---- Phase 0: load tokens (x + ctx) -> Xbf; thread = (row n, chunk q16) ----
  {
    int n = tid >> 4, c = tid & 15;
    int ts1 = n >> 3, ts2 = n & 7;
    int hh = ((wi << 3) + ts1 + 4) & 255;
    int ww = ((wj << 3) + ts2 + 4) & 255;
    const float* xs = xin + (((size_t)((b << 16) + (hh << 8) + ww)) << 7) + (c << 3);
    const float* cs = ctx + (((size_t)((((b << 5) + (hh >> 3)) << 5) + (ww >> 3))) << 7) + (c << 3);
    float4 xa = *(const float4*)xs;
    float4 xb = *(const float4*)(xs + 4);
    float4 ca = *(const float4*)cs;
    float4 cb = *(const float4*)(cs + 4);
    float v[8];
    v[0] = xa.x + ca.x; v[1] = xa.y + ca.y; v[2] = xa.z + ca.z; v[3] = xa.w + ca.w;
    v[4] = xb.x + cb.x; v[5] = xb.y + cb.y; v[6] = xb.z + cb.z; v[7] = xb.w + cb.w;
    bf16x8 p8;
#pragma unroll
    for (int e = 0; e < 8; ++e) p8[e] = (__bf16)v[e];
    *(bf16x8*)(Xbf + (n << 7) + ((c ^ (n & 7)) << 3)) = p8;
  }
  __syncthreads();

  // ---- Phase 1a: Q,K = X @ Wqk (wave -> 1 ntile of 16 cols) ----
  {
    int ntG = wv;                           // 0..15 over 256 q/k cols
    int col = (ntG << 4) + lm;
    float bias = (col < 128) ? qkvb[col] * QSCALE : qkvb[col];
    __bf16* dst = (col < 128) ? QO : Kl;
    int cc = col & 127;
    for (int mt = 0; mt < 4; ++mt) {
      bf16x8 af[4];
#pragma unroll
      for (int ks = 0; ks < 4; ++ks) af[ks] = ld_tile(Xbf, 16, mt * 16, ks * 4, lane);
      f32x4 acc = {0.f, 0.f, 0.f, 0.f};
#pragma unroll
      for (int ks = 0; ks < 4; ++ks)
        acc = mfma16(af[ks], ld_pack(pk_qkv, ntG, ks, 4, lane), acc);
#pragma unroll
      for (int r = 0; r < 4; ++r) {
        int row = mt * 16 + lg * 4 + r;
        dst[swz_idx(row, cc, 16)] = (__bf16)(acc[r] + bias);
      }
    }
  }
  // ---- Phase 1b: V^T = Wv @ X^T (wave pair per ch-tile; nt split) ----
  {
    int mtG = wv >> 1;                      // ch tile 0..7
    bf16x8 af[4];
#pragma unroll
    for (int ks = 0; ks < 4; ++ks) af[ks] = ld_pack(pk_wv, mtG, ks, 4, lane);
#pragma unroll
    for (int nt2 = 0; nt2 < 2; ++nt2) {
      int nt = ((wv & 1) << 1) + nt2;       // own 2 of 4 token tiles
      f32x4 acc = {0.f, 0.f, 0.f, 0.f};
#pragma unroll
      for (int ks = 0; ks < 4; ++ks)
        acc = mfma16(af[ks], ld_tile(Xbf, 16, nt * 16, ks * 4, lane), acc);
      int tok = (nt << 4) + lm;
#pragma unroll
      for (int r = 0; r < 4; ++r) {
        int ch = (mtG << 4) + lg * 4 + r;
        Vt[swz_idx(ch, tok, 8)] = (__bf16)(acc[r] + qkvb[256 + ch]);
      }
    }
  }
  __syncthreads();

  // ---- Phase 2: scores + softmax. Wave = (head h, row-quarter mq) ----
  float rinv[4];
  const int h = wv >> 2, mq = wv & 3;       // head, 16-row quarter
  __bf16* Pme = Pl + (h << 12);             // head's P buffer (quarters disjoint)
  {
    bf16x8 aq = ld_tile(QO, 16, mq * 16, h * 4, lane);
    bf16x8 bk[4];
#pragma unroll
    for (int nt = 0; nt < 4; ++nt)
      bk[nt] = ld_tile(Kl, 16, nt * 16, h * 4, lane);
    f32x4 sc[4];
#pragma unroll
    for (int nt = 0; nt < 4; ++nt) {
      f32x4 z = {0.f, 0.f, 0.f, 0.f};
      sc[nt] = mfma16(aq, bk[nt], z);
    }
    // precomputed bias+mask table: [variant][h][64][64], coalesced over lm
    const int variant = (wi == 31 ? 1 : 0) | (wj == 31 ? 2 : 0);
    const float* btw = btf + (((variant << 2) + h) << 12);
#pragma unroll
    for (int r = 0; r < 4; ++r) {
      int n = mq * 16 + lg * 4 + r;
      const float* brow = btw + (n << 6) + lm;
      float v[4];
#pragma unroll
      for (int nt = 0; nt < 4; ++nt)
        v[nt] = sc[nt][r] + brow[nt << 4];
      float mx = fmaxf(fmaxf(v[0], v[1]), fmaxf(v[2], v[3]));
#pragma unroll
      for (int d = 1; d < 16; d <<= 1) mx = fmaxf(mx, __shfl_xor(mx, d));
      float ssum = 0.f;
#pragma unroll
      for (int nt = 0; nt < 4; ++nt) { v[nt] = __expf(v[nt] - mx); ssum += v[nt]; }
#pragma unroll
      for (int d = 1; d < 16; d <<= 1) ssum += __shfl_xor(ssum, d);
      rinv[r] = 1.f / ssum;
#pragma unroll
      for (int nt = 0; nt < 4; ++nt)
        Pme[swz_idx(n, nt * 16 + lm, 8)] = (__bf16)v[nt];
    }
  }

  // ---- Phase 3: O_h = P @ V_h (own 16-row quarter; own P rows only) ----
  {
    bf16x8 ap[2], bv[2][2];
#pragma unroll
    for (int nt = 0; nt < 2; ++nt)
#pragma unroll
      for (int ks = 0; ks < 2; ++ks)
        bv[nt][ks] = ld_tile(Vt, 8, h * 32 + nt * 16, ks * 4, lane);
#pragma unroll
    for (int ks = 0; ks < 2; ++ks)
      ap[ks] = ld_tile(Pme, 8, mq * 16, ks * 4, lane);
#pragma unroll
    for (int nt = 0; nt < 2; ++nt) {
      f32x4 acc = {0.f, 0.f, 0.f, 0.f};
      acc = mfma16(ap[0], bv[nt][0], acc);
      acc = mfma16(ap[1], bv[nt][1], acc);
      int cc = h * 32 + nt * 16 + lm;
#pragma unroll
      for (int r = 0; r < 4; ++r) {
        int row = mq * 16 + lg * 4 + r;
        QO[swz_idx(row, cc, 16)] = (__bf16)(acc[r] * rinv[r]);
      }
    }
  }
  __syncthreads();

  // ---- Phase 4: R = O @ Wproj + b -> Rf f32 (wave pair per ntile; mt split) ----
  {
    int ntG = wv >> 1;
    int col = (ntG << 4) + lm;
    float pb = projb[col];
#pragma unroll
    for (int mt2 = 0; mt2 < 2; ++mt2) {
      int mt = ((wv & 1) << 1) + mt2;
      bf16x8 ao[4];
#pragma unroll
      for (int ks = 0; ks < 4; ++ks) ao[ks] = ld_tile(QO, 16, mt * 16, ks * 4, lane);
      f32x4 acc = {0.f, 0.f, 0.f, 0.f};
#pragma unroll
      for (int ks = 0; ks < 4; ++ks)
        acc = mfma16(ao[ks], ld_pack(pk_proj, ntG, ks, 4, lane), acc);
#pragma unroll
      for (int r = 0; r < 4; ++r) {
        int row = mt * 16 + lg * 4 + r;
        Rf[row * XF_LD + col] = acc[r] + pb;
      }
    }
  }
  __syncthreads();

  // ---- Phase 5: x1 = x + LN(R); pristine x reloaded; x1 -> xr regs + Xbf ----
  {
    int n = tid >> 4, c = tid & 15;
    int ts1 = n >> 3, ts2 = n & 7;
    int hh = ((wi << 3) + ts1 + 4) & 255;
    int ww = ((wj << 3) + ts2 + 4) & 255;
    const float* xp = xin + (((size_t)((b << 16) + (hh << 8) + ww)) << 7) + (c << 3);
    float xv[8];
    {
      float4 v4 = *(const float4*)xp;
      float4 w4 = *(const float4*)(xp + 4);
      xv[0] = v4.x; xv[1] = v4.y; xv[2] = v4.z; xv[3] = v4.w;
      xv[4] = w4.x; xv[5] = w4.y; xv[6] = w4.z; xv[7] = w4.w;
    }
    const float* rrow = Rf + n * XF_LD + (c << 3);
    float vals[8];
    float sum1 = 0.f, sum2 = 0.f;
#pragma unroll
    for (int jj = 0; jj < 8; ++jj) { float v = rrow[jj]; vals[jj] = v; sum1 += v; sum2 += v * v; }
    sum1 += __shfl_xor(sum1, 1); sum1 += __shfl_xor(sum1, 2);
    sum1 += __shfl_xor(sum1, 4); sum1 += __shfl_xor(sum1, 8);
    sum2 += __shfl_xor(sum2, 1); sum2 += __shfl_xor(sum2, 2);
    sum2 += __shfl_xor(sum2, 4); sum2 += __shfl_xor(sum2, 8);
    float mean = sum1 * 0.0078125f;
    float var = sum2 * 0.0078125f - mean * mean;
    float rstd = rsqrtf(var + 1e-5f);
    bf16x8 p8;
#pragma unroll
    for (int e = 0; e < 8; ++e) {
      int d = (c << 3) + e;
      float ln = (vals[e] - mean) * rstd * n1g[d] + n1b[d];
      float x1 = xv[e] + ln;
      xr[e] = x1;
      p8[e] = (__bf16)x1;
    }
    *(bf16x8*)(Xbf + (n << 7) + ((c ^ (n & 7)) << 3)) = p8;
  }
  __syncthreads();

  // ---- Phase 6: H = gelu(x1 @ Wfc1 + b) -> Hl bf16 swz (wave -> 1 ntile) ----
  {
    int ntG = wv;                           // 0..15 over 256 cols
    int col = (ntG << 4) + lm;
    float b1 = fc1b[col];
    for (int mt = 0; mt < 4; ++mt) {
      bf16x8 a1[4];
#pragma unroll
      for (int ks = 0; ks < 4; ++ks) a1[ks] = ld_tile(Xbf, 16, mt * 16, ks * 4, lane);
      f32x4 acc = {0.f, 0.f, 0.f, 0.f};
#pragma unroll
      for (int ks = 0; ks < 4; ++ks)
        acc = mfma16(a1[ks], ld_pack(pk_fc1, ntG, ks, 4, lane), acc);
#pragma unroll
      for (int r = 0; r < 4; ++r) {
        int row = mt * 16 + lg * 4 + r;
        float hv = acc[r] + b1;
        // tanh-form gelu: x*e/(e+1), e = exp(2*0.79788456*(x+0.044715x^3))
        float u = hv * (0.7978845608f + 0.0356774081f * hv * hv);
        float e = __expf(2.f * u);
        hv = hv - hv / (e + 1.f);
        Hl[swz_idx(row, col, 32)] = (__bf16)hv;
      }
    }
  }
  __syncthreads();

  // ---- Phase 7: F = H @ Wfc2 + b -> Ff f32 (wave pair per ntile; mt split) ----
  {
    int ntG = wv >> 1;
    int col = (ntG << 4) + lm;
    float b2 = fc2b[col];
#pragma unroll
    for (int mt2 = 0; mt2 < 2; ++mt2) {
      int mt = ((wv & 1) << 1) + mt2;
      bf16x8 a2[8];
#pragma unroll
      for (int ks = 0; ks < 8; ++ks) a2[ks] = ld_tile(Hl, 32, mt * 16, ks * 4, lane);
      f32x4 acc = {0.f, 0.f, 0.f, 0.f};
#pragma unroll
      for (int ks = 0; ks < 8; ++ks)
        acc = mfma16(a2[ks], ld_pack(pk_fc2, ntG, ks, 8, lane), acc);
#pragma unroll
      for (int r = 0; r < 4; ++r) {
        int row = mt * 16 + lg * 4 + r;
        Ff[row * XF_LD + col] = acc[r] + b2;
      }
    }
  }
  __syncthreads();

  // ---- Phase 8: out = x1 + LN(F), scatter back to original positions ----
  {
    int n = tid >> 4, c = tid & 15;
    const float* frow = Ff + n * XF_LD + (c << 3);
    float vals[8];
    float sum1 = 0.f, sum2 = 0.f;
#pragma unroll
    for (int jj = 0; jj < 8; ++jj) { float v = frow[jj]; vals[jj] = v; sum1 += v; sum2 += v * v; }
    sum1 += __shfl_xor(sum1, 1); sum1 += __shfl_xor(sum1, 2);
    sum1 += __shfl_xor(sum1, 4); sum1 += __shfl_xor(sum1, 8);
    sum2 += __shfl_xor(sum2, 1); sum2 += __shfl_xor(sum2, 2);
    sum2 += __shfl_xor(sum2, 4); sum2 += __shfl_xor(sum2, 8);
    float mean = sum1 * 0.0078125f;
    float var = sum2 * 0.0078125f - mean * mean;
    float rstd = rsqrtf(var + 1e-5f);
    int ts1 = n >> 3, ts2 = n & 7;
    int hh = ((wi << 3) + ts1 + 4) & 255;
    int ww = ((wj << 3) + ts2 + 4) & 255;
    float* op = outp + (((size_t)((b << 16) + (hh << 8) + ww)) << 7) + (c << 3);
    int dbase = (c << 3);
    float4 o4a, o4b;
    o4a.x = xr[0] + (vals[0] - mean) * rstd * n2g[dbase + 0] + n2b[dbase + 0];
    o4a.y = xr[1] + (vals[1] - mean) * rstd * n2g[dbase + 1] + n2b[dbase + 1];
    o4a.z = xr[2] + (vals[2] - mean) * rstd * n2g[dbase + 2] + n2b[dbase + 2];
    o4a.w = xr[3] + (vals[3] - mean) * rstd * n2g[dbase + 3] + n2b[dbase + 3];
    o4b.x = xr[4] + (vals[4] - mean) * rstd * n2g[dbase + 4] + n2b[dbase + 4];
    o4b.y = xr[5] + (vals[5] - mean) * rstd * n2g[dbase + 5] + n2b[dbase + 5];
    o4b.z = xr[6] + (vals[6] - mean) * rstd * n2g[dbase + 6] + n2b[dbase + 6];
    o4b.w = xr[7] + (vals[7] - mean) * rstd * n2g[dbase + 7] + n2b[dbase + 7];
    *(float4*)op = o4a;
    *(float4*)(op + 4) = o4b;
  }
}

// ---------------- launch ----------------
extern "C" void kernel_launch(void* const* d_in, const int* in_sizes, int n_in,
                              void* d_out, int out_size, void* d_ws, size_t ws_size,
                              hipStream_t stream) {
  const float* x      = (const float*)d_in[0];
  const float* uni_w  = (const float*)d_in[1];
  const float* uni_b  = (const float*)d_in[2];
  const float* ngqkvw = (const float*)d_in[3];
  const float* ngqkvb = (const float*)d_in[4];
  const float* ngprojw= (const float*)d_in[5];
  const float* ngprojb= (const float*)d_in[6];
  const float* ngbias = (const float*)d_in[7];
  const float* mergew = (const float*)d_in[8];
  const float* mergeb = (const float*)d_in[9];
  const float* qkvw   = (const float*)d_in[10];
  const float* qkvb   = (const float*)d_in[11];
  const float* projw  = (const float*)d_in[12];
  const float* projb  = (const float*)d_in[13];
  const float* bt     = (const float*)d_in[14];
  const float* n1g    = (const float*)d_in[15];
  const float* n1b    = (const float*)d_in[16];
  const float* n2g    = (const float*)d_in[17];
  const float* n2b    = (const float*)d_in[18];
  const float* fc1w   = (const float*)d_in[19];
  const float* fc1b   = (const float*)d_in[20];
  const float* fc2w   = (const float*)d_in[21];
  const float* fc2b   = (const float*)d_in[22];

  char* ws = (char*)d_ws;
  float*  uni = (float*)ws;                   // 1 MiB : [4][32][32][64]
  float*  ctx = (float*)(ws + (1 << 20));     // 2 MiB : [4][32][32][128]
  __bf16* pk  = (__bf16*)(ws + (3 << 20));    // 256 KiB packed weights
  __bf16* pk_qkv  = pk;
  __bf16* pk_wv   = pk + 32768;
  __bf16* pk_proj = pk + 49152;
  __bf16* pk_fc1  = pk + 65536;
  __bf16* pk_fc2  = pk + 98304;
  float*  w12T = (float*)(ws + (7 << 19));    // 3.5 MiB: [2][64][128] fused ctx weights
  float*  fb   = w12T + 16384;                // fused ctx bias [128]
  float*  btf  = (float*)(ws + 3840 * 1024);  // 256 KiB: [4][4][64][64] bias+mask

  k_prep<<<2881, 256, 0, stream>>>(qkvw, projw, fc1w, fc2w, ngprojw, ngprojb,
                                   mergew, mergeb, bt, x, uni_w, uni_b,
                                   pk, w12T, fb, btf, uni);
  k_ngram<<<512, 256, 158096, stream>>>(uni, ngqkvw, ngqkvb, ngbias, w12T, fb, ctx);
  k_main<<<4096, 1024, 98304, stream>>>(x, ctx, pk_qkv, pk_wv, pk_proj, pk_fc1, pk_fc2,
                                        qkvb, projb, btf, n1g, n1b, n2g, n2b, fc1b, fc2b,
                                        (float*)d_out);
}

// Round 11
// 303.670 us; speedup vs baseline: 5.3359x; 1.0948x over previous
//
#include <hip/hip_runtime.h>

// ---------------- types / helpers ----------------
typedef __bf16 bf16x8 __attribute__((ext_vector_type(8)));
typedef __bf16 bf16x4 __attribute__((ext_vector_type(4)));
typedef float  f32x4  __attribute__((ext_vector_type(4)));

#define QSCALE 0.17677669529663687f   // 32^-0.5 (main attn head_dim=32)
#define XF_LD 132                     // f32 tile stride: 132 ≡ 4 (mod 32), 16B-aligned rows

__device__ __forceinline__ f32x4 mfma16(bf16x8 a, bf16x8 b, f32x4 c) {
  return __builtin_amdgcn_mfma_f32_16x16x32_bf16(a, b, c, 0, 0, 0);
}

// row-major [rows][rowChunks*8] bf16 tile with XOR-swizzled 16B chunks
__device__ __forceinline__ int swz_idx(int row, int col, int rowChunks) {
  return row * (rowChunks << 3) + ((((col >> 3) ^ (row & 7)) << 3) | (col & 7));
}

// A/B fragment load from swizzled row-major LDS tile.
__device__ __forceinline__ bf16x8 ld_tile(const __bf16* t, int rowChunks,
                                          int rowBase, int chunkBase, int lane) {
  int row = rowBase + (lane & 15);
  int c = (chunkBase + (lane >> 4)) ^ (row & 7);
  return *(const bf16x8*)(t + row * (rowChunks << 3) + (c << 3));
}

// fragment load from pre-packed global weights (coalesced 1KiB per wave)
__device__ __forceinline__ bf16x8 ld_pack(const __bf16* pk, int nt, int ks,
                                          int ksteps, int lane) {
  int idx = ((nt * ksteps + ks) * 64 + lane) * 8;
  return *(const bf16x8*)(pk + idx);
}

// ---------------- K_prep: fused uniconv + weight packs + bias/mask table ------
__global__ void k_prep(const float* __restrict__ qkvw, const float* __restrict__ projw,
                       const float* __restrict__ fc1w, const float* __restrict__ fc2w,
                       const float* __restrict__ ngprojw, const float* __restrict__ ngprojb,
                       const float* __restrict__ mergew, const float* __restrict__ mergeb,
                       const float* __restrict__ bt,
                       const float* __restrict__ x, const float* __restrict__ uw,
                       const float* __restrict__ ub,
                       __bf16* __restrict__ pk, float* __restrict__ w12T,
                       float* __restrict__ fb, float* __restrict__ btf,
                       float* __restrict__ uni) {
  int blk = blockIdx.x;
  if (blk < 2048) {
    int bidx = blk * 2 + (threadIdx.x >> 7);
    int b = bidx >> 10, oh = (bidx >> 5) & 31, ow = bidx & 31;
    int d = threadIdx.x & 127;
    const float* xb = x + (((size_t)((b << 16) + ((oh << 3) << 8) + (ow << 3))) << 7) + d;
    const float* w = uw + d * 64;
    float acc = 0.f;
#pragma unroll
    for (int kh = 0; kh < 8; ++kh)
#pragma unroll
      for (int kw = 0; kw < 8; ++kw)
        acc += xb[(size_t)(((kh << 8) + kw)) << 7] * w[kh * 8 + kw];
    acc += __shfl_xor(acc, 1);
    if (!(d & 1)) uni[((size_t)bidx << 6) + (d >> 1)] = acc + ub[d >> 1];
  } else if (blk < 2560) {
    int i = (blk - 2048) * 256 + threadIdx.x;
    const float* src; int K; int e; int scaleQ = 0;
    if (i < 32768)      { src = qkvw;             K = 128; e = i;          scaleQ = 1; }
    else if (i < 49152) { src = qkvw + 256 * 128; K = 128; e = i - 32768; }
    else if (i < 65536) { src = projw;            K = 128; e = i - 49152; }
    else if (i < 98304) { src = fc1w;             K = 128; e = i - 65536; }
    else                { src = fc2w;             K = 256; e = i - 98304; }
    int i8 = e & 7, ln = (e >> 3) & 63, t = e >> 9;
    int ls = (K == 256) ? 3 : 2;
    int ks = t & ((1 << ls) - 1), nt = t >> ls;
    int row = (nt << 4) + (ln & 15);
    int k = (ks << 5) + ((ln >> 4) << 3) + i8;
    float v = src[row * K + k];
    if (scaleQ && row < 128) v *= QSCALE;
    pk[i] = (__bf16)v;
  } else if (blk < 2816) {
    // btf TRANSPOSED: idx = v<<14 | h<<12 | k<<6 | q  (rolled window coords)
    int idx = (blk - 2560) * 256 + threadIdx.x;
    int v = idx >> 14, h = (idx >> 12) & 3, kk = (idx >> 6) & 63, q = idx & 63;
    int s1n = q >> 3, s2n = q & 7, s1m = kk >> 3, s2m = kk & 7;
    int rpi = (s1n - s1m + 7) * 15 + (s2n - s2m + 7);
    float val = bt[rpi * 4 + h];
    if (((v & 1) && ((s1n < 4) != (s1m < 4))) ||
        ((v & 2) && ((s2n < 4) != (s2m < 4))))
      val -= 100.f;
    btf[idx] = val;
  } else {
    int idx = (blk - 2816) * 256 + threadIdx.x;
    if (idx < 16384) {
      int which = idx >> 13;
      int r = idx & 8191;
      int e = r >> 7, o = r & 127;
      float a = 0.f;
#pragma unroll 8
      for (int d = 0; d < 64; ++d)
        a += mergew[o * 128 + which * 64 + d] * ngprojw[d * 64 + e];
      w12T[idx] = a;
    } else if (idx < 16384 + 128) {
      int o = idx - 16384;
      float a = mergeb[o];
#pragma unroll 8
      for (int d = 0; d < 64; ++d)
        a += (mergew[o * 128 + d] + mergew[o * 128 + 64 + d]) * ngprojb[d];
      fb[o] = a;
    }
  }
}

// ---------------- K2: ngram path, 8 windows/block, LDS-staged weights ----------------
__global__ void __launch_bounds__(256, 1)
k_ngram(const float* __restrict__ uni, const float* __restrict__ ngqkvw,
        const float* __restrict__ ngqkvb, const float* __restrict__ ngbias,
        const float* __restrict__ w12T, const float* __restrict__ fbg,
        float* __restrict__ ctx) {
  extern __shared__ float sm[];
  float* qkvT = sm;                     // 12288
  float* w1T  = qkvT + 12288;           // 8192
  float* w2T  = w1T + 8192;             // 8192
  float* tokl = w2T + 8192;             // 2304
  float* qs   = tokl + 2304;            // 6912
  float* prs  = qs + 6912;              // 256
  float* avgl = prs + 256;              // 1024
  float* ngb  = avgl + 1024;            // 192
  float* fbs  = ngb + 192;              // 128
  float* nbias= fbs + 128;              // 36

  const int t = threadIdx.x;
  const int bidx = blockIdx.x;
  const int b = bidx >> 7, ii = (bidx >> 2) & 31, jq = bidx & 3;
  const int j0 = jq * 8;

#pragma unroll
  for (int it = 0; it < 12; ++it) {
    int f = it * 256 + t;
    int o = f >> 4, c4 = (f & 15) << 2;
    float4 v = *(const float4*)(ngqkvw + o * 64 + c4);
    float s = (o < 64) ? 0.25f : 1.f;
    qkvT[(c4 + 0) * 192 + o] = v.x * s;
    qkvT[(c4 + 1) * 192 + o] = v.y * s;
    qkvT[(c4 + 2) * 192 + o] = v.z * s;
    qkvT[(c4 + 3) * 192 + o] = v.w * s;
  }
#pragma unroll
  for (int it = 0; it < 16; ++it) {
    int f = (it * 256 + t) << 2;
    *(float4*)(w1T + f) = *(const float4*)(w12T + f);
  }
  if (t < 192) ngb[t] = ngqkvb[t] * (t < 64 ? 0.25f : 1.f);
  if (t < 128) fbs[t] = fbg[t];
  if (t < 36)  nbias[t] = ngbias[t];
  {
    int w = t >> 6, lane = t & 63;
    int dir = w >> 1, rr = w & 1;
    int pi = ii + rr;
    int srcr = (dir == 0) ? ((pi < 32) ? pi : 30) : ((pi == 0) ? 1 : pi - 1);
#pragma unroll
    for (int cc = 0; cc < 9; ++cc) {
      int pj = j0 + cc;
      int srcc = (dir == 0) ? ((pj < 32) ? pj : 30) : ((pj == 0) ? 1 : pj - 1);
      tokl[((dir * 2 + rr) * 9 + cc) * 64 + lane] =
          uni[(size_t)((b * 32 + srcr) * 32 + srcc) * 64 + lane];
    }
  }
  __syncthreads();

  {
    int w = t >> 6, lane = t & 63;
    for (int itp = 0; itp < 9; ++itp) {
      int pos = itp * 4 + w;
      const float* tk = tokl + pos * 64;
      float a0 = ngb[lane], a1 = ngb[64 + lane], a2 = ngb[128 + lane];
#pragma unroll 4
      for (int c = 0; c < 64; ++c) {
        float tv = tk[c];
        const float* qr = qkvT + c * 192;
        a0 += qr[lane] * tv;
        a1 += qr[64 + lane] * tv;
        a2 += qr[128 + lane] * tv;
      }
      float* dst = qs + pos * 192;
      dst[lane] = a0; dst[64 + lane] = a1; dst[128 + lane] = a2;
    }
  }
  __syncthreads();

  {
    int dw = t >> 4;
    int idx = t & 15, h = idx >> 2, p = idx & 3;
    int dir = dw >> 3, jl = dw & 7;
    const float* qp = qs + ((dir * 2 + (p >> 1)) * 9 + jl + (p & 1)) * 192 + h * 16;
    float s[4];
#pragma unroll
    for (int m = 0; m < 4; ++m) {
      const float* km = qs + ((dir * 2 + (m >> 1)) * 9 + jl + (m & 1)) * 192 + 64 + h * 16;
      float a = 0.f;
#pragma unroll
      for (int e = 0; e < 16; ++e) a += qp[e] * km[e];
      int bi2 = ((p >> 1) - (m >> 1) + 1) * 3 + ((p & 1) - (m & 1) + 1);
      s[m] = a + nbias[bi2 * 4 + h];
    }
    float mx = fmaxf(fmaxf(s[0], s[1]), fmaxf(s[2], s[3]));
    float e0 = __expf(s[0] - mx), e1 = __expf(s[1] - mx);
    float e2 = __expf(s[2] - mx), e3 = __expf(s[3] - mx);
    float inv = 1.f / (e0 + e1 + e2 + e3);
    float p0 = e0 * inv, p1 = e1 * inv, p2 = e2 * inv, p3 = e3 * inv;
    p0 += __shfl_xor(p0, 1); p0 += __shfl_xor(p0, 2);
    p1 += __shfl_xor(p1, 1); p1 += __shfl_xor(p1, 2);
    p2 += __shfl_xor(p2, 1); p2 += __shfl_xor(p2, 2);
    p3 += __shfl_xor(p3, 1); p3 += __shfl_xor(p3, 2);
    if (p == 0) {
      float* d = prs + (dw * 4 + h) * 4;
      d[0] = p0; d[1] = p1; d[2] = p2; d[3] = p3;
    }
  }
  __syncthreads();

  {
    int w = t >> 6, lane = t & 63;
#pragma unroll
    for (int it = 0; it < 4; ++it) {
      int dw = it * 4 + w;
      int dir = dw >> 3, jl = dw & 7;
      int h = lane >> 4;
      float a = 0.f;
#pragma unroll
      for (int m = 0; m < 4; ++m) {
        float pm = prs[(dw * 4 + h) * 4 + m];
        float vv = qs[((dir * 2 + (m >> 1)) * 9 + jl + (m & 1)) * 192 + 128 + lane];
        a += pm * vv;
      }
      avgl[dw * 64 + lane] = a * 0.25f;
    }
  }
  __syncthreads();

  {
#pragma unroll
    for (int it = 0; it < 4; ++it) {
      int id = it * 256 + t;
      int win = id >> 7, o = id & 127;
      const float* af = avgl + win * 64;
      const float* ab = avgl + (8 + win) * 64;
      float a = fbs[o];
#pragma unroll 4
      for (int c = 0; c < 64; ++c)
        a += w1T[c * 128 + o] * af[c] + w2T[c * 128 + o] * ab[c];
      int j = j0 + win;
      ctx[((size_t)((b * 32 + ii) * 32 + j)) * 128 + o] = a;
    }
  }
}

// ---------------- K3: fused window attention + LN + FFN + LN ----------------
// 1024 threads (16 waves); LDS map IDENTICAL to passing R10 (96 KiB, 1 blk/CU).
// All GEMM phases now compute C^T via operand swap -> packed 8B/16B C-stores.
__global__ void __launch_bounds__(1024, 2)
k_main(const float* __restrict__ xin, const float* __restrict__ ctx,
       const __bf16* __restrict__ pk_qkv, const __bf16* __restrict__ pk_wv,
       const __bf16* __restrict__ pk_proj, const __bf16* __restrict__ pk_fc1,
       const __bf16* __restrict__ pk_fc2,
       const float* __restrict__ qkvb, const float* __restrict__ projb,
       const float* __restrict__ btf,
       const float* __restrict__ n1g, const float* __restrict__ n1b,
       const float* __restrict__ n2g, const float* __restrict__ n2b,
       const float* __restrict__ fc1b, const float* __restrict__ fc2b,
       float* __restrict__ outp) {
  extern __shared__ char smem[];
  __bf16* Xbf = (__bf16*)smem;
  __bf16* QO  = (__bf16*)(smem + 16 * 1024);
  __bf16* Kl  = (__bf16*)(smem + 32 * 1024);
  __bf16* Vt  = (__bf16*)(smem + 48 * 1024);
  __bf16* Pl  = (__bf16*)(smem + 64 * 1024);
  float*  Rf  = (float*)(smem + 48 * 1024);   // [64][132] f32 (over dead Vt+Pl-head)
  __bf16* Hl  = (__bf16*)(smem + 16 * 1024);  // [64][256] bf16 swz (over dead QO+Kl)
  float*  Ff  = (float*)(smem + 48 * 1024);   // [64][132] f32

  const int widx = blockIdx.x;
  const int b = widx >> 10, wi = (widx >> 5) & 31, wj = widx & 31;
  const int tid = threadIdx.x;
  const int lane = tid & 63, wv = tid >> 6;   // 16 waves
  const int lm = lane & 15, lg = lane >> 4;

  float xr[8];   // x1 channels, regs from phase 5 to 8

  // ---- Phase 0: load tokens (x + ctx) -> Xbf ----
  {
    int n = tid >> 4, c = tid & 15;
    int ts1 = n >> 3, ts2 = n & 7;
    int hh = ((wi << 3) + ts1 + 4) & 255;
    int ww = ((wj << 3) + ts2 + 4) & 255;
    const float* xs = xin + (((size_t)((b << 16) + (hh << 8) + ww)) << 7) + (c << 3);
    const float* cs = ctx + (((size_t)((((b << 5) + (hh >> 3)) << 5) + (ww >> 3))) << 7) + (c << 3);
    float4 xa = *(const float4*)xs;
    float4 xb = *(const float4*)(xs + 4);
    float4 ca = *(const float4*)cs;
    float4 cb = *(const float4*)(cs + 4);
    float v[8];
    v[0] = xa.x + ca.x; v[1] = xa.y + ca.y; v[2] = xa.z + ca.z; v[3] = xa.w + ca.w;
    v[4] = xb.x + cb.x; v[5] = xb.y + cb.y; v[6] = xb.z + cb.z; v[7] = xb.w + cb.w;
    bf16x8 p8;
#pragma unroll
    for (int e = 0; e < 8; ++e) p8[e] = (__bf16)v[e];
    *(bf16x8*)(Xbf + (n << 7) + ((c ^ (n & 7)) << 3)) = p8;
  }
  __syncthreads();

  // ---- Phase 1a: Q,K = (W @ X^T)^T — packed stores (4 consecutive channels) ----
  {
    int ntG = wv;                           // channel tile 0..15 (Q:0-7, K:8-15)
    bf16x8 wf[4];
#pragma unroll
    for (int ks = 0; ks < 4; ++ks) wf[ks] = ld_pack(pk_qkv, ntG, ks, 4, lane);
    int col0 = (ntG << 4) + (lg << 2);      // 4 channels this thread owns
    float bias[4];
#pragma unroll
    for (int r = 0; r < 4; ++r)
      bias[r] = (ntG < 8) ? qkvb[col0 + r] * QSCALE : qkvb[col0 + r];
    __bf16* dst = (ntG < 8) ? QO : Kl;
    int cc0 = col0 & 127;
    for (int nt = 0; nt < 4; ++nt) {
      bf16x8 xf[4];
#pragma unroll
      for (int ks = 0; ks < 4; ++ks) xf[ks] = ld_tile(Xbf, 16, nt * 16, ks * 4, lane);
      f32x4 acc = {0.f, 0.f, 0.f, 0.f};
#pragma unroll
      for (int ks = 0; ks < 4; ++ks) acc = mfma16(wf[ks], xf[ks], acc);
      int tok = nt * 16 + lm;
      bf16x4 p4;
#pragma unroll
      for (int r = 0; r < 4; ++r) p4[r] = (__bf16)(acc[r] + bias[r]);
      *(bf16x4*)(dst + (tok << 7) + ((((cc0 >> 3) ^ (tok & 7)) << 3) | (cc0 & 7))) = p4;
    }
  }
  // ---- Phase 1b: V^T = Wv @ X^T (scalar stores; Vt is [ch][tok]) ----
  {
    int mtG = wv >> 1;                      // ch tile 0..7
    bf16x8 af[4];
#pragma unroll
    for (int ks = 0; ks < 4; ++ks) af[ks] = ld_pack(pk_wv, mtG, ks, 4, lane);
#pragma unroll
    for (int nt2 = 0; nt2 < 2; ++nt2) {
      int nt = ((wv & 1) << 1) + nt2;
      f32x4 acc = {0.f, 0.f, 0.f, 0.f};
#pragma unroll
      for (int ks = 0; ks < 4; ++ks)
        acc = mfma16(af[ks], ld_tile(Xbf, 16, nt * 16, ks * 4, lane), acc);
      int tok = (nt << 4) + lm;
#pragma unroll
      for (int r = 0; r < 4; ++r) {
        int ch = (mtG << 4) + lg * 4 + r;
        Vt[swz_idx(ch, tok, 8)] = (__bf16)(acc[r] + qkvb[256 + ch]);
      }
    }
  }
  __syncthreads();

  // ---- Phase 2: S^T = (K Q^T): thread owns one q-row slice; rinv folded into P ----
  const int h = wv >> 2, mq = wv & 3;       // head, 16-row quarter
  __bf16* Pme = Pl + (h << 12);
  {
    bf16x8 aq = ld_tile(QO, 16, mq * 16, h * 4, lane);      // B operand (rows=q)
    bf16x8 bk[4];
#pragma unroll
    for (int nt = 0; nt < 4; ++nt)
      bk[nt] = ld_tile(Kl, 16, nt * 16, h * 4, lane);       // A operands (rows=k)
    f32x4 sc[4];
#pragma unroll
    for (int nt = 0; nt < 4; ++nt) {
      f32x4 z = {0.f, 0.f, 0.f, 0.f};
      sc[nt] = mfma16(bk[nt], aq, z);       // C[k][q]: col=q, row=k
    }
    const int variant = (wi == 31 ? 1 : 0) | (wj == 31 ? 2 : 0);
    const float* btw = btf + (((variant << 2) + h) << 12);  // [k][q]
    const int q = mq * 16 + lm;
    float v[4][4];
    float mx = -1e30f;
#pragma unroll
    for (int nt = 0; nt < 4; ++nt)
#pragma unroll
      for (int r = 0; r < 4; ++r) {
        int kk = nt * 16 + (lg << 2) + r;
        float s = sc[nt][r] + btw[(kk << 6) + q];
        v[nt][r] = s;
        mx = fmaxf(mx, s);
      }
    mx = fmaxf(mx, __shfl_xor(mx, 16));
    mx = fmaxf(mx, __shfl_xor(mx, 32));
    float ssum = 0.f;
#pragma unroll
    for (int nt = 0; nt < 4; ++nt)
#pragma unroll
      for (int r = 0; r < 4; ++r) { v[nt][r] = __expf(v[nt][r] - mx); ssum += v[nt][r]; }
    ssum += __shfl_xor(ssum, 16);
    ssum += __shfl_xor(ssum, 32);
    float rinv = 1.f / ssum;
#pragma unroll
    for (int nt = 0; nt < 4; ++nt) {
      bf16x4 p4;
#pragma unroll
      for (int r = 0; r < 4; ++r) p4[r] = (__bf16)(v[nt][r] * rinv);
      int k0 = nt * 16 + (lg << 2);
      *(bf16x4*)(Pme + (q << 6) + ((((k0 >> 3) ^ (q & 7)) << 3) | (k0 & 7))) = p4;
    }
  }

  // ---- Phase 3: O^T = (V^T P^T): packed stores of 4 consecutive channels ----
  {
    bf16x8 ap[2];
#pragma unroll
    for (int ks = 0; ks < 2; ++ks)
      ap[ks] = ld_tile(Pme, 8, mq * 16, ks * 4, lane);      // B (rows=q)
#pragma unroll
    for (int nt = 0; nt < 2; ++nt) {
      bf16x8 bv0 = ld_tile(Vt, 8, h * 32 + nt * 16, 0, lane);   // A (rows=ch)
      bf16x8 bv1 = ld_tile(Vt, 8, h * 32 + nt * 16, 4, lane);
      f32x4 acc = {0.f, 0.f, 0.f, 0.f};
      acc = mfma16(bv0, ap[0], acc);
      acc = mfma16(bv1, ap[1], acc);
      int q = mq * 16 + lm;
      int ch0 = h * 32 + nt * 16 + (lg << 2);
      bf16x4 p4;
#pragma unroll
      for (int r = 0; r < 4; ++r) p4[r] = (__bf16)acc[r];
      *(bf16x4*)(QO + (q << 7) + ((((ch0 >> 3) ^ (q & 7)) << 3) | (ch0 & 7))) = p4;
    }
  }
  __syncthreads();

  // ---- Phase 4: R^T = (Wproj @ O^T): float4 stores into Rf [64][132] ----
  {
    int ntG = wv >> 1;
    int ch0 = (ntG << 4) + (lg << 2);
    float pb[4];
#pragma unroll
    for (int r = 0; r < 4; ++r) pb[r] = projb[ch0 + r];
    bf16x8 wf[4];
#pragma unroll
    for (int ks = 0; ks < 4; ++ks) wf[ks] = ld_pack(pk_proj, ntG, ks, 4, lane);
#pragma unroll
    for (int mt2 = 0; mt2 < 2; ++mt2) {
      int mt = ((wv & 1) << 1) + mt2;
      f32x4 acc = {0.f, 0.f, 0.f, 0.f};
#pragma unroll
      for (int ks = 0; ks < 4; ++ks)
        acc = mfma16(wf[ks], ld_tile(QO, 16, mt * 16, ks * 4, lane), acc);
      int tok = mt * 16 + lm;
      float4 st;
      st.x = acc[0] + pb[0]; st.y = acc[1] + pb[1];
      st.z = acc[2] + pb[2]; st.w = acc[3] + pb[3];
      *(float4*)(Rf + tok * XF_LD + ch0) = st;
    }
  }
  __syncthreads();

  // ---- Phase 5: x1 = x + LN(R); pristine x reloaded; x1 -> xr regs + Xbf ----
  {
    int n = tid >> 4, c = tid & 15;
    int ts1 = n >> 3, ts2 = n & 7;
    int hh = ((wi << 3) + ts1 + 4) & 255;
    int ww = ((wj << 3) + ts2 + 4) & 255;
    const float* xp = xin + (((size_t)((b << 16) + (hh << 8) + ww)) << 7) + (c << 3);
    float xv[8];
    {
      float4 v4 = *(const float4*)xp;
      float4 w4 = *(const float4*)(xp + 4);
      xv[0] = v4.x; xv[1] = v4.y; xv[2] = v4.z; xv[3] = v4.w;
      xv[4] = w4.x; xv[5] = w4.y; xv[6] = w4.z; xv[7] = w4.w;
    }
    const float* rrow = Rf + n * XF_LD + (c << 3);
    float vals[8];
    float sum1 = 0.f, sum2 = 0.f;
#pragma unroll
    for (int jj = 0; jj < 8; ++jj) { float v = rrow[jj]; vals[jj] = v; sum1 += v; sum2 += v * v; }
    sum1 += __shfl_xor(sum1, 1); sum1 += __shfl_xor(sum1, 2);
    sum1 += __shfl_xor(sum1, 4); sum1 += __shfl_xor(sum1, 8);
    sum2 += __shfl_xor(sum2, 1); sum2 += __shfl_xor(sum2, 2);
    sum2 += __shfl_xor(sum2, 4); sum2 += __shfl_xor(sum2, 8);
    float mean = sum1 * 0.0078125f;
    float var = sum2 * 0.0078125f - mean * mean;
    float rstd = rsqrtf(var + 1e-5f);
    bf16x8 p8;
#pragma unroll
    for (int e = 0; e < 8; ++e) {
      int d = (c << 3) + e;
      float ln = (vals[e] - mean) * rstd * n1g[d] + n1b[d];
      float x1 = xv[e] + ln;
      xr[e] = x1;
      p8[e] = (__bf16)x1;
    }
    *(bf16x8*)(Xbf + (n << 7) + ((c ^ (n & 7)) << 3)) = p8;
  }
  __syncthreads();

  // ---- Phase 6: H^T = (Wfc1 @ x1^T) + gelu: packed bf16x4 stores ----
  {
    int ntG = wv;                           // 0..15 over 256 cols
    int ch0 = (ntG << 4) + (lg << 2);
    float b1[4];
#pragma unroll
    for (int r = 0; r < 4; ++r) b1[r] = fc1b[ch0 + r];
    bf16x8 wf[4];
#pragma unroll
    for (int ks = 0; ks < 4; ++ks) wf[ks] = ld_pack(pk_fc1, ntG, ks, 4, lane);
    for (int nt = 0; nt < 4; ++nt) {
      f32x4 acc = {0.f, 0.f, 0.f, 0.f};
#pragma unroll
      for (int ks = 0; ks < 4; ++ks)
        acc = mfma16(wf[ks], ld_tile(Xbf, 16, nt * 16, ks * 4, lane), acc);
      int tok = nt * 16 + lm;
      bf16x4 p4;
#pragma unroll
      for (int r = 0; r < 4; ++r) {
        float hv = acc[r] + b1[r];
        float u = hv * (0.7978845608f + 0.0356774081f * hv * hv);
        float e = __expf(2.f * u);
        hv = hv - hv / (e + 1.f);
        p4[r] = (__bf16)hv;
      }
      *(bf16x4*)(Hl + (tok << 8) + ((((ch0 >> 3) ^ (tok & 7)) << 3) | (ch0 & 7))) = p4;
    }
  }
  __syncthreads();

  // ---- Phase 7: F^T = (Wfc2 @ H^T): float4 stores into Ff [64][132] ----
  {
    int ntG = wv >> 1;
    int ch0 = (ntG << 4) + (lg << 2);
    float b2[4];
#pragma unroll
    for (int r = 0; r < 4; ++r) b2[r] = fc2b[ch0 + r];
    bf16x8 wf[8];
#pragma unroll
    for (int ks = 0; ks < 8; ++ks) wf[ks] = ld_pack(pk_fc2, ntG, ks, 8, lane);
#pragma unroll
    for (int mt2 = 0; mt2 < 2; ++mt2) {
      int mt = ((wv & 1) << 1) + mt2;
      f32x4 acc = {0.f, 0.f, 0.f, 0.f};
#pragma unroll
      for (int ks = 0; ks < 8; ++ks)
        acc = mfma16(wf[ks], ld_tile(Hl, 32, mt * 16, ks * 4, lane), acc);
      int tok = mt * 16 + lm;
      float4 st;
      st.x = acc[0] + b2[0]; st.y = acc[1] + b2[1];
      st.z = acc[2] + b2[2]; st.w = acc[3] + b2[3];
      *(float4*)(Ff + tok * XF_LD + ch0) = st;
    }
  }
  __syncthreads();

  // ---- Phase 8: out = x1 + LN(F), scatter back to original positions ----
  {
    int n = tid >> 4, c = tid & 15;
    const float* frow = Ff + n * XF_LD + (c << 3);
    float vals[8];
    float sum1 = 0.f, sum2 = 0.f;
#pragma unroll
    for (int jj = 0; jj < 8; ++jj) { float v = frow[jj]; vals[jj] = v; sum1 += v; sum2 += v * v; }
    sum1 += __shfl_xor(sum1, 1); sum1 += __shfl_xor(sum1, 2);
    sum1 += __shfl_xor(sum1, 4); sum1 += __shfl_xor(sum1, 8);
    sum2 += __shfl_xor(sum2, 1); sum2 += __shfl_xor(sum2, 2);
    sum2 += __shfl_xor(sum2, 4); sum2 += __shfl_xor(sum2, 8);
    float mean = sum1 * 0.0078125f;
    float var = sum2 * 0.0078125f - mean * mean;
    float rstd = rsqrtf(var + 1e-5f);
    int ts1 = n >> 3, ts2 = n & 7;
    int hh = ((wi << 3) + ts1 + 4) & 255;
    int ww = ((wj << 3) + ts2 + 4) & 255;
    float* op = outp + (((size_t)((b << 16) + (hh << 8) + ww)) << 7) + (c << 3);
    int dbase = (c << 3);
    float4 o4a, o4b;
    o4a.x = xr[0] + (vals[0] - mean) * rstd * n2g[dbase + 0] + n2b[dbase + 0];
    o4a.y = xr[1] + (vals[1] - mean) * rstd * n2g[dbase + 1] + n2b[dbase + 1];
    o4a.z = xr[2] + (vals[2] - mean) * rstd * n2g[dbase + 2] + n2b[dbase + 2];
    o4a.w = xr[3] + (vals[3] - mean) * rstd * n2g[dbase + 3] + n2b[dbase + 3];
    o4b.x = xr[4] + (vals[4] - mean) * rstd * n2g[dbase + 4] + n2b[dbase + 4];
    o4b.y = xr[5] + (vals[5] - mean) * rstd * n2g[dbase + 5] + n2b[dbase + 5];
    o4b.z = xr[6] + (vals[6] - mean) * rstd * n2g[dbase + 6] + n2b[dbase + 6];
    o4b.w = xr[7] + (vals[7] - mean) * rstd * n2g[dbase + 7] + n2b[dbase + 7];
    *(float4*)op = o4a;
    *(float4*)(op + 4) = o4b;
  }
}

// ---------------- launch ----------------
extern "C" void kernel_launch(void* const* d_in, const int* in_sizes, int n_in,
                              void* d_out, int out_size, void* d_ws, size_t ws_size,
                              hipStream_t stream) {
  const float* x      = (const float*)d_in[0];
  const float* uni_w  = (const float*)d_in[1];
  const float* uni_b  = (const float*)d_in[2];
  const float* ngqkvw = (const float*)d_in[3];
  const float* ngqkvb = (const float*)d_in[4];
  const float* ngprojw= (const float*)d_in[5];
  const float* ngprojb= (const float*)d_in[6];
  const float* ngbias = (const float*)d_in[7];
  const float* mergew = (const float*)d_in[8];
  const float* mergeb = (const float*)d_in[9];
  const float* qkvw   = (const float*)d_in[10];
  const float* qkvb   = (const float*)d_in[11];
  const float* projw  = (const float*)d_in[12];
  const float* projb  = (const float*)d_in[13];
  const float* bt     = (const float*)d_in[14];
  const float* n1g    = (const float*)d_in[15];
  const float* n1b    = (const float*)d_in[16];
  const float* n2g    = (const float*)d_in[17];
  const float* n2b    = (const float*)d_in[18];
  const float* fc1w   = (const float*)d_in[19];
  const float* fc1b   = (const float*)d_in[20];
  const float* fc2w   = (const float*)d_in[21];
  const float* fc2b   = (const float*)d_in[22];

  char* ws = (char*)d_ws;
  float*  uni = (float*)ws;                   // 1 MiB : [4][32][32][64]
  float*  ctx = (float*)(ws + (1 << 20));     // 2 MiB : [4][32][32][128]
  __bf16* pk  = (__bf16*)(ws + (3 << 20));    // 256 KiB packed weights
  __bf16* pk_qkv  = pk;
  __bf16* pk_wv   = pk + 32768;
  __bf16* pk_proj = pk + 49152;
  __bf16* pk_fc1  = pk + 65536;
  __bf16* pk_fc2  = pk + 98304;
  float*  w12T = (float*)(ws + (7 << 19));    // 3.5 MiB: [2][64][128] fused ctx weights
  float*  fb   = w12T + 16384;                // fused ctx bias [128]
  float*  btf  = (float*)(ws + 3840 * 1024);  // 256 KiB: [4][4][64(k)][64(q)] bias+mask

  k_prep<<<2881, 256, 0, stream>>>(qkvw, projw, fc1w, fc2w, ngprojw, ngprojb,
                                   mergew, mergeb, bt, x, uni_w, uni_b,
                                   pk, w12T, fb, btf, uni);
  k_ngram<<<512, 256, 158096, stream>>>(uni, ngqkvw, ngqkvb, ngbias, w12T, fb, ctx);
  k_main<<<4096, 1024, 98304, stream>>>(x, ctx, pk_qkv, pk_wv, pk_proj, pk_fc1, pk_fc2,
                                        qkvb, projb, btf, n1g, n1b, n2g, n2b, fc1b, fc2b,
                                        (float*)d_out);
}